// Round 1
// baseline (508.281 us; speedup 1.0000x reference)
//
#include <hip/hip_runtime.h>
#include <hip/hip_bf16.h>

#define DEV __device__ __forceinline__

#define B_    16
#define T_    40
#define TDEC  41
#define NH    128
#define HF    8
#define WF    128
#define HID   64
#define G3    192
#define NCLS  6625
#define SPAT  1024

DEV float sigmoidf_(float x){ return 1.0f/(1.0f + __expf(-x)); }
DEV float tanhf_(float x){ float e = __expf(2.0f*x); return 1.0f - 2.0f/(e + 1.0f); }
DEV float gelu_(float x){ return 0.5f*x*(1.0f + erff(x*0.70710678118654752f)); }
DEV float bnf_(float x, float g, float b, float m, float v){
  return (x - m)*rsqrtf(v + 1e-5f)*g + b;
}

// ---------------- conv0 4x4 s4 + BN + GELU -> h (16,128,8,128) ----------------
__global__ __launch_bounds__(256) void k_conv0(const float* __restrict__ x,
    const float* __restrict__ w, const float* __restrict__ bias,
    const float* __restrict__ bng, const float* __restrict__ bnb,
    const float* __restrict__ bnm, const float* __restrict__ bnv,
    float* __restrict__ h)
{
  int tid = blockIdx.x*256 + threadIdx.x;   // 524288 threads, 4 co each
  int ow = tid & 127;
  int oh = (tid >> 7) & 7;
  int c4 = (tid >> 10) & 31;
  int b  = tid >> 15;
  float acc[4] = {0.f,0.f,0.f,0.f};
  int xbase = ((b*3)*32 + oh*4)*512 + ow*4;
  for (int ci = 0; ci < 3; ++ci){
    #pragma unroll
    for (int kh = 0; kh < 4; ++kh){
      float4 xv = *(const float4*)(x + xbase + ci*(32*512) + kh*512);
      #pragma unroll
      for (int cc = 0; cc < 4; ++cc){
        int co = c4*4 + cc;
        const float* wp = w + ((co*3 + ci)*4 + kh)*4;
        acc[cc] += xv.x*wp[0] + xv.y*wp[1] + xv.z*wp[2] + xv.w*wp[3];
      }
    }
  }
  #pragma unroll
  for (int cc = 0; cc < 4; ++cc){
    int co = c4*4 + cc;
    float v = acc[cc] + bias[co];
    v = bnf_(v, bng[co], bnb[co], bnm[co], bnv[co]);
    h[((b*NH + co)*HF + oh)*WF + ow] = gelu_(v);
  }
}

// ---------------- depthwise 3x3 (blk idx 1) + BN + GELU + residual -> t -------
__global__ __launch_bounds__(256) void k_dw(const float* __restrict__ h,
    const float* __restrict__ dww, const float* __restrict__ dwb,
    const float* __restrict__ g1, const float* __restrict__ b1,
    const float* __restrict__ m1, const float* __restrict__ v1,
    float* __restrict__ t)
{
  int tid = blockIdx.x*256 + threadIdx.x;   // 2097152
  int ow = tid & 127;
  int oh = (tid >> 7) & 7;
  int c  = (tid >> 10) & 127;
  int b  = tid >> 17;
  const float* wp = dww + NH*9 + c*9;       // block index 1
  const float* hp = h + ((b*NH + c)*HF)*WF;
  float acc = 0.f;
  #pragma unroll
  for (int kh = 0; kh < 3; ++kh){
    int ih = oh + kh - 1;
    if (ih < 0 || ih >= HF) continue;
    #pragma unroll
    for (int kw = 0; kw < 3; ++kw){
      int iw = ow + kw - 1;
      if (iw < 0 || iw >= WF) continue;
      acc += hp[ih*WF + iw]*wp[kh*3 + kw];
    }
  }
  float val = acc + dwb[NH + c];
  val = bnf_(val, g1[NH + c], b1[NH + c], m1[NH + c], v1[NH + c]);
  t[tid] = hp[oh*WF + ow] + gelu_(val);
}

// ---------------- transpose pw weights: pwT[ci][co] = pw[1][co][ci] ----------
__global__ void k_pwT(const float* __restrict__ pw, float* __restrict__ pwT){
  int tid = blockIdx.x*256 + threadIdx.x;   // 16384
  int ci = tid & 127; int co = tid >> 7;
  pwT[ci*128 + co] = pw[16384 + co*128 + ci];
}

// ---------------- pointwise 128x128 (blk idx 1) + BN + GELU -> feat ----------
__global__ __launch_bounds__(512) void k_pw(const float* __restrict__ t,
    const float* __restrict__ pwT, const float* __restrict__ pwb,
    const float* __restrict__ g2, const float* __restrict__ b2,
    const float* __restrict__ m2, const float* __restrict__ v2,
    float* __restrict__ feat)
{
  int bid = blockIdx.x;                     // (b, oh, whalf): 256 blocks
  int wh = bid & 1; int oh = (bid >> 1) & 7; int b = bid >> 4;
  int w0 = wh*64;
  int tid = threadIdx.x;
  __shared__ __align__(16) float tile[128*64];
  for (int i = 0; i < 16; ++i){
    int e = i*512 + tid; int ci = e >> 6; int wloc = e & 63;
    tile[ci*64 + wloc] = t[((b*NH + ci)*HF + oh)*WF + w0 + wloc];
  }
  __syncthreads();
  int co = tid & 127; int wq = tid >> 7;
  float acc[16];
  #pragma unroll
  for (int i = 0; i < 16; ++i) acc[i] = 0.f;
  for (int ci = 0; ci < 128; ++ci){
    float wt = pwT[ci*128 + co];
    const float4* tp = (const float4*)(tile + ci*64 + wq*16);
    #pragma unroll
    for (int j = 0; j < 4; ++j){
      float4 tv = tp[j];
      acc[j*4+0] += tv.x*wt; acc[j*4+1] += tv.y*wt;
      acc[j*4+2] += tv.z*wt; acc[j*4+3] += tv.w*wt;
    }
  }
  float bb = pwb[128 + co];
  float gg = g2[128 + co], bc = b2[128 + co], mm = m2[128 + co], vv = v2[128 + co];
  float* op = feat + ((b*NH + co)*HF + oh)*WF + w0 + wq*16;
  #pragma unroll
  for (int i = 0; i < 16; ++i){
    float v = bnf_(acc[i] + bb, gg, bc, mm, vv);
    op[i] = gelu_(v);
  }
}

// ---------------- enc xp GEMM: (2048x1024)@(192x1024)^T + bih -> xp ----------
__global__ __launch_bounds__(256) void k_encxp(const float* __restrict__ feat,
    const float* __restrict__ wih, const float* __restrict__ bih,
    float* __restrict__ xp)
{
  int m0 = blockIdx.x*32;     // 64 m-tiles
  int n0 = blockIdx.y*48;     // 4 n-tiles
  int b  = m0 >> 7;
  int w0 = m0 & 127;
  int tid = threadIdx.x;
  __shared__ float As[64*33];  // [k][m]
  __shared__ float Bs[64*49];  // [k][n]
  int tx = tid & 15, ty = tid >> 4;
  float acc[2][3] = {{0.f,0.f,0.f},{0.f,0.f,0.f}};
  for (int kt = 0; kt < 16; ++kt){
    int k0 = kt*64;
    #pragma unroll
    for (int i = 0; i < 8; ++i){
      int e = i*256 + tid; int kd = e >> 5; int mi = e & 31;
      int kg = k0 + kd;
      As[kd*33 + mi] = feat[((b*NH + (kg >> 3))*HF + (kg & 7))*WF + w0 + mi];
    }
    #pragma unroll
    for (int i = 0; i < 12; ++i){
      int e = i*256 + tid; int gi = e >> 6; int kd = e & 63;
      Bs[kd*49 + gi] = wih[(n0 + gi)*1024 + k0 + kd];
    }
    __syncthreads();
    for (int kd = 0; kd < 64; ++kd){
      float a0 = As[kd*33 + ty*2], a1 = As[kd*33 + ty*2 + 1];
      float b0 = Bs[kd*49 + tx*3], b1 = Bs[kd*49 + tx*3 + 1], b2 = Bs[kd*49 + tx*3 + 2];
      acc[0][0] += a0*b0; acc[0][1] += a0*b1; acc[0][2] += a0*b2;
      acc[1][0] += a1*b0; acc[1][1] += a1*b1; acc[1][2] += a1*b2;
    }
    __syncthreads();
  }
  #pragma unroll
  for (int i = 0; i < 2; ++i){
    int m = m0 + ty*2 + i;
    #pragma unroll
    for (int j = 0; j < 3; ++j){
      int g = n0 + tx*3 + j;
      xp[m*G3 + g] = acc[i][j] + bih[g];
    }
  }
}

// ---------------- enc GRU scan: 128 steps, keep only final h -----------------
__global__ __launch_bounds__(192) void k_encscan(const float* __restrict__ xp,
    const float* __restrict__ whh, const float* __restrict__ bhh,
    float* __restrict__ indec)
{
  __shared__ float hsh[HID];
  __shared__ float hpsh[G3];
  __shared__ float xtsh[G3];
  int g = threadIdx.x; int b = blockIdx.x;
  float4 w4[16];
  const float4* wp4 = (const float4*)(whh + g*HID);
  #pragma unroll
  for (int j = 0; j < 16; ++j) w4[j] = wp4[j];
  float bg = bhh[g];
  if (g < HID) hsh[g] = 0.f;
  __syncthreads();
  const float* xpb = xp + b*(WF*G3);
  for (int t = 0; t < WF; ++t){
    float xt = xpb[t*G3 + g];
    const float4* h4 = (const float4*)hsh;
    float a0 = 0.f, a1 = 0.f, a2 = 0.f, a3 = 0.f;
    #pragma unroll
    for (int j = 0; j < 16; ++j){
      float4 hv = h4[j];
      a0 += hv.x*w4[j].x; a1 += hv.y*w4[j].y;
      a2 += hv.z*w4[j].z; a3 += hv.w*w4[j].w;
    }
    hpsh[g] = (a0 + a1) + (a2 + a3) + bg;
    xtsh[g] = xt;
    __syncthreads();
    if (g < HID){
      float r = sigmoidf_(xtsh[g] + hpsh[g]);
      float z = sigmoidf_(xtsh[HID + g] + hpsh[HID + g]);
      float n = tanhf_(xtsh[2*HID + g] + r*hpsh[2*HID + g]);
      hsh[g] = (1.f - z)*n + z*hsh[g];
    }
    __syncthreads();
  }
  if (g < HID) indec[(b*TDEC)*HID + g] = hsh[g];
}

// ---------------- embedding fill: indec rows 1..40 ---------------------------
__global__ void k_embed(const int* __restrict__ tgt, const float* __restrict__ emb,
                        float* __restrict__ indec)
{
  int tid = blockIdx.x*256 + threadIdx.x;   // 40960
  if (tid >= B_*T_*HID) return;
  int j = tid & 63; int rest = tid >> 6;
  int t = rest % T_; int b = rest / T_;
  int cls = tgt[b*T_ + t];
  indec[(b*TDEC + 1 + t)*HID + j] = emb[cls*HID + j];
}

// ---------------- dec xp: (656x64)@(192x64)^T + bih --------------------------
__global__ void k_xpd(const float* __restrict__ indec, const float* __restrict__ wih,
                      const float* __restrict__ bih, float* __restrict__ xpd)
{
  int tid = blockIdx.x*256 + threadIdx.x;   // 125952
  if (tid >= B_*TDEC*G3) return;
  int g = tid % G3; int bt = tid / G3;
  const float4* r4 = (const float4*)(indec + bt*HID);
  const float4* w4 = (const float4*)(wih + g*HID);
  float acc = bih[g];
  #pragma unroll
  for (int j = 0; j < 16; ++j){
    float4 rv = r4[j], wv = w4[j];
    acc += rv.x*wv.x + rv.y*wv.y + rv.z*wv.z + rv.w*wv.w;
  }
  xpd[tid] = acc;
}

// ---------------- dec GRU scan: 41 steps, keep all y -------------------------
__global__ __launch_bounds__(192) void k_decscan(const float* __restrict__ xpd,
    const float* __restrict__ whh, const float* __restrict__ bhh,
    float* __restrict__ y)
{
  __shared__ float hsh[HID];
  __shared__ float hpsh[G3];
  __shared__ float xtsh[G3];
  int g = threadIdx.x; int b = blockIdx.x;
  float4 w4[16];
  const float4* wp4 = (const float4*)(whh + g*HID);
  #pragma unroll
  for (int j = 0; j < 16; ++j) w4[j] = wp4[j];
  float bg = bhh[g];
  if (g < HID) hsh[g] = 0.f;
  __syncthreads();
  const float* xpb = xpd + b*(TDEC*G3);
  for (int t = 0; t < TDEC; ++t){
    float xt = xpb[t*G3 + g];
    const float4* h4 = (const float4*)hsh;
    float a0 = 0.f, a1 = 0.f, a2 = 0.f, a3 = 0.f;
    #pragma unroll
    for (int j = 0; j < 16; ++j){
      float4 hv = h4[j];
      a0 += hv.x*w4[j].x; a1 += hv.y*w4[j].y;
      a2 += hv.z*w4[j].z; a3 += hv.w*w4[j].w;
    }
    hpsh[g] = (a0 + a1) + (a2 + a3) + bg;
    xtsh[g] = xt;
    __syncthreads();
    if (g < HID){
      float r = sigmoidf_(xtsh[g] + hpsh[g]);
      float z = sigmoidf_(xtsh[HID + g] + hpsh[HID + g]);
      float n = tanhf_(xtsh[2*HID + g] + r*hpsh[2*HID + g]);
      float hn = (1.f - z)*n + z*hsh[g];
      hsh[g] = hn;
      y[(b*TDEC + t)*HID + g] = hn;
    }
    __syncthreads();
  }
}

// ---------------- q = y @ q_w^T + q_b ---------------------------------------
__global__ void k_q(const float* __restrict__ y, const float* __restrict__ qw,
                    const float* __restrict__ qb0, float* __restrict__ q)
{
  int tid = blockIdx.x*256 + threadIdx.x;   // 83968
  if (tid >= B_*TDEC*NH) return;
  int co = tid & 127; int bt = tid >> 7;
  const float4* r4 = (const float4*)(y + bt*HID);
  const float4* w4 = (const float4*)(qw + co*HID);
  float acc = qb0[co];
  #pragma unroll
  for (int j = 0; j < 16; ++j){
    float4 rv = r4[j], wv = w4[j];
    acc += rv.x*wv.x + rv.y*wv.y + rv.z*wv.z + rv.w*wv.w;
  }
  q[tid] = acc;
}

// ---------------- k conv 3x3 pad 1 (conv + bias only) ------------------------
__global__ __launch_bounds__(256) void k_kconv(const float* __restrict__ feat,
    const float* __restrict__ kwp, const float* __restrict__ kb,
    float* __restrict__ ko)
{
  int bid = blockIdx.x;                  // (b, oh, wh): 256 blocks
  int wh = bid & 1; int oh = (bid >> 1) & 7; int b = bid >> 4;
  int w0 = wh*64;
  int tid = threadIdx.x;
  int wg = tid & 7;        // 8 groups of 8 w
  int cog = tid >> 3;      // 32 groups of 4 co
  __shared__ __align__(16) float ins[8*3*68];
  __shared__ __align__(16) float wts[8*9*128];
  float acc[4][8];
  #pragma unroll
  for (int i = 0; i < 4; ++i)
    #pragma unroll
    for (int j = 0; j < 8; ++j) acc[i][j] = 0.f;

  for (int cc = 0; cc < 16; ++cc){
    int ci0 = cc*8;
    // weights: wts[(ci*9+k)][co] <- kw[co][ci0+ci][kh][kw] (72 contiguous per co)
    if (tid < 128){
      int co = tid;
      const float* wp = kwp + co*1152 + ci0*9;
      #pragma unroll
      for (int u = 0; u < 72; u += 4){
        float4 wv = *(const float4*)(wp + u);
        wts[(u+0)*128 + co] = wv.x; wts[(u+1)*128 + co] = wv.y;
        wts[(u+2)*128 + co] = wv.z; wts[(u+3)*128 + co] = wv.w;
      }
    }
    // input halo tile: ins[ci][kh][ww], ww in [0,66) -> iw = w0-1+ww
    {
      int r = tid >> 5;        // ci within chunk
      int lane = tid & 31;
      #pragma unroll
      for (int kh = 0; kh < 3; ++kh){
        int ih = oh + kh - 1;
        for (int ww = lane; ww < 66; ww += 32){
          int iw = w0 - 1 + ww;
          float v = 0.f;
          if (ih >= 0 && ih < HF && iw >= 0 && iw < WF)
            v = feat[((b*NH + ci0 + r)*HF + ih)*WF + iw];
          ins[(r*3 + kh)*68 + ww] = v;
        }
      }
    }
    __syncthreads();
    #pragma unroll
    for (int ci = 0; ci < 8; ++ci){
      float wv[4][9];
      #pragma unroll
      for (int k9 = 0; k9 < 9; ++k9){
        float4 t4 = *(const float4*)(wts + (ci*9 + k9)*128 + cog*4);
        wv[0][k9] = t4.x; wv[1][k9] = t4.y; wv[2][k9] = t4.z; wv[3][k9] = t4.w;
      }
      float inr[3][10];
      #pragma unroll
      for (int kh = 0; kh < 3; ++kh)
        #pragma unroll
        for (int u = 0; u < 10; ++u)
          inr[kh][u] = ins[(ci*3 + kh)*68 + wg*8 + u];
      #pragma unroll
      for (int c2 = 0; c2 < 4; ++c2)
        #pragma unroll
        for (int kh = 0; kh < 3; ++kh)
          #pragma unroll
          for (int kw2 = 0; kw2 < 3; ++kw2)
            #pragma unroll
            for (int ww = 0; ww < 8; ++ww)
              acc[c2][ww] += inr[kh][ww + kw2]*wv[c2][kh*3 + kw2];
    }
    __syncthreads();
  }
  #pragma unroll
  for (int c2 = 0; c2 < 4; ++c2){
    int co = cog*4 + c2;
    float bias = kb[co];
    float* op = ko + ((b*NH + co)*HF + oh)*WF + w0 + wg*8;
    #pragma unroll
    for (int ww = 0; ww < 8; ++ww) op[ww] = acc[c2][ww] + bias;
  }
}

// ---------------- e[b,t,s] = sum_c e_w[c]*tanh(k[b,c,s] + q[b,t,c]) + e_b ----
__global__ __launch_bounds__(256) void k_e(const float* __restrict__ k,
    const float* __restrict__ q, const float* __restrict__ ew,
    const float* __restrict__ eb, float* __restrict__ e)
{
  int bt = blockIdx.x;
  int b = bt / TDEC;
  int tid = threadIdx.x;
  __shared__ float qs[NH];
  if (tid < NH) qs[tid] = q[bt*NH + tid];
  __syncthreads();
  float ebv = eb[0];
  float acc[4] = {ebv, ebv, ebv, ebv};
  for (int c = 0; c < NH; ++c){
    float ewc = ew[c];
    float qc = qs[c];
    const float* kp = k + (b*NH + c)*SPAT;
    #pragma unroll
    for (int i = 0; i < 4; ++i)
      acc[i] += ewc*tanhf_(kp[tid + i*256] + qc);
  }
  #pragma unroll
  for (int i = 0; i < 4; ++i)
    e[bt*SPAT + tid + i*256] = acc[i];
}

// ---------------- softmax over 1024 per (b,t), in-place ----------------------
__global__ __launch_bounds__(256) void k_softmax(float* __restrict__ e)
{
  int bt = blockIdx.x; int tid = threadIdx.x;
  float* row = e + bt*SPAT;
  __shared__ float red[256];
  float v[4];
  #pragma unroll
  for (int i = 0; i < 4; ++i) v[i] = row[tid + i*256];
  float m = fmaxf(fmaxf(v[0], v[1]), fmaxf(v[2], v[3]));
  red[tid] = m; __syncthreads();
  for (int s = 128; s > 0; s >>= 1){
    if (tid < s) red[tid] = fmaxf(red[tid], red[tid + s]);
    __syncthreads();
  }
  float mx = red[0];
  __syncthreads();
  float ev[4]; float sum = 0.f;
  #pragma unroll
  for (int i = 0; i < 4; ++i){ ev[i] = __expf(v[i] - mx); sum += ev[i]; }
  red[tid] = sum; __syncthreads();
  for (int s = 128; s > 0; s >>= 1){
    if (tid < s) red[tid] += red[tid + s];
    __syncthreads();
  }
  float inv = 1.f/red[0];
  #pragma unroll
  for (int i = 0; i < 4; ++i) row[tid + i*256] = ev[i]*inv;
}

// ---------------- attn_feat[b,t,c] = sum_s feat[b,c,s]*a[b,t,s] --------------
__global__ __launch_bounds__(256) void k_attnf(const float* __restrict__ feat,
    const float* __restrict__ a, float* __restrict__ attnf)
{
  int bid = blockIdx.x;                  // (b, tq(11), ch(2)): 352 blocks
  int ch = bid & 1; int rest = bid >> 1;
  int tq = rest % 11; int b = rest / 11;
  int tid = threadIdx.x;
  __shared__ __align__(16) float ash[4*SPAT];
  __shared__ float psh[4*4*64];
  for (int i = 0; i < 16; ++i){
    int e = i*256 + tid; int tt = e >> 10; int s = e & 1023;
    int t = tq*4 + tt;
    ash[e] = (t < TDEC) ? a[(b*TDEC + t)*SPAT + s] : 0.f;
  }
  __syncthreads();
  int cl = tid & 63; int sq = tid >> 6;
  const float* fp = feat + (b*NH + ch*64 + cl)*SPAT + sq*256;
  float acc[4] = {0.f,0.f,0.f,0.f};
  for (int i = 0; i < 64; ++i){
    float4 fv = *(const float4*)(fp + i*4);
    #pragma unroll
    for (int tt = 0; tt < 4; ++tt){
      const float* ar = ash + tt*SPAT + sq*256 + i*4;
      acc[tt] += fv.x*ar[0] + fv.y*ar[1] + fv.z*ar[2] + fv.w*ar[3];
    }
  }
  #pragma unroll
  for (int tt = 0; tt < 4; ++tt) psh[(sq*4 + tt)*64 + cl] = acc[tt];
  __syncthreads();
  {
    int tt = tid >> 6; int c2 = tid & 63;
    int t = tq*4 + tt;
    if (t < TDEC){
      float v = psh[(0*4 + tt)*64 + c2] + psh[(1*4 + tt)*64 + c2]
              + psh[(2*4 + tt)*64 + c2] + psh[(3*4 + tt)*64 + c2];
      attnf[(b*TDEC + t)*NH + ch*64 + c2] = v;
    }
  }
}

// ---------------- out = attnf @ fc_w^T + fc_b --------------------------------
__global__ __launch_bounds__(256) void k_fc(const float* __restrict__ attnf,
    const float* __restrict__ fcw, const float* __restrict__ fcb,
    float* __restrict__ out)
{
  int n0 = blockIdx.x*64;   // 104 cls-tiles
  int m0 = blockIdx.y*32;   // 21 m-tiles
  int tid = threadIdx.x;
  __shared__ __align__(16) float at[128*36];   // [j][m]
  __shared__ __align__(16) float wt[128*68];   // [j][cls]
  __shared__ float bsh[64];
  for (int i = 0; i < 16; ++i){
    int e = i*256 + tid; int m = e >> 7; int j = e & 127;
    at[j*36 + m] = (m0 + m < B_*TDEC) ? attnf[(m0 + m)*NH + j] : 0.f;
  }
  for (int i = 0; i < 32; ++i){
    int e = i*256 + tid; int cl = e >> 7; int j = e & 127;
    int n = n0 + cl;
    wt[j*68 + cl] = (n < NCLS) ? fcw[n*NH + j] : 0.f;
  }
  if (tid < 64) bsh[tid] = (n0 + tid < NCLS) ? fcb[n0 + tid] : 0.f;
  __syncthreads();
  int tn = tid & 15, tm = tid >> 4;
  float acc[2][4] = {{0.f,0.f,0.f,0.f},{0.f,0.f,0.f,0.f}};
  for (int j = 0; j < 128; ++j){
    float2 av = *(const float2*)(at + j*36 + tm*2);
    float4 wv = *(const float4*)(wt + j*68 + tn*4);
    acc[0][0] += av.x*wv.x; acc[0][1] += av.x*wv.y;
    acc[0][2] += av.x*wv.z; acc[0][3] += av.x*wv.w;
    acc[1][0] += av.y*wv.x; acc[1][1] += av.y*wv.y;
    acc[1][2] += av.y*wv.z; acc[1][3] += av.y*wv.w;
  }
  #pragma unroll
  for (int i = 0; i < 2; ++i){
    int m = m0 + tm*2 + i;
    if (m < B_*TDEC){
      #pragma unroll
      for (int ii = 0; ii < 4; ++ii){
        int n = n0 + tn*4 + ii;
        if (n < NCLS) out[m*NCLS + n] = acc[i][ii] + bsh[tn*4 + ii];
      }
    }
  }
}

// ============================================================================
extern "C" void kernel_launch(void* const* d_in, const int* in_sizes, int n_in,
                              void* d_out, int out_size, void* d_ws, size_t ws_size,
                              hipStream_t stream)
{
  (void)in_sizes; (void)n_in; (void)out_size; (void)ws_size;
  const float* x      = (const float*)d_in[0];
  const int*   tgt    = (const int*)  d_in[1];
  const float* conv0w = (const float*)d_in[2];
  const float* conv0b = (const float*)d_in[3];
  const float* bn0g   = (const float*)d_in[4];
  const float* bn0b   = (const float*)d_in[5];
  const float* bn0m   = (const float*)d_in[6];
  const float* bn0v   = (const float*)d_in[7];
  const float* dww    = (const float*)d_in[8];
  const float* dwb    = (const float*)d_in[9];
  const float* bn1g   = (const float*)d_in[10];
  const float* bn1b   = (const float*)d_in[11];
  const float* bn1m   = (const float*)d_in[12];
  const float* bn1v   = (const float*)d_in[13];
  const float* pww    = (const float*)d_in[14];
  const float* pwb    = (const float*)d_in[15];
  const float* bn2g   = (const float*)d_in[16];
  const float* bn2b   = (const float*)d_in[17];
  const float* bn2m   = (const float*)d_in[18];
  const float* bn2v   = (const float*)d_in[19];
  const float* encwih = (const float*)d_in[20];
  const float* encwhh = (const float*)d_in[21];
  const float* encbih = (const float*)d_in[22];
  const float* encbhh = (const float*)d_in[23];
  const float* decwih = (const float*)d_in[24];
  const float* decwhh = (const float*)d_in[25];
  const float* decbih = (const float*)d_in[26];
  const float* decbhh = (const float*)d_in[27];
  const float* emb    = (const float*)d_in[28];
  const float* qw     = (const float*)d_in[29];
  const float* qb0    = (const float*)d_in[30];
  const float* kw     = (const float*)d_in[31];
  const float* kb     = (const float*)d_in[32];
  const float* ew     = (const float*)d_in[33];
  const float* eb     = (const float*)d_in[34];
  const float* fcw    = (const float*)d_in[35];
  const float* fcb    = (const float*)d_in[36];

  float* ws    = (float*)d_ws;
  float* hbuf  = ws + 0;         // 2097152
  float* tbuf  = ws + 2097152;   // 2097152
  float* feat  = ws + 4194304;   // 2097152
  float* xp    = ws + 6291456;   // 393216
  float* indec = ws + 6684672;   // 41984
  float* xpd   = ws + 6726656;   // 125952
  float* ybuf  = ws + 6852608;   // 41984
  float* qbuf  = ws + 6894592;   // 83968
  float* attf  = ws + 6978560;   // 83968
  float* pwT   = ws + 7062528;   // 16384
  float* kbuf  = hbuf;           // alias: h dead after k_dw
  float* ebuf  = tbuf;           // alias: t dead after k_pw
  float* out   = (float*)d_out;

  hipLaunchKernelGGL(k_pwT,     dim3(64),          dim3(256), 0, stream, pww, pwT);
  hipLaunchKernelGGL(k_conv0,   dim3(2048),        dim3(256), 0, stream,
                     x, conv0w, conv0b, bn0g, bn0b, bn0m, bn0v, hbuf);
  hipLaunchKernelGGL(k_dw,      dim3(8192),        dim3(256), 0, stream,
                     hbuf, dww, dwb, bn1g, bn1b, bn1m, bn1v, tbuf);
  hipLaunchKernelGGL(k_pw,      dim3(256),         dim3(512), 0, stream,
                     tbuf, pwT, pwb, bn2g, bn2b, bn2m, bn2v, feat);
  hipLaunchKernelGGL(k_embed,   dim3(160),         dim3(256), 0, stream, tgt, emb, indec);
  hipLaunchKernelGGL(k_encxp,   dim3(64, 4),       dim3(256), 0, stream,
                     feat, encwih, encbih, xp);
  hipLaunchKernelGGL(k_encscan, dim3(16),          dim3(192), 0, stream,
                     xp, encwhh, encbhh, indec);
  hipLaunchKernelGGL(k_xpd,     dim3(492),         dim3(256), 0, stream,
                     indec, decwih, decbih, xpd);
  hipLaunchKernelGGL(k_decscan, dim3(16),          dim3(192), 0, stream,
                     xpd, decwhh, decbhh, ybuf);
  hipLaunchKernelGGL(k_q,       dim3(328),         dim3(256), 0, stream,
                     ybuf, qw, qb0, qbuf);
  hipLaunchKernelGGL(k_kconv,   dim3(256),         dim3(256), 0, stream,
                     feat, kw, kb, kbuf);
  hipLaunchKernelGGL(k_e,       dim3(B_*TDEC),     dim3(256), 0, stream,
                     kbuf, qbuf, ew, eb, ebuf);
  hipLaunchKernelGGL(k_softmax, dim3(B_*TDEC),     dim3(256), 0, stream, ebuf);
  hipLaunchKernelGGL(k_attnf,   dim3(352),         dim3(256), 0, stream,
                     feat, ebuf, attf);
  hipLaunchKernelGGL(k_fc,      dim3(104, 21),     dim3(256), 0, stream,
                     attf, fcw, fcb, out);
}

// Round 2
// 455.197 us; speedup vs baseline: 1.1166x; 1.1166x over previous
//
#include <hip/hip_runtime.h>
#include <hip/hip_bf16.h>

#define DEV __device__ __forceinline__

#define B_    16
#define T_    40
#define TDEC  41
#define NH    128
#define HF    8
#define WF    128
#define HID   64
#define G3    192
#define NCLS  6625
#define SPAT  1024

typedef _Float16 half8 __attribute__((ext_vector_type(8)));
typedef float    f32x4 __attribute__((ext_vector_type(4)));

DEV float sigmoidf_(float x){ return 1.0f/(1.0f + __expf(-x)); }
DEV float tanhf_(float x){ float e = __expf(2.0f*x); return 1.0f - 2.0f/(e + 1.0f); }
DEV float gelu_(float x){ return 0.5f*x*(1.0f + erff(x*0.70710678118654752f)); }
DEV float bnf_(float x, float g, float b, float m, float v){
  return (x - m)*rsqrtf(v + 1e-5f)*g + b;
}

// ---------------- conv0 4x4 s4 + BN + GELU -> h (16,128,8,128) ----------------
__global__ __launch_bounds__(256) void k_conv0(const float* __restrict__ x,
    const float* __restrict__ w, const float* __restrict__ bias,
    const float* __restrict__ bng, const float* __restrict__ bnb,
    const float* __restrict__ bnm, const float* __restrict__ bnv,
    float* __restrict__ h)
{
  int tid = blockIdx.x*256 + threadIdx.x;   // 524288 threads, 4 co each
  int ow = tid & 127;
  int oh = (tid >> 7) & 7;
  int c4 = (tid >> 10) & 31;
  int b  = tid >> 15;
  float acc[4] = {0.f,0.f,0.f,0.f};
  int xbase = ((b*3)*32 + oh*4)*512 + ow*4;
  for (int ci = 0; ci < 3; ++ci){
    #pragma unroll
    for (int kh = 0; kh < 4; ++kh){
      float4 xv = *(const float4*)(x + xbase + ci*(32*512) + kh*512);
      #pragma unroll
      for (int cc = 0; cc < 4; ++cc){
        int co = c4*4 + cc;
        const float* wp = w + ((co*3 + ci)*4 + kh)*4;
        acc[cc] += xv.x*wp[0] + xv.y*wp[1] + xv.z*wp[2] + xv.w*wp[3];
      }
    }
  }
  #pragma unroll
  for (int cc = 0; cc < 4; ++cc){
    int co = c4*4 + cc;
    float v = acc[cc] + bias[co];
    v = bnf_(v, bng[co], bnb[co], bnm[co], bnv[co]);
    h[((b*NH + co)*HF + oh)*WF + ow] = gelu_(v);
  }
}

// ---------------- depthwise 3x3 (blk idx 1) + BN + GELU + residual -> t -------
__global__ __launch_bounds__(256) void k_dw(const float* __restrict__ h,
    const float* __restrict__ dww, const float* __restrict__ dwb,
    const float* __restrict__ g1, const float* __restrict__ b1,
    const float* __restrict__ m1, const float* __restrict__ v1,
    float* __restrict__ t)
{
  int tid = blockIdx.x*256 + threadIdx.x;   // 2097152
  int ow = tid & 127;
  int oh = (tid >> 7) & 7;
  int c  = (tid >> 10) & 127;
  int b  = tid >> 17;
  const float* wp = dww + NH*9 + c*9;       // block index 1
  const float* hp = h + ((b*NH + c)*HF)*WF;
  float acc = 0.f;
  #pragma unroll
  for (int kh = 0; kh < 3; ++kh){
    int ih = oh + kh - 1;
    if (ih < 0 || ih >= HF) continue;
    #pragma unroll
    for (int kw = 0; kw < 3; ++kw){
      int iw = ow + kw - 1;
      if (iw < 0 || iw >= WF) continue;
      acc += hp[ih*WF + iw]*wp[kh*3 + kw];
    }
  }
  float val = acc + dwb[NH + c];
  val = bnf_(val, g1[NH + c], b1[NH + c], m1[NH + c], v1[NH + c]);
  t[tid] = hp[oh*WF + ow] + gelu_(val);
}

// ---------------- transpose pw weights: pwT[ci][co] = pw[1][co][ci] ----------
__global__ void k_pwT(const float* __restrict__ pw, float* __restrict__ pwT){
  int tid = blockIdx.x*256 + threadIdx.x;   // 16384
  int ci = tid & 127; int co = tid >> 7;
  pwT[ci*128 + co] = pw[16384 + co*128 + ci];
}

// ---------------- pointwise 128x128 (blk idx 1) + BN + GELU -> feat ----------
__global__ __launch_bounds__(512) void k_pw(const float* __restrict__ t,
    const float* __restrict__ pwT, const float* __restrict__ pwb,
    const float* __restrict__ g2, const float* __restrict__ b2,
    const float* __restrict__ m2, const float* __restrict__ v2,
    float* __restrict__ feat)
{
  int bid = blockIdx.x;                     // (b, oh, whalf): 256 blocks
  int wh = bid & 1; int oh = (bid >> 1) & 7; int b = bid >> 4;
  int w0 = wh*64;
  int tid = threadIdx.x;
  __shared__ __align__(16) float tile[128*64];
  for (int i = 0; i < 16; ++i){
    int e = i*512 + tid; int ci = e >> 6; int wloc = e & 63;
    tile[ci*64 + wloc] = t[((b*NH + ci)*HF + oh)*WF + w0 + wloc];
  }
  __syncthreads();
  int co = tid & 127; int wq = tid >> 7;
  float acc[16];
  #pragma unroll
  for (int i = 0; i < 16; ++i) acc[i] = 0.f;
  for (int ci = 0; ci < 128; ++ci){
    float wt = pwT[ci*128 + co];
    const float4* tp = (const float4*)(tile + ci*64 + wq*16);
    #pragma unroll
    for (int j = 0; j < 4; ++j){
      float4 tv = tp[j];
      acc[j*4+0] += tv.x*wt; acc[j*4+1] += tv.y*wt;
      acc[j*4+2] += tv.z*wt; acc[j*4+3] += tv.w*wt;
    }
  }
  float bb = pwb[128 + co];
  float gg = g2[128 + co], bc = b2[128 + co], mm = m2[128 + co], vv = v2[128 + co];
  float* op = feat + ((b*NH + co)*HF + oh)*WF + w0 + wq*16;
  #pragma unroll
  for (int i = 0; i < 16; ++i){
    float v = bnf_(acc[i] + bb, gg, bc, mm, vv);
    op[i] = gelu_(v);
  }
}

// ---------------- enc xp GEMM: (2048x1024)@(192x1024)^T + bih -> xp ----------
__global__ __launch_bounds__(256) void k_encxp(const float* __restrict__ feat,
    const float* __restrict__ wih, const float* __restrict__ bih,
    float* __restrict__ xp)
{
  int m0 = blockIdx.x*32;     // 64 m-tiles
  int n0 = blockIdx.y*48;     // 4 n-tiles
  int b  = m0 >> 7;
  int w0 = m0 & 127;
  int tid = threadIdx.x;
  __shared__ float As[64*33];  // [k][m]
  __shared__ float Bs[64*49];  // [k][n]
  int tx = tid & 15, ty = tid >> 4;
  float acc[2][3] = {{0.f,0.f,0.f},{0.f,0.f,0.f}};
  for (int kt = 0; kt < 16; ++kt){
    int k0 = kt*64;
    #pragma unroll
    for (int i = 0; i < 8; ++i){
      int e = i*256 + tid; int kd = e >> 5; int mi = e & 31;
      int kg = k0 + kd;
      As[kd*33 + mi] = feat[((b*NH + (kg >> 3))*HF + (kg & 7))*WF + w0 + mi];
    }
    #pragma unroll
    for (int i = 0; i < 12; ++i){
      int e = i*256 + tid; int gi = e >> 6; int kd = e & 63;
      Bs[kd*49 + gi] = wih[(n0 + gi)*1024 + k0 + kd];
    }
    __syncthreads();
    for (int kd = 0; kd < 64; ++kd){
      float a0 = As[kd*33 + ty*2], a1 = As[kd*33 + ty*2 + 1];
      float b0 = Bs[kd*49 + tx*3], b1 = Bs[kd*49 + tx*3 + 1], b2 = Bs[kd*49 + tx*3 + 2];
      acc[0][0] += a0*b0; acc[0][1] += a0*b1; acc[0][2] += a0*b2;
      acc[1][0] += a1*b0; acc[1][1] += a1*b1; acc[1][2] += a1*b2;
    }
    __syncthreads();
  }
  #pragma unroll
  for (int i = 0; i < 2; ++i){
    int m = m0 + ty*2 + i;
    #pragma unroll
    for (int j = 0; j < 3; ++j){
      int g = n0 + tx*3 + j;
      xp[m*G3 + g] = acc[i][j] + bih[g];
    }
  }
}

// ---------------- enc GRU scan: 128 steps, keep only final h -----------------
__global__ __launch_bounds__(192) void k_encscan(const float* __restrict__ xp,
    const float* __restrict__ whh, const float* __restrict__ bhh,
    float* __restrict__ indec)
{
  __shared__ float hsh[HID];
  __shared__ float hpsh[G3];
  __shared__ float xtsh[G3];
  int g = threadIdx.x; int b = blockIdx.x;
  float4 w4[16];
  const float4* wp4 = (const float4*)(whh + g*HID);
  #pragma unroll
  for (int j = 0; j < 16; ++j) w4[j] = wp4[j];
  float bg = bhh[g];
  if (g < HID) hsh[g] = 0.f;
  __syncthreads();
  const float* xpb = xp + b*(WF*G3);
  for (int t = 0; t < WF; ++t){
    float xt = xpb[t*G3 + g];
    const float4* h4 = (const float4*)hsh;
    float a0 = 0.f, a1 = 0.f, a2 = 0.f, a3 = 0.f;
    #pragma unroll
    for (int j = 0; j < 16; ++j){
      float4 hv = h4[j];
      a0 += hv.x*w4[j].x; a1 += hv.y*w4[j].y;
      a2 += hv.z*w4[j].z; a3 += hv.w*w4[j].w;
    }
    hpsh[g] = (a0 + a1) + (a2 + a3) + bg;
    xtsh[g] = xt;
    __syncthreads();
    if (g < HID){
      float r = sigmoidf_(xtsh[g] + hpsh[g]);
      float z = sigmoidf_(xtsh[HID + g] + hpsh[HID + g]);
      float n = tanhf_(xtsh[2*HID + g] + r*hpsh[2*HID + g]);
      hsh[g] = (1.f - z)*n + z*hsh[g];
    }
    __syncthreads();
  }
  if (g < HID) indec[(b*TDEC)*HID + g] = hsh[g];
}

// ---------------- embedding fill: indec rows 1..40 ---------------------------
__global__ void k_embed(const int* __restrict__ tgt, const float* __restrict__ emb,
                        float* __restrict__ indec)
{
  int tid = blockIdx.x*256 + threadIdx.x;   // 40960
  if (tid >= B_*T_*HID) return;
  int j = tid & 63; int rest = tid >> 6;
  int t = rest % T_; int b = rest / T_;
  int cls = tgt[b*T_ + t];
  indec[(b*TDEC + 1 + t)*HID + j] = emb[cls*HID + j];
}

// ---------------- dec xp: (656x64)@(192x64)^T + bih --------------------------
__global__ void k_xpd(const float* __restrict__ indec, const float* __restrict__ wih,
                      const float* __restrict__ bih, float* __restrict__ xpd)
{
  int tid = blockIdx.x*256 + threadIdx.x;   // 125952
  if (tid >= B_*TDEC*G3) return;
  int g = tid % G3; int bt = tid / G3;
  const float4* r4 = (const float4*)(indec + bt*HID);
  const float4* w4 = (const float4*)(wih + g*HID);
  float acc = bih[g];
  #pragma unroll
  for (int j = 0; j < 16; ++j){
    float4 rv = r4[j], wv = w4[j];
    acc += rv.x*wv.x + rv.y*wv.y + rv.z*wv.z + rv.w*wv.w;
  }
  xpd[tid] = acc;
}

// ---------------- dec GRU scan: 41 steps, keep all y -------------------------
__global__ __launch_bounds__(192) void k_decscan(const float* __restrict__ xpd,
    const float* __restrict__ whh, const float* __restrict__ bhh,
    float* __restrict__ y)
{
  __shared__ float hsh[HID];
  __shared__ float hpsh[G3];
  __shared__ float xtsh[G3];
  int g = threadIdx.x; int b = blockIdx.x;
  float4 w4[16];
  const float4* wp4 = (const float4*)(whh + g*HID);
  #pragma unroll
  for (int j = 0; j < 16; ++j) w4[j] = wp4[j];
  float bg = bhh[g];
  if (g < HID) hsh[g] = 0.f;
  __syncthreads();
  const float* xpb = xpd + b*(TDEC*G3);
  for (int t = 0; t < TDEC; ++t){
    float xt = xpb[t*G3 + g];
    const float4* h4 = (const float4*)hsh;
    float a0 = 0.f, a1 = 0.f, a2 = 0.f, a3 = 0.f;
    #pragma unroll
    for (int j = 0; j < 16; ++j){
      float4 hv = h4[j];
      a0 += hv.x*w4[j].x; a1 += hv.y*w4[j].y;
      a2 += hv.z*w4[j].z; a3 += hv.w*w4[j].w;
    }
    hpsh[g] = (a0 + a1) + (a2 + a3) + bg;
    xtsh[g] = xt;
    __syncthreads();
    if (g < HID){
      float r = sigmoidf_(xtsh[g] + hpsh[g]);
      float z = sigmoidf_(xtsh[HID + g] + hpsh[HID + g]);
      float n = tanhf_(xtsh[2*HID + g] + r*hpsh[2*HID + g]);
      float hn = (1.f - z)*n + z*hsh[g];
      hsh[g] = hn;
      y[(b*TDEC + t)*HID + g] = hn;
    }
    __syncthreads();
  }
}

// ---------------- q = y @ q_w^T + q_b ---------------------------------------
__global__ void k_q(const float* __restrict__ y, const float* __restrict__ qw,
                    const float* __restrict__ qb0, float* __restrict__ q)
{
  int tid = blockIdx.x*256 + threadIdx.x;   // 83968
  if (tid >= B_*TDEC*NH) return;
  int co = tid & 127; int bt = tid >> 7;
  const float4* r4 = (const float4*)(y + bt*HID);
  const float4* w4 = (const float4*)(qw + co*HID);
  float acc = qb0[co];
  #pragma unroll
  for (int j = 0; j < 16; ++j){
    float4 rv = r4[j], wv = w4[j];
    acc += rv.x*wv.x + rv.y*wv.y + rv.z*wv.z + rv.w*wv.w;
  }
  q[tid] = acc;
}

// ---------------- k-conv weight prep: fragment-ordered fp16 A ---------------
// kwA[((s*8 + f)*64 + l)*8 + j] = kw[co][ci][r] with co=f*16+(l&15),
// k = s*32 + (l>>4)*8 + j, r = k>>7, ci = k&127   (K order: k = r*128 + ci)
__global__ void k_wprep(const float* __restrict__ kw, _Float16* __restrict__ kwA)
{
  int tid = blockIdx.x*256 + threadIdx.x;   // 147456
  if (tid >= 36*8*64*8) return;
  int j = tid & 7;
  int l = (tid >> 3) & 63;
  int f = (tid >> 9) & 7;
  int s = tid >> 12;
  int co = f*16 + (l & 15);
  int k  = s*32 + ((l >> 4) << 3) + j;
  int r  = k >> 7;
  int ci = k & 127;
  kwA[tid] = (_Float16)kw[(co*128 + ci)*9 + r];
}

// ---------------- k conv 3x3 pad 1 via fp16 MFMA implicit GEMM --------------
// D[co][m] = sum_k W[co][k] * Patch[k][m];  m = ow within (b,oh,wq) tile.
__global__ __launch_bounds__(256) void k_kconv2(const float* __restrict__ feat,
    const _Float16* __restrict__ kwA, const float* __restrict__ kb,
    float* __restrict__ ko)
{
  int bid = blockIdx.x;                     // (b, oh, wq): 256 blocks
  int wq = bid & 1; int oh = (bid >> 1) & 7; int b = bid >> 4;
  int w0 = wq*64;
  int tid = threadIdx.x;
  int l  = tid & 63;
  int wv = tid >> 6;

  __shared__ _Float16 Alds[4096];   // 8 co-frags x 64 lanes x 8
  __shared__ _Float16 Blds[2048];   // 4 m-frags  x 64 lanes x 8

  f32x4 acc[2][4];
  #pragma unroll
  for (int i = 0; i < 2; ++i)
    #pragma unroll
    for (int n = 0; n < 4; ++n)
      acc[i][n] = (f32x4){0.f,0.f,0.f,0.f};

  // B staging roles: u = m index, c0 = base of 8 k-rows this thread converts
  int u  = tid & 63;
  int c0 = (tid >> 6)*8;
  int bl  = ((c0 >> 3) << 4) + (u & 15);    // lane slot
  int bnf = u >> 4;
  int bdst = (bnf*64 + bl)*8;               // halves

  float bv[8];
  uint4 av0, av1;

  const uint4* kwA4 = (const uint4*)kwA;    // 8 halves per uint4

  #define ISSUE_A(s) { av0 = kwA4[(s)*512 + tid]; av1 = kwA4[(s)*512 + tid + 256]; }
  #define ISSUE_B(s) {                                                        \
    int r = (s) >> 2; int ci0 = ((s) & 3) << 5;                               \
    int dh = r/3 - 1, dw2 = r%3 - 1;                                          \
    int ih = oh + dh;                                                         \
    int iw = w0 + u + dw2;                                                    \
    bool ok = (ih >= 0) & (ih < HF) & (iw >= 0) & (iw < WF);                  \
    const float* fp = feat + ((b*NH + ci0 + c0)*HF + ih)*WF + iw;             \
    _Pragma("unroll")                                                         \
    for (int jj = 0; jj < 8; ++jj) bv[jj] = ok ? fp[jj*(HF*WF)] : 0.f;        \
  }
  #define COMMIT() {                                                          \
    ((uint4*)Alds)[tid] = av0; ((uint4*)Alds)[tid + 256] = av1;               \
    half8 hb;                                                                 \
    _Pragma("unroll")                                                         \
    for (int jj = 0; jj < 8; ++jj) hb[jj] = (_Float16)bv[jj];                 \
    *(half8*)(Blds + bdst) = hb;                                              \
  }

  ISSUE_A(0); ISSUE_B(0);
  COMMIT();
  __syncthreads();

  for (int s = 0; s < 36; ++s){
    if (s < 35){ ISSUE_A(s+1); ISSUE_B(s+1); }
    half8 af[2], bf[4];
    #pragma unroll
    for (int i = 0; i < 2; ++i)
      af[i] = *(const half8*)(Alds + ((wv*2 + i)*64 + l)*8);
    #pragma unroll
    for (int n = 0; n < 4; ++n)
      bf[n] = *(const half8*)(Blds + (n*64 + l)*8);
    #pragma unroll
    for (int i = 0; i < 2; ++i)
      #pragma unroll
      for (int n = 0; n < 4; ++n)
        acc[i][n] = __builtin_amdgcn_mfma_f32_16x16x32_f16(af[i], bf[n], acc[i][n], 0, 0, 0);
    __syncthreads();
    if (s < 35){ COMMIT(); __syncthreads(); }
  }

  // epilogue: lane holds D[co][m]: co = frag*16 + (l>>4)*4 + q, m = l&15
  #pragma unroll
  for (int i = 0; i < 2; ++i){
    int cobase = (wv*2 + i)*16 + ((l >> 4) << 2);
    #pragma unroll
    for (int q = 0; q < 4; ++q){
      int co = cobase + q;
      float bias = kb[co];
      float* op = ko + ((b*NH + co)*HF + oh)*WF + w0 + (l & 15);
      #pragma unroll
      for (int n = 0; n < 4; ++n)
        op[n*16] = acc[i][n][q] + bias;
    }
  }
  #undef ISSUE_A
  #undef ISSUE_B
  #undef COMMIT
}

// ---------------- e[b,t,s] = sum_c e_w[c]*tanh(k[b,c,s] + q[b,t,c]) + e_b ----
__global__ __launch_bounds__(256) void k_e(const float* __restrict__ k,
    const float* __restrict__ q, const float* __restrict__ ew,
    const float* __restrict__ eb, float* __restrict__ e)
{
  int bt = blockIdx.x;
  int b = bt / TDEC;
  int tid = threadIdx.x;
  __shared__ float qs[NH];
  if (tid < NH) qs[tid] = q[bt*NH + tid];
  __syncthreads();
  float ebv = eb[0];
  float acc[4] = {ebv, ebv, ebv, ebv};
  for (int c = 0; c < NH; ++c){
    float ewc = ew[c];
    float qc = qs[c];
    const float* kp = k + (b*NH + c)*SPAT;
    #pragma unroll
    for (int i = 0; i < 4; ++i)
      acc[i] += ewc*tanhf_(kp[tid + i*256] + qc);
  }
  #pragma unroll
  for (int i = 0; i < 4; ++i)
    e[bt*SPAT + tid + i*256] = acc[i];
}

// ---------------- softmax over 1024 per (b,t), in-place ----------------------
__global__ __launch_bounds__(256) void k_softmax(float* __restrict__ e)
{
  int bt = blockIdx.x; int tid = threadIdx.x;
  float* row = e + bt*SPAT;
  __shared__ float red[256];
  float v[4];
  #pragma unroll
  for (int i = 0; i < 4; ++i) v[i] = row[tid + i*256];
  float m = fmaxf(fmaxf(v[0], v[1]), fmaxf(v[2], v[3]));
  red[tid] = m; __syncthreads();
  for (int s = 128; s > 0; s >>= 1){
    if (tid < s) red[tid] = fmaxf(red[tid], red[tid + s]);
    __syncthreads();
  }
  float mx = red[0];
  __syncthreads();
  float ev[4]; float sum = 0.f;
  #pragma unroll
  for (int i = 0; i < 4; ++i){ ev[i] = __expf(v[i] - mx); sum += ev[i]; }
  red[tid] = sum; __syncthreads();
  for (int s = 128; s > 0; s >>= 1){
    if (tid < s) red[tid] += red[tid + s];
    __syncthreads();
  }
  float inv = 1.f/red[0];
  #pragma unroll
  for (int i = 0; i < 4; ++i) row[tid + i*256] = ev[i]*inv;
}

// ---------------- attn_feat[b,t,c] = sum_s feat[b,c,s]*a[b,t,s] --------------
__global__ __launch_bounds__(256) void k_attnf(const float* __restrict__ feat,
    const float* __restrict__ a, float* __restrict__ attnf)
{
  int bid = blockIdx.x;                  // (b, tq(11), ch(2)): 352 blocks
  int ch = bid & 1; int rest = bid >> 1;
  int tq = rest % 11; int b = rest / 11;
  int tid = threadIdx.x;
  __shared__ __align__(16) float ash[4*SPAT];
  __shared__ float psh[4*4*64];
  for (int i = 0; i < 16; ++i){
    int e = i*256 + tid; int tt = e >> 10; int s = e & 1023;
    int t = tq*4 + tt;
    ash[e] = (t < TDEC) ? a[(b*TDEC + t)*SPAT + s] : 0.f;
  }
  __syncthreads();
  int cl = tid & 63; int sq = tid >> 6;
  const float* fp = feat + (b*NH + ch*64 + cl)*SPAT + sq*256;
  float acc[4] = {0.f,0.f,0.f,0.f};
  for (int i = 0; i < 64; ++i){
    float4 fv = *(const float4*)(fp + i*4);
    #pragma unroll
    for (int tt = 0; tt < 4; ++tt){
      const float* ar = ash + tt*SPAT + sq*256 + i*4;
      acc[tt] += fv.x*ar[0] + fv.y*ar[1] + fv.z*ar[2] + fv.w*ar[3];
    }
  }
  #pragma unroll
  for (int tt = 0; tt < 4; ++tt) psh[(sq*4 + tt)*64 + cl] = acc[tt];
  __syncthreads();
  {
    int tt = tid >> 6; int c2 = tid & 63;
    int t = tq*4 + tt;
    if (t < TDEC){
      float v = psh[(0*4 + tt)*64 + c2] + psh[(1*4 + tt)*64 + c2]
              + psh[(2*4 + tt)*64 + c2] + psh[(3*4 + tt)*64 + c2];
      attnf[(b*TDEC + t)*NH + ch*64 + c2] = v;
    }
  }
}

// ---------------- out = attnf @ fc_w^T + fc_b --------------------------------
__global__ __launch_bounds__(256) void k_fc(const float* __restrict__ attnf,
    const float* __restrict__ fcw, const float* __restrict__ fcb,
    float* __restrict__ out)
{
  int n0 = blockIdx.x*64;   // 104 cls-tiles
  int m0 = blockIdx.y*32;   // 21 m-tiles
  int tid = threadIdx.x;
  __shared__ __align__(16) float at[128*36];   // [j][m]
  __shared__ __align__(16) float wt[128*68];   // [j][cls]
  __shared__ float bsh[64];
  for (int i = 0; i < 16; ++i){
    int e = i*256 + tid; int m = e >> 7; int j = e & 127;
    at[j*36 + m] = (m0 + m < B_*TDEC) ? attnf[(m0 + m)*NH + j] : 0.f;
  }
  for (int i = 0; i < 32; ++i){
    int e = i*256 + tid; int cl = e >> 7; int j = e & 127;
    int n = n0 + cl;
    wt[j*68 + cl] = (n < NCLS) ? fcw[n*NH + j] : 0.f;
  }
  if (tid < 64) bsh[tid] = (n0 + tid < NCLS) ? fcb[n0 + tid] : 0.f;
  __syncthreads();
  int tn = tid & 15, tm = tid >> 4;
  float acc[2][4] = {{0.f,0.f,0.f,0.f},{0.f,0.f,0.f,0.f}};
  for (int j = 0; j < 128; ++j){
    float2 av = *(const float2*)(at + j*36 + tm*2);
    float4 wv = *(const float4*)(wt + j*68 + tn*4);
    acc[0][0] += av.x*wv.x; acc[0][1] += av.x*wv.y;
    acc[0][2] += av.x*wv.z; acc[0][3] += av.x*wv.w;
    acc[1][0] += av.y*wv.x; acc[1][1] += av.y*wv.y;
    acc[1][2] += av.y*wv.z; acc[1][3] += av.y*wv.w;
  }
  #pragma unroll
  for (int i = 0; i < 2; ++i){
    int m = m0 + tm*2 + i;
    if (m < B_*TDEC){
      #pragma unroll
      for (int ii = 0; ii < 4; ++ii){
        int n = n0 + tn*4 + ii;
        if (n < NCLS) out[m*NCLS + n] = acc[i][ii] + bsh[tn*4 + ii];
      }
    }
  }
}

// ============================================================================
extern "C" void kernel_launch(void* const* d_in, const int* in_sizes, int n_in,
                              void* d_out, int out_size, void* d_ws, size_t ws_size,
                              hipStream_t stream)
{
  (void)in_sizes; (void)n_in; (void)out_size; (void)ws_size;
  const float* x      = (const float*)d_in[0];
  const int*   tgt    = (const int*)  d_in[1];
  const float* conv0w = (const float*)d_in[2];
  const float* conv0b = (const float*)d_in[3];
  const float* bn0g   = (const float*)d_in[4];
  const float* bn0b   = (const float*)d_in[5];
  const float* bn0m   = (const float*)d_in[6];
  const float* bn0v   = (const float*)d_in[7];
  const float* dww    = (const float*)d_in[8];
  const float* dwb    = (const float*)d_in[9];
  const float* bn1g   = (const float*)d_in[10];
  const float* bn1b   = (const float*)d_in[11];
  const float* bn1m   = (const float*)d_in[12];
  const float* bn1v   = (const float*)d_in[13];
  const float* pww    = (const float*)d_in[14];
  const float* pwb    = (const float*)d_in[15];
  const float* bn2g   = (const float*)d_in[16];
  const float* bn2b   = (const float*)d_in[17];
  const float* bn2m   = (const float*)d_in[18];
  const float* bn2v   = (const float*)d_in[19];
  const float* encwih = (const float*)d_in[20];
  const float* encwhh = (const float*)d_in[21];
  const float* encbih = (const float*)d_in[22];
  const float* encbhh = (const float*)d_in[23];
  const float* decwih = (const float*)d_in[24];
  const float* decwhh = (const float*)d_in[25];
  const float* decbih = (const float*)d_in[26];
  const float* decbhh = (const float*)d_in[27];
  const float* emb    = (const float*)d_in[28];
  const float* qw     = (const float*)d_in[29];
  const float* qb0    = (const float*)d_in[30];
  const float* kw     = (const float*)d_in[31];
  const float* kb     = (const float*)d_in[32];
  const float* ew     = (const float*)d_in[33];
  const float* eb     = (const float*)d_in[34];
  const float* fcw    = (const float*)d_in[35];
  const float* fcb    = (const float*)d_in[36];

  float* ws    = (float*)d_ws;
  float* hbuf  = ws + 0;         // 2097152
  float* tbuf  = ws + 2097152;   // 2097152 (t; later: ebuf [0,671744) + kwA)
  float* feat  = ws + 4194304;   // 2097152
  float* xp    = ws + 6291456;   // 393216
  float* indec = ws + 6684672;   // 41984
  float* xpd   = ws + 6726656;   // 125952
  float* ybuf  = ws + 6852608;   // 41984
  float* qbuf  = ws + 6894592;   // 83968
  float* attf  = ws + 6978560;   // 83968
  float* pwT   = ws + 7062528;   // 16384
  float* kbuf  = hbuf;           // alias: h dead after k_dw
  float* ebuf  = tbuf;           // alias: t dead after k_pw (671744 floats)
  _Float16* kwA = (_Float16*)(tbuf + 1048576); // 147456 halves, inside dead tbuf
  float* out   = (float*)d_out;

  hipLaunchKernelGGL(k_pwT,     dim3(64),          dim3(256), 0, stream, pww, pwT);
  hipLaunchKernelGGL(k_conv0,   dim3(2048),        dim3(256), 0, stream,
                     x, conv0w, conv0b, bn0g, bn0b, bn0m, bn0v, hbuf);
  hipLaunchKernelGGL(k_dw,      dim3(8192),        dim3(256), 0, stream,
                     hbuf, dww, dwb, bn1g, bn1b, bn1m, bn1v, tbuf);
  hipLaunchKernelGGL(k_pw,      dim3(256),         dim3(512), 0, stream,
                     tbuf, pwT, pwb, bn2g, bn2b, bn2m, bn2v, feat);
  hipLaunchKernelGGL(k_wprep,   dim3(576),         dim3(256), 0, stream, kw, kwA);
  hipLaunchKernelGGL(k_embed,   dim3(160),         dim3(256), 0, stream, tgt, emb, indec);
  hipLaunchKernelGGL(k_encxp,   dim3(64, 4),       dim3(256), 0, stream,
                     feat, encwih, encbih, xp);
  hipLaunchKernelGGL(k_encscan, dim3(16),          dim3(192), 0, stream,
                     xp, encwhh, encbhh, indec);
  hipLaunchKernelGGL(k_xpd,     dim3(492),         dim3(256), 0, stream,
                     indec, decwih, decbih, xpd);
  hipLaunchKernelGGL(k_decscan, dim3(16),          dim3(192), 0, stream,
                     xpd, decwhh, decbhh, ybuf);
  hipLaunchKernelGGL(k_q,       dim3(328),         dim3(256), 0, stream,
                     ybuf, qw, qb0, qbuf);
  hipLaunchKernelGGL(k_kconv2,  dim3(256),         dim3(256), 0, stream,
                     feat, kwA, kb, kbuf);
  hipLaunchKernelGGL(k_e,       dim3(B_*TDEC),     dim3(256), 0, stream,
                     kbuf, qbuf, ew, eb, ebuf);
  hipLaunchKernelGGL(k_softmax, dim3(B_*TDEC),     dim3(256), 0, stream, ebuf);
  hipLaunchKernelGGL(k_attnf,   dim3(352),         dim3(256), 0, stream,
                     feat, ebuf, attf);
  hipLaunchKernelGGL(k_fc,      dim3(104, 21),     dim3(256), 0, stream,
                     attf, fcw, fcb, out);
}

// Round 3
// 414.893 us; speedup vs baseline: 1.2251x; 1.0971x over previous
//
#include <hip/hip_runtime.h>
#include <hip/hip_bf16.h>

#define DEV __device__ __forceinline__

#define B_    16
#define T_    40
#define TDEC  41
#define NH    128
#define HF    8
#define WF    128
#define HID   64
#define G3    192
#define NCLS  6625
#define SPAT  1024

typedef _Float16 half8 __attribute__((ext_vector_type(8)));
typedef float    f32x4 __attribute__((ext_vector_type(4)));
typedef float    f32x2 __attribute__((ext_vector_type(2)));

DEV float sigmoidf_(float x){ return 1.0f/(1.0f + __expf(-x)); }
DEV float tanhf_(float x){ float e = __expf(2.0f*x); return 1.0f - 2.0f/(e + 1.0f); }
DEV float gelu_(float x){ return 0.5f*x*(1.0f + erff(x*0.70710678118654752f)); }
DEV float bnf_(float x, float g, float b, float m, float v){
  return (x - m)*rsqrtf(v + 1e-5f)*g + b;
}

// ---------------- conv0 4x4 s4 + BN + GELU -> h (16,128,8,128) ----------------
__global__ __launch_bounds__(256) void k_conv0(const float* __restrict__ x,
    const float* __restrict__ w, const float* __restrict__ bias,
    const float* __restrict__ bng, const float* __restrict__ bnb,
    const float* __restrict__ bnm, const float* __restrict__ bnv,
    float* __restrict__ h)
{
  int tid = blockIdx.x*256 + threadIdx.x;   // 524288 threads, 4 co each
  int ow = tid & 127;
  int oh = (tid >> 7) & 7;
  int c4 = (tid >> 10) & 31;
  int b  = tid >> 15;
  float acc[4] = {0.f,0.f,0.f,0.f};
  int xbase = ((b*3)*32 + oh*4)*512 + ow*4;
  for (int ci = 0; ci < 3; ++ci){
    #pragma unroll
    for (int kh = 0; kh < 4; ++kh){
      float4 xv = *(const float4*)(x + xbase + ci*(32*512) + kh*512);
      #pragma unroll
      for (int cc = 0; cc < 4; ++cc){
        int co = c4*4 + cc;
        const float* wp = w + ((co*3 + ci)*4 + kh)*4;
        acc[cc] += xv.x*wp[0] + xv.y*wp[1] + xv.z*wp[2] + xv.w*wp[3];
      }
    }
  }
  #pragma unroll
  for (int cc = 0; cc < 4; ++cc){
    int co = c4*4 + cc;
    float v = acc[cc] + bias[co];
    v = bnf_(v, bng[co], bnb[co], bnm[co], bnv[co]);
    h[((b*NH + co)*HF + oh)*WF + ow] = gelu_(v);
  }
}

// ---------------- depthwise 3x3 (blk idx 1) + BN + GELU + residual -> t -------
__global__ __launch_bounds__(256) void k_dw(const float* __restrict__ h,
    const float* __restrict__ dww, const float* __restrict__ dwb,
    const float* __restrict__ g1, const float* __restrict__ b1,
    const float* __restrict__ m1, const float* __restrict__ v1,
    float* __restrict__ t)
{
  int tid = blockIdx.x*256 + threadIdx.x;   // 2097152
  int ow = tid & 127;
  int oh = (tid >> 7) & 7;
  int c  = (tid >> 10) & 127;
  int b  = tid >> 17;
  const float* wp = dww + NH*9 + c*9;       // block index 1
  const float* hp = h + ((b*NH + c)*HF)*WF;
  float acc = 0.f;
  #pragma unroll
  for (int kh = 0; kh < 3; ++kh){
    int ih = oh + kh - 1;
    if (ih < 0 || ih >= HF) continue;
    #pragma unroll
    for (int kw = 0; kw < 3; ++kw){
      int iw = ow + kw - 1;
      if (iw < 0 || iw >= WF) continue;
      acc += hp[ih*WF + iw]*wp[kh*3 + kw];
    }
  }
  float val = acc + dwb[NH + c];
  val = bnf_(val, g1[NH + c], b1[NH + c], m1[NH + c], v1[NH + c]);
  t[tid] = hp[oh*WF + ow] + gelu_(val);
}

// ---------------- transpose pw weights: pwT[ci][co] = pw[1][co][ci] ----------
__global__ void k_pwT(const float* __restrict__ pw, float* __restrict__ pwT){
  int tid = blockIdx.x*256 + threadIdx.x;   // 16384
  int ci = tid & 127; int co = tid >> 7;
  pwT[ci*128 + co] = pw[16384 + co*128 + ci];
}

// ---------------- pointwise 128x128 (blk idx 1) + BN + GELU -> feat ----------
__global__ __launch_bounds__(512) void k_pw(const float* __restrict__ t,
    const float* __restrict__ pwT, const float* __restrict__ pwb,
    const float* __restrict__ g2, const float* __restrict__ b2,
    const float* __restrict__ m2, const float* __restrict__ v2,
    float* __restrict__ feat)
{
  int bid = blockIdx.x;                     // (b, oh, whalf): 256 blocks
  int wh = bid & 1; int oh = (bid >> 1) & 7; int b = bid >> 4;
  int w0 = wh*64;
  int tid = threadIdx.x;
  __shared__ __align__(16) float tile[128*64];
  for (int i = 0; i < 16; ++i){
    int e = i*512 + tid; int ci = e >> 6; int wloc = e & 63;
    tile[ci*64 + wloc] = t[((b*NH + ci)*HF + oh)*WF + w0 + wloc];
  }
  __syncthreads();
  int co = tid & 127; int wq = tid >> 7;
  float acc[16];
  #pragma unroll
  for (int i = 0; i < 16; ++i) acc[i] = 0.f;
  for (int ci = 0; ci < 128; ++ci){
    float wt = pwT[ci*128 + co];
    const float4* tp = (const float4*)(tile + ci*64 + wq*16);
    #pragma unroll
    for (int j = 0; j < 4; ++j){
      float4 tv = tp[j];
      acc[j*4+0] += tv.x*wt; acc[j*4+1] += tv.y*wt;
      acc[j*4+2] += tv.z*wt; acc[j*4+3] += tv.w*wt;
    }
  }
  float bb = pwb[128 + co];
  float gg = g2[128 + co], bc = b2[128 + co], mm = m2[128 + co], vv = v2[128 + co];
  float* op = feat + ((b*NH + co)*HF + oh)*WF + w0 + wq*16;
  #pragma unroll
  for (int i = 0; i < 16; ++i){
    float v = bnf_(acc[i] + bb, gg, bc, mm, vv);
    op[i] = gelu_(v);
  }
}

// ---------------- enc xp GEMM: (2048x1024)@(192x1024)^T + bih -> xp ----------
__global__ __launch_bounds__(256) void k_encxp(const float* __restrict__ feat,
    const float* __restrict__ wih, const float* __restrict__ bih,
    float* __restrict__ xp)
{
  int m0 = blockIdx.x*32;     // 64 m-tiles
  int n0 = blockIdx.y*48;     // 4 n-tiles
  int b  = m0 >> 7;
  int w0 = m0 & 127;
  int tid = threadIdx.x;
  __shared__ float As[64*33];  // [k][m]
  __shared__ float Bs[64*49];  // [k][n]
  int tx = tid & 15, ty = tid >> 4;
  float acc[2][3] = {{0.f,0.f,0.f},{0.f,0.f,0.f}};
  for (int kt = 0; kt < 16; ++kt){
    int k0 = kt*64;
    #pragma unroll
    for (int i = 0; i < 8; ++i){
      int e = i*256 + tid; int kd = e >> 5; int mi = e & 31;
      int kg = k0 + kd;
      As[kd*33 + mi] = feat[((b*NH + (kg >> 3))*HF + (kg & 7))*WF + w0 + mi];
    }
    #pragma unroll
    for (int i = 0; i < 12; ++i){
      int e = i*256 + tid; int gi = e >> 6; int kd = e & 63;
      Bs[kd*49 + gi] = wih[(n0 + gi)*1024 + k0 + kd];
    }
    __syncthreads();
    for (int kd = 0; kd < 64; ++kd){
      float a0 = As[kd*33 + ty*2], a1 = As[kd*33 + ty*2 + 1];
      float b0 = Bs[kd*49 + tx*3], b1 = Bs[kd*49 + tx*3 + 1], b2 = Bs[kd*49 + tx*3 + 2];
      acc[0][0] += a0*b0; acc[0][1] += a0*b1; acc[0][2] += a0*b2;
      acc[1][0] += a1*b0; acc[1][1] += a1*b1; acc[1][2] += a1*b2;
    }
    __syncthreads();
  }
  #pragma unroll
  for (int i = 0; i < 2; ++i){
    int m = m0 + ty*2 + i;
    #pragma unroll
    for (int j = 0; j < 3; ++j){
      int g = n0 + tx*3 + j;
      xp[m*G3 + g] = acc[i][j] + bih[g];
    }
  }
}

// ---------------- GRU scan, single-wave per batch, weights in VGPRs ----------
// lane g holds whh rows {g, 64+g, 128+g}; h broadcast via 64-float LDS.
template<int STEPS, bool WRITE_ALL>
__global__ __launch_bounds__(64, 1) void k_scan(const float* __restrict__ xp,
    const float* __restrict__ whh, const float* __restrict__ bhh,
    float* __restrict__ outp)
{
  __shared__ float hsh[HID];
  int g = threadIdx.x;     // 0..63
  int b = blockIdx.x;
  f32x2 w0[32], w1[32], w2[32];
  const f32x2* p0 = (const f32x2*)(whh + g*HID);
  const f32x2* p1 = (const f32x2*)(whh + (HID + g)*HID);
  const f32x2* p2 = (const f32x2*)(whh + (2*HID + g)*HID);
  #pragma unroll
  for (int k = 0; k < 32; ++k){ w0[k] = p0[k]; w1[k] = p1[k]; w2[k] = p2[k]; }
  float b0 = bhh[g], b1 = bhh[HID + g], b2 = bhh[2*HID + g];
  float hg = 0.f;
  hsh[g] = 0.f;
  __syncthreads();
  const float* xpb = xp + b*STEPS*G3;
  float x0 = xpb[g], x1 = xpb[HID + g], x2 = xpb[2*HID + g];
  for (int t = 0; t < STEPS; ++t){
    float x0n = 0.f, x1n = 0.f, x2n = 0.f;
    if (t + 1 < STEPS){
      const float* p = xpb + (t + 1)*G3 + g;
      x0n = p[0]; x1n = p[HID]; x2n = p[2*HID];
    }
    f32x2 ar0{0.f,0.f}, ar1{0.f,0.f}, az0{0.f,0.f}, az1{0.f,0.f}, an0{0.f,0.f}, an1{0.f,0.f};
    const f32x2* h2 = (const f32x2*)hsh;
    #pragma unroll
    for (int k = 0; k < 32; k += 2){
      f32x2 hA = h2[k], hB = h2[k+1];
      ar0 += w0[k]*hA; ar1 += w0[k+1]*hB;
      az0 += w1[k]*hA; az1 += w1[k+1]*hB;
      an0 += w2[k]*hA; an1 += w2[k+1]*hB;
    }
    float hp0 = (ar0.x + ar0.y) + (ar1.x + ar1.y) + b0;
    float hp1 = (az0.x + az0.y) + (az1.x + az1.y) + b1;
    float hp2 = (an0.x + an0.y) + (an1.x + an1.y) + b2;
    float r = sigmoidf_(x0 + hp0);
    float z = sigmoidf_(x1 + hp1);
    float n = tanhf_(x2 + r*hp2);
    hg = (1.f - z)*n + z*hg;
    if (WRITE_ALL) outp[(b*TDEC + t)*HID + g] = hg;
    x0 = x0n; x1 = x1n; x2 = x2n;
    __syncthreads();
    hsh[g] = hg;
    __syncthreads();
  }
  if (!WRITE_ALL) outp[(b*TDEC)*HID + g] = hg;
}

// ---------------- embedding fill: indec rows 1..40 ---------------------------
__global__ void k_embed(const int* __restrict__ tgt, const float* __restrict__ emb,
                        float* __restrict__ indec)
{
  int tid = blockIdx.x*256 + threadIdx.x;   // 40960
  if (tid >= B_*T_*HID) return;
  int j = tid & 63; int rest = tid >> 6;
  int t = rest % T_; int b = rest / T_;
  int cls = tgt[b*T_ + t];
  indec[(b*TDEC + 1 + t)*HID + j] = emb[cls*HID + j];
}

// ---------------- dec xp: (656x64)@(192x64)^T + bih --------------------------
__global__ void k_xpd(const float* __restrict__ indec, const float* __restrict__ wih,
                      const float* __restrict__ bih, float* __restrict__ xpd)
{
  int tid = blockIdx.x*256 + threadIdx.x;   // 125952
  if (tid >= B_*TDEC*G3) return;
  int g = tid % G3; int bt = tid / G3;
  const float4* r4 = (const float4*)(indec + bt*HID);
  const float4* w4 = (const float4*)(wih + g*HID);
  float acc = bih[g];
  #pragma unroll
  for (int j = 0; j < 16; ++j){
    float4 rv = r4[j], wv = w4[j];
    acc += rv.x*wv.x + rv.y*wv.y + rv.z*wv.z + rv.w*wv.w;
  }
  xpd[tid] = acc;
}

// ---------------- q = y @ q_w^T + q_b ---------------------------------------
__global__ void k_q(const float* __restrict__ y, const float* __restrict__ qw,
                    const float* __restrict__ qb0, float* __restrict__ q)
{
  int tid = blockIdx.x*256 + threadIdx.x;   // 83968
  if (tid >= B_*TDEC*NH) return;
  int co = tid & 127; int bt = tid >> 7;
  const float4* r4 = (const float4*)(y + bt*HID);
  const float4* w4 = (const float4*)(qw + co*HID);
  float acc = qb0[co];
  #pragma unroll
  for (int j = 0; j < 16; ++j){
    float4 rv = r4[j], wv = w4[j];
    acc += rv.x*wv.x + rv.y*wv.y + rv.z*wv.z + rv.w*wv.w;
  }
  q[tid] = acc;
}

// ---------------- k-conv weight prep: fragment-ordered fp16 A ---------------
__global__ void k_wprep(const float* __restrict__ kw, _Float16* __restrict__ kwA)
{
  int tid = blockIdx.x*256 + threadIdx.x;   // 147456
  if (tid >= 36*8*64*8) return;
  int j = tid & 7;
  int l = (tid >> 3) & 63;
  int f = (tid >> 9) & 7;
  int s = tid >> 12;
  int co = f*16 + (l & 15);
  int k  = s*32 + ((l >> 4) << 3) + j;
  int r  = k >> 7;
  int ci = k & 127;
  kwA[tid] = (_Float16)kw[(co*128 + ci)*9 + r];
}

// ---------------- k conv 3x3 pad 1 via fp16 MFMA implicit GEMM --------------
__global__ __launch_bounds__(256) void k_kconv2(const float* __restrict__ feat,
    const _Float16* __restrict__ kwA, const float* __restrict__ kb,
    float* __restrict__ ko)
{
  int bid = blockIdx.x;                     // (b, oh, wq): 256 blocks
  int wq = bid & 1; int oh = (bid >> 1) & 7; int b = bid >> 4;
  int w0 = wq*64;
  int tid = threadIdx.x;
  int l  = tid & 63;
  int wv = tid >> 6;

  __shared__ _Float16 Alds[4096];   // 8 co-frags x 64 lanes x 8
  __shared__ _Float16 Blds[2048];   // 4 m-frags  x 64 lanes x 8

  f32x4 acc[2][4];
  #pragma unroll
  for (int i = 0; i < 2; ++i)
    #pragma unroll
    for (int n = 0; n < 4; ++n)
      acc[i][n] = (f32x4){0.f,0.f,0.f,0.f};

  int u  = tid & 63;
  int c0 = (tid >> 6)*8;
  int bl  = ((c0 >> 3) << 4) + (u & 15);
  int bnf = u >> 4;
  int bdst = (bnf*64 + bl)*8;

  float bv[8];
  uint4 av0, av1;

  const uint4* kwA4 = (const uint4*)kwA;

  #define ISSUE_A(s) { av0 = kwA4[(s)*512 + tid]; av1 = kwA4[(s)*512 + tid + 256]; }
  #define ISSUE_B(s) {                                                        \
    int r = (s) >> 2; int ci0 = ((s) & 3) << 5;                               \
    int dh = r/3 - 1, dw2 = r%3 - 1;                                          \
    int ih = oh + dh;                                                         \
    int iw = w0 + u + dw2;                                                    \
    bool ok = (ih >= 0) & (ih < HF) & (iw >= 0) & (iw < WF);                  \
    const float* fp = feat + ((b*NH + ci0 + c0)*HF + ih)*WF + iw;             \
    _Pragma("unroll")                                                         \
    for (int jj = 0; jj < 8; ++jj) bv[jj] = ok ? fp[jj*(HF*WF)] : 0.f;        \
  }
  #define COMMIT() {                                                          \
    ((uint4*)Alds)[tid] = av0; ((uint4*)Alds)[tid + 256] = av1;               \
    half8 hb;                                                                 \
    _Pragma("unroll")                                                         \
    for (int jj = 0; jj < 8; ++jj) hb[jj] = (_Float16)bv[jj];                 \
    *(half8*)(Blds + bdst) = hb;                                              \
  }

  ISSUE_A(0); ISSUE_B(0);
  COMMIT();
  __syncthreads();

  for (int s = 0; s < 36; ++s){
    if (s < 35){ ISSUE_A(s+1); ISSUE_B(s+1); }
    half8 af[2], bf[4];
    #pragma unroll
    for (int i = 0; i < 2; ++i)
      af[i] = *(const half8*)(Alds + ((wv*2 + i)*64 + l)*8);
    #pragma unroll
    for (int n = 0; n < 4; ++n)
      bf[n] = *(const half8*)(Blds + (n*64 + l)*8);
    #pragma unroll
    for (int i = 0; i < 2; ++i)
      #pragma unroll
      for (int n = 0; n < 4; ++n)
        acc[i][n] = __builtin_amdgcn_mfma_f32_16x16x32_f16(af[i], bf[n], acc[i][n], 0, 0, 0);
    __syncthreads();
    if (s < 35){ COMMIT(); __syncthreads(); }
  }

  #pragma unroll
  for (int i = 0; i < 2; ++i){
    int cobase = (wv*2 + i)*16 + ((l >> 4) << 2);
    #pragma unroll
    for (int q = 0; q < 4; ++q){
      int co = cobase + q;
      float bias = kb[co];
      float* op = ko + ((b*NH + co)*HF + oh)*WF + w0 + (l & 15);
      #pragma unroll
      for (int n = 0; n < 4; ++n)
        op[n*16] = acc[i][n][q] + bias;
    }
  }
  #undef ISSUE_A
  #undef ISSUE_B
  #undef COMMIT
}

// ---------------- e[b,t,s] = sum_c e_w[c]*tanh(k[b,c,s] + q[b,t,c]) + e_b ----
__global__ __launch_bounds__(256) void k_e(const float* __restrict__ k,
    const float* __restrict__ q, const float* __restrict__ ew,
    const float* __restrict__ eb, float* __restrict__ e)
{
  int bt = blockIdx.x;
  int b = bt / TDEC;
  int tid = threadIdx.x;
  __shared__ float qs[NH];
  if (tid < NH) qs[tid] = q[bt*NH + tid];
  __syncthreads();
  float ebv = eb[0];
  float acc[4] = {ebv, ebv, ebv, ebv};
  for (int c = 0; c < NH; ++c){
    float ewc = ew[c];
    float qc = qs[c];
    const float* kp = k + (b*NH + c)*SPAT;
    #pragma unroll
    for (int i = 0; i < 4; ++i)
      acc[i] += ewc*tanhf_(kp[tid + i*256] + qc);
  }
  #pragma unroll
  for (int i = 0; i < 4; ++i)
    e[bt*SPAT + tid + i*256] = acc[i];
}

// ---------------- softmax over 1024 per (b,t), in-place ----------------------
__global__ __launch_bounds__(256) void k_softmax(float* __restrict__ e)
{
  int bt = blockIdx.x; int tid = threadIdx.x;
  float* row = e + bt*SPAT;
  __shared__ float red[256];
  float v[4];
  #pragma unroll
  for (int i = 0; i < 4; ++i) v[i] = row[tid + i*256];
  float m = fmaxf(fmaxf(v[0], v[1]), fmaxf(v[2], v[3]));
  red[tid] = m; __syncthreads();
  for (int s = 128; s > 0; s >>= 1){
    if (tid < s) red[tid] = fmaxf(red[tid], red[tid + s]);
    __syncthreads();
  }
  float mx = red[0];
  __syncthreads();
  float ev[4]; float sum = 0.f;
  #pragma unroll
  for (int i = 0; i < 4; ++i){ ev[i] = __expf(v[i] - mx); sum += ev[i]; }
  red[tid] = sum; __syncthreads();
  for (int s = 128; s > 0; s >>= 1){
    if (tid < s) red[tid] += red[tid + s];
    __syncthreads();
  }
  float inv = 1.f/red[0];
  #pragma unroll
  for (int i = 0; i < 4; ++i) row[tid + i*256] = ev[i]*inv;
}

// ---------------- attn_feat[b,t,c] = sum_s feat[b,c,s]*a[b,t,s] --------------
__global__ __launch_bounds__(256) void k_attnf(const float* __restrict__ feat,
    const float* __restrict__ a, float* __restrict__ attnf)
{
  int bid = blockIdx.x;                  // (b, tq(11), ch(2)): 352 blocks
  int ch = bid & 1; int rest = bid >> 1;
  int tq = rest % 11; int b = rest / 11;
  int tid = threadIdx.x;
  __shared__ __align__(16) float ash[4*SPAT];
  __shared__ float psh[4*4*64];
  for (int i = 0; i < 16; ++i){
    int e = i*256 + tid; int tt = e >> 10; int s = e & 1023;
    int t = tq*4 + tt;
    ash[e] = (t < TDEC) ? a[(b*TDEC + t)*SPAT + s] : 0.f;
  }
  __syncthreads();
  int cl = tid & 63; int sq = tid >> 6;
  const float* fp = feat + (b*NH + ch*64 + cl)*SPAT + sq*256;
  float acc[4] = {0.f,0.f,0.f,0.f};
  for (int i = 0; i < 64; ++i){
    float4 fv = *(const float4*)(fp + i*4);
    #pragma unroll
    for (int tt = 0; tt < 4; ++tt){
      const float* ar = ash + tt*SPAT + sq*256 + i*4;
      acc[tt] += fv.x*ar[0] + fv.y*ar[1] + fv.z*ar[2] + fv.w*ar[3];
    }
  }
  #pragma unroll
  for (int tt = 0; tt < 4; ++tt) psh[(sq*4 + tt)*64 + cl] = acc[tt];
  __syncthreads();
  {
    int tt = tid >> 6; int c2 = tid & 63;
    int t = tq*4 + tt;
    if (t < TDEC){
      float v = psh[(0*4 + tt)*64 + c2] + psh[(1*4 + tt)*64 + c2]
              + psh[(2*4 + tt)*64 + c2] + psh[(3*4 + tt)*64 + c2];
      attnf[(b*TDEC + t)*NH + ch*64 + c2] = v;
    }
  }
}

// ---------------- out = attnf @ fc_w^T + fc_b --------------------------------
__global__ __launch_bounds__(256) void k_fc(const float* __restrict__ attnf,
    const float* __restrict__ fcw, const float* __restrict__ fcb,
    float* __restrict__ out)
{
  int n0 = blockIdx.x*64;   // 104 cls-tiles
  int m0 = blockIdx.y*32;   // 21 m-tiles
  int tid = threadIdx.x;
  __shared__ __align__(16) float at[128*36];   // [j][m]
  __shared__ __align__(16) float wt[128*68];   // [j][cls]
  __shared__ float bsh[64];
  for (int i = 0; i < 16; ++i){
    int e = i*256 + tid; int m = e >> 7; int j = e & 127;
    at[j*36 + m] = (m0 + m < B_*TDEC) ? attnf[(m0 + m)*NH + j] : 0.f;
  }
  for (int i = 0; i < 32; ++i){
    int e = i*256 + tid; int cl = e >> 7; int j = e & 127;
    int n = n0 + cl;
    wt[j*68 + cl] = (n < NCLS) ? fcw[n*NH + j] : 0.f;
  }
  if (tid < 64) bsh[tid] = (n0 + tid < NCLS) ? fcb[n0 + tid] : 0.f;
  __syncthreads();
  int tn = tid & 15, tm = tid >> 4;
  float acc[2][4] = {{0.f,0.f,0.f,0.f},{0.f,0.f,0.f,0.f}};
  for (int j = 0; j < 128; ++j){
    float2 av = *(const float2*)(at + j*36 + tm*2);
    float4 wv = *(const float4*)(wt + j*68 + tn*4);
    acc[0][0] += av.x*wv.x; acc[0][1] += av.x*wv.y;
    acc[0][2] += av.x*wv.z; acc[0][3] += av.x*wv.w;
    acc[1][0] += av.y*wv.x; acc[1][1] += av.y*wv.y;
    acc[1][2] += av.y*wv.z; acc[1][3] += av.y*wv.w;
  }
  #pragma unroll
  for (int i = 0; i < 2; ++i){
    int m = m0 + tm*2 + i;
    if (m < B_*TDEC){
      #pragma unroll
      for (int ii = 0; ii < 4; ++ii){
        int n = n0 + tn*4 + ii;
        if (n < NCLS) out[m*NCLS + n] = acc[i][ii] + bsh[tn*4 + ii];
      }
    }
  }
}

// ============================================================================
extern "C" void kernel_launch(void* const* d_in, const int* in_sizes, int n_in,
                              void* d_out, int out_size, void* d_ws, size_t ws_size,
                              hipStream_t stream)
{
  (void)in_sizes; (void)n_in; (void)out_size; (void)ws_size;
  const float* x      = (const float*)d_in[0];
  const int*   tgt    = (const int*)  d_in[1];
  const float* conv0w = (const float*)d_in[2];
  const float* conv0b = (const float*)d_in[3];
  const float* bn0g   = (const float*)d_in[4];
  const float* bn0b   = (const float*)d_in[5];
  const float* bn0m   = (const float*)d_in[6];
  const float* bn0v   = (const float*)d_in[7];
  const float* dww    = (const float*)d_in[8];
  const float* dwb    = (const float*)d_in[9];
  const float* bn1g   = (const float*)d_in[10];
  const float* bn1b   = (const float*)d_in[11];
  const float* bn1m   = (const float*)d_in[12];
  const float* bn1v   = (const float*)d_in[13];
  const float* pww    = (const float*)d_in[14];
  const float* pwb    = (const float*)d_in[15];
  const float* bn2g   = (const float*)d_in[16];
  const float* bn2b   = (const float*)d_in[17];
  const float* bn2m   = (const float*)d_in[18];
  const float* bn2v   = (const float*)d_in[19];
  const float* encwih = (const float*)d_in[20];
  const float* encwhh = (const float*)d_in[21];
  const float* encbih = (const float*)d_in[22];
  const float* encbhh = (const float*)d_in[23];
  const float* decwih = (const float*)d_in[24];
  const float* decwhh = (const float*)d_in[25];
  const float* decbih = (const float*)d_in[26];
  const float* decbhh = (const float*)d_in[27];
  const float* emb    = (const float*)d_in[28];
  const float* qw     = (const float*)d_in[29];
  const float* qb0    = (const float*)d_in[30];
  const float* kw     = (const float*)d_in[31];
  const float* kb     = (const float*)d_in[32];
  const float* ew     = (const float*)d_in[33];
  const float* eb     = (const float*)d_in[34];
  const float* fcw    = (const float*)d_in[35];
  const float* fcb    = (const float*)d_in[36];

  float* ws    = (float*)d_ws;
  float* hbuf  = ws + 0;         // 2097152
  float* tbuf  = ws + 2097152;   // 2097152 (t; later: ebuf + kwA)
  float* feat  = ws + 4194304;   // 2097152
  float* xp    = ws + 6291456;   // 393216
  float* indec = ws + 6684672;   // 41984
  float* xpd   = ws + 6726656;   // 125952
  float* ybuf  = ws + 6852608;   // 41984
  float* qbuf  = ws + 6894592;   // 83968
  float* attf  = ws + 6978560;   // 83968
  float* pwT   = ws + 7062528;   // 16384
  float* kbuf  = hbuf;           // alias: h dead after k_dw
  float* ebuf  = tbuf;           // alias: t dead after k_pw (671744 floats)
  _Float16* kwA = (_Float16*)(tbuf + 1048576); // 147456 halves, inside dead tbuf
  float* out   = (float*)d_out;

  hipLaunchKernelGGL(k_pwT,     dim3(64),          dim3(256), 0, stream, pww, pwT);
  hipLaunchKernelGGL(k_conv0,   dim3(2048),        dim3(256), 0, stream,
                     x, conv0w, conv0b, bn0g, bn0b, bn0m, bn0v, hbuf);
  hipLaunchKernelGGL(k_dw,      dim3(8192),        dim3(256), 0, stream,
                     hbuf, dww, dwb, bn1g, bn1b, bn1m, bn1v, tbuf);
  hipLaunchKernelGGL(k_pw,      dim3(256),         dim3(512), 0, stream,
                     tbuf, pwT, pwb, bn2g, bn2b, bn2m, bn2v, feat);
  hipLaunchKernelGGL(k_wprep,   dim3(576),         dim3(256), 0, stream, kw, kwA);
  hipLaunchKernelGGL(k_embed,   dim3(160),         dim3(256), 0, stream, tgt, emb, indec);
  hipLaunchKernelGGL(k_encxp,   dim3(64, 4),       dim3(256), 0, stream,
                     feat, encwih, encbih, xp);
  hipLaunchKernelGGL((k_scan<128,false>), dim3(16), dim3(64), 0, stream,
                     xp, encwhh, encbhh, indec);
  hipLaunchKernelGGL(k_xpd,     dim3(492),         dim3(256), 0, stream,
                     indec, decwih, decbih, xpd);
  hipLaunchKernelGGL((k_scan<TDEC,true>), dim3(16), dim3(64), 0, stream,
                     xpd, decwhh, decbhh, ybuf);
  hipLaunchKernelGGL(k_q,       dim3(328),         dim3(256), 0, stream,
                     ybuf, qw, qb0, qbuf);
  hipLaunchKernelGGL(k_kconv2,  dim3(256),         dim3(256), 0, stream,
                     feat, kwA, kb, kbuf);
  hipLaunchKernelGGL(k_e,       dim3(B_*TDEC),     dim3(256), 0, stream,
                     kbuf, qbuf, ew, eb, ebuf);
  hipLaunchKernelGGL(k_softmax, dim3(B_*TDEC),     dim3(256), 0, stream, ebuf);
  hipLaunchKernelGGL(k_attnf,   dim3(352),         dim3(256), 0, stream,
                     feat, ebuf, attf);
  hipLaunchKernelGGL(k_fc,      dim3(104, 21),     dim3(256), 0, stream,
                     attf, fcw, fcb, out);
}

// Round 4
// 388.514 us; speedup vs baseline: 1.3083x; 1.0679x over previous
//
#include <hip/hip_runtime.h>
#include <hip/hip_bf16.h>

#define DEV __device__ __forceinline__

#define B_    16
#define T_    40
#define TDEC  41
#define NH    128
#define HF    8
#define WF    128
#define HID   64
#define G3    192
#define NCLS  6625
#define SPAT  1024

typedef _Float16 half8 __attribute__((ext_vector_type(8)));
typedef float    f32x4 __attribute__((ext_vector_type(4)));
typedef float    f32x2 __attribute__((ext_vector_type(2)));

DEV float sigmoidf_(float x){ return 1.0f/(1.0f + __expf(-x)); }
DEV float tanhf_(float x){ float e = __expf(2.0f*x); return 1.0f - 2.0f/(e + 1.0f); }
DEV float gelu_(float x){ return 0.5f*x*(1.0f + erff(x*0.70710678118654752f)); }
DEV float bnf_(float x, float g, float b, float m, float v){
  return (x - m)*rsqrtf(v + 1e-5f)*g + b;
}

// ---------------- conv0 4x4 s4 + BN + GELU -> h (16,128,8,128) ----------------
__global__ __launch_bounds__(256) void k_conv0(const float* __restrict__ x,
    const float* __restrict__ w, const float* __restrict__ bias,
    const float* __restrict__ bng, const float* __restrict__ bnb,
    const float* __restrict__ bnm, const float* __restrict__ bnv,
    float* __restrict__ h)
{
  int tid = blockIdx.x*256 + threadIdx.x;   // 524288 threads, 4 co each
  int ow = tid & 127;
  int oh = (tid >> 7) & 7;
  int c4 = (tid >> 10) & 31;
  int b  = tid >> 15;
  float acc[4] = {0.f,0.f,0.f,0.f};
  int xbase = ((b*3)*32 + oh*4)*512 + ow*4;
  for (int ci = 0; ci < 3; ++ci){
    #pragma unroll
    for (int kh = 0; kh < 4; ++kh){
      float4 xv = *(const float4*)(x + xbase + ci*(32*512) + kh*512);
      #pragma unroll
      for (int cc = 0; cc < 4; ++cc){
        int co = c4*4 + cc;
        const float* wp = w + ((co*3 + ci)*4 + kh)*4;
        acc[cc] += xv.x*wp[0] + xv.y*wp[1] + xv.z*wp[2] + xv.w*wp[3];
      }
    }
  }
  #pragma unroll
  for (int cc = 0; cc < 4; ++cc){
    int co = c4*4 + cc;
    float v = acc[cc] + bias[co];
    v = bnf_(v, bng[co], bnb[co], bnm[co], bnv[co]);
    h[((b*NH + co)*HF + oh)*WF + ow] = gelu_(v);
  }
}

// ---------------- depthwise 3x3 (blk idx 1) + BN + GELU + residual -> t -------
__global__ __launch_bounds__(256) void k_dw(const float* __restrict__ h,
    const float* __restrict__ dww, const float* __restrict__ dwb,
    const float* __restrict__ g1, const float* __restrict__ b1,
    const float* __restrict__ m1, const float* __restrict__ v1,
    float* __restrict__ t)
{
  int tid = blockIdx.x*256 + threadIdx.x;   // 2097152
  int ow = tid & 127;
  int oh = (tid >> 7) & 7;
  int c  = (tid >> 10) & 127;
  int b  = tid >> 17;
  const float* wp = dww + NH*9 + c*9;       // block index 1
  const float* hp = h + ((b*NH + c)*HF)*WF;
  float acc = 0.f;
  #pragma unroll
  for (int kh = 0; kh < 3; ++kh){
    int ih = oh + kh - 1;
    if (ih < 0 || ih >= HF) continue;
    #pragma unroll
    for (int kw = 0; kw < 3; ++kw){
      int iw = ow + kw - 1;
      if (iw < 0 || iw >= WF) continue;
      acc += hp[ih*WF + iw]*wp[kh*3 + kw];
    }
  }
  float val = acc + dwb[NH + c];
  val = bnf_(val, g1[NH + c], b1[NH + c], m1[NH + c], v1[NH + c]);
  t[tid] = hp[oh*WF + ow] + gelu_(val);
}

// ---------------- transpose pw weights: pwT[ci][co] = pw[1][co][ci] ----------
__global__ void k_pwT(const float* __restrict__ pw, float* __restrict__ pwT){
  int tid = blockIdx.x*256 + threadIdx.x;   // 16384
  int ci = tid & 127; int co = tid >> 7;
  pwT[ci*128 + co] = pw[16384 + co*128 + ci];
}

// ---------------- pointwise 128x128 (blk idx 1) + BN + GELU -> feat ----------
__global__ __launch_bounds__(512) void k_pw(const float* __restrict__ t,
    const float* __restrict__ pwT, const float* __restrict__ pwb,
    const float* __restrict__ g2, const float* __restrict__ b2,
    const float* __restrict__ m2, const float* __restrict__ v2,
    float* __restrict__ feat)
{
  int bid = blockIdx.x;                     // (b, oh, whalf): 256 blocks
  int wh = bid & 1; int oh = (bid >> 1) & 7; int b = bid >> 4;
  int w0 = wh*64;
  int tid = threadIdx.x;
  __shared__ __align__(16) float tile[128*64];
  for (int i = 0; i < 16; ++i){
    int e = i*512 + tid; int ci = e >> 6; int wloc = e & 63;
    tile[ci*64 + wloc] = t[((b*NH + ci)*HF + oh)*WF + w0 + wloc];
  }
  __syncthreads();
  int co = tid & 127; int wq = tid >> 7;
  float acc[16];
  #pragma unroll
  for (int i = 0; i < 16; ++i) acc[i] = 0.f;
  for (int ci = 0; ci < 128; ++ci){
    float wt = pwT[ci*128 + co];
    const float4* tp = (const float4*)(tile + ci*64 + wq*16);
    #pragma unroll
    for (int j = 0; j < 4; ++j){
      float4 tv = tp[j];
      acc[j*4+0] += tv.x*wt; acc[j*4+1] += tv.y*wt;
      acc[j*4+2] += tv.z*wt; acc[j*4+3] += tv.w*wt;
    }
  }
  float bb = pwb[128 + co];
  float gg = g2[128 + co], bc = b2[128 + co], mm = m2[128 + co], vv = v2[128 + co];
  float* op = feat + ((b*NH + co)*HF + oh)*WF + w0 + wq*16;
  #pragma unroll
  for (int i = 0; i < 16; ++i){
    float v = bnf_(acc[i] + bb, gg, bc, mm, vv);
    op[i] = gelu_(v);
  }
}

// ---------------- enc xp GEMM: (2048x1024)@(192x1024)^T + bih -> xp ----------
__global__ __launch_bounds__(256) void k_encxp(const float* __restrict__ feat,
    const float* __restrict__ wih, const float* __restrict__ bih,
    float* __restrict__ xp)
{
  int m0 = blockIdx.x*32;     // 64 m-tiles
  int n0 = blockIdx.y*48;     // 4 n-tiles
  int b  = m0 >> 7;
  int w0 = m0 & 127;
  int tid = threadIdx.x;
  __shared__ float As[64*33];  // [k][m]
  __shared__ float Bs[64*49];  // [k][n]
  int tx = tid & 15, ty = tid >> 4;
  float acc[2][3] = {{0.f,0.f,0.f},{0.f,0.f,0.f}};
  for (int kt = 0; kt < 16; ++kt){
    int k0 = kt*64;
    #pragma unroll
    for (int i = 0; i < 8; ++i){
      int e = i*256 + tid; int kd = e >> 5; int mi = e & 31;
      int kg = k0 + kd;
      As[kd*33 + mi] = feat[((b*NH + (kg >> 3))*HF + (kg & 7))*WF + w0 + mi];
    }
    #pragma unroll
    for (int i = 0; i < 12; ++i){
      int e = i*256 + tid; int gi = e >> 6; int kd = e & 63;
      Bs[kd*49 + gi] = wih[(n0 + gi)*1024 + k0 + kd];
    }
    __syncthreads();
    for (int kd = 0; kd < 64; ++kd){
      float a0 = As[kd*33 + ty*2], a1 = As[kd*33 + ty*2 + 1];
      float b0 = Bs[kd*49 + tx*3], b1 = Bs[kd*49 + tx*3 + 1], b2 = Bs[kd*49 + tx*3 + 2];
      acc[0][0] += a0*b0; acc[0][1] += a0*b1; acc[0][2] += a0*b2;
      acc[1][0] += a1*b0; acc[1][1] += a1*b1; acc[1][2] += a1*b2;
    }
    __syncthreads();
  }
  #pragma unroll
  for (int i = 0; i < 2; ++i){
    int m = m0 + ty*2 + i;
    #pragma unroll
    for (int j = 0; j < 3; ++j){
      int g = n0 + tx*3 + j;
      xp[m*G3 + g] = acc[i][j] + bih[g];
    }
  }
}

// ---------------- GRU scan, single-wave per batch, weights in VGPRs ----------
template<int STEPS, bool WRITE_ALL>
__global__ __launch_bounds__(64, 1) void k_scan(const float* __restrict__ xp,
    const float* __restrict__ whh, const float* __restrict__ bhh,
    float* __restrict__ outp)
{
  __shared__ float hsh[HID];
  int g = threadIdx.x;     // 0..63
  int b = blockIdx.x;
  f32x2 w0[32], w1[32], w2[32];
  const f32x2* p0 = (const f32x2*)(whh + g*HID);
  const f32x2* p1 = (const f32x2*)(whh + (HID + g)*HID);
  const f32x2* p2 = (const f32x2*)(whh + (2*HID + g)*HID);
  #pragma unroll
  for (int k = 0; k < 32; ++k){ w0[k] = p0[k]; w1[k] = p1[k]; w2[k] = p2[k]; }
  float b0 = bhh[g], b1 = bhh[HID + g], b2 = bhh[2*HID + g];
  float hg = 0.f;
  hsh[g] = 0.f;
  __syncthreads();
  const float* xpb = xp + b*STEPS*G3;
  float x0 = xpb[g], x1 = xpb[HID + g], x2 = xpb[2*HID + g];
  for (int t = 0; t < STEPS; ++t){
    float x0n = 0.f, x1n = 0.f, x2n = 0.f;
    if (t + 1 < STEPS){
      const float* p = xpb + (t + 1)*G3 + g;
      x0n = p[0]; x1n = p[HID]; x2n = p[2*HID];
    }
    f32x2 ar0{0.f,0.f}, ar1{0.f,0.f}, az0{0.f,0.f}, az1{0.f,0.f}, an0{0.f,0.f}, an1{0.f,0.f};
    const f32x2* h2 = (const f32x2*)hsh;
    #pragma unroll
    for (int k = 0; k < 32; k += 2){
      f32x2 hA = h2[k], hB = h2[k+1];
      ar0 += w0[k]*hA; ar1 += w0[k+1]*hB;
      az0 += w1[k]*hA; az1 += w1[k+1]*hB;
      an0 += w2[k]*hA; an1 += w2[k+1]*hB;
    }
    float hp0 = (ar0.x + ar0.y) + (ar1.x + ar1.y) + b0;
    float hp1 = (az0.x + az0.y) + (az1.x + az1.y) + b1;
    float hp2 = (an0.x + an0.y) + (an1.x + an1.y) + b2;
    float r = sigmoidf_(x0 + hp0);
    float z = sigmoidf_(x1 + hp1);
    float n = tanhf_(x2 + r*hp2);
    hg = (1.f - z)*n + z*hg;
    if (WRITE_ALL) outp[(b*TDEC + t)*HID + g] = hg;
    x0 = x0n; x1 = x1n; x2 = x2n;
    __syncthreads();
    hsh[g] = hg;
    __syncthreads();
  }
  if (!WRITE_ALL) outp[(b*TDEC)*HID + g] = hg;
}

// ---------------- embedding fill: indec rows 1..40 ---------------------------
__global__ void k_embed(const int* __restrict__ tgt, const float* __restrict__ emb,
                        float* __restrict__ indec)
{
  int tid = blockIdx.x*256 + threadIdx.x;   // 40960
  if (tid >= B_*T_*HID) return;
  int j = tid & 63; int rest = tid >> 6;
  int t = rest % T_; int b = rest / T_;
  int cls = tgt[b*T_ + t];
  indec[(b*TDEC + 1 + t)*HID + j] = emb[cls*HID + j];
}

// ---------------- dec xp: (656x64)@(192x64)^T + bih --------------------------
__global__ void k_xpd(const float* __restrict__ indec, const float* __restrict__ wih,
                      const float* __restrict__ bih, float* __restrict__ xpd)
{
  int tid = blockIdx.x*256 + threadIdx.x;   // 125952
  if (tid >= B_*TDEC*G3) return;
  int g = tid % G3; int bt = tid / G3;
  const float4* r4 = (const float4*)(indec + bt*HID);
  const float4* w4 = (const float4*)(wih + g*HID);
  float acc = bih[g];
  #pragma unroll
  for (int j = 0; j < 16; ++j){
    float4 rv = r4[j], wv = w4[j];
    acc += rv.x*wv.x + rv.y*wv.y + rv.z*wv.z + rv.w*wv.w;
  }
  xpd[tid] = acc;
}

// ---------------- q = y @ q_w^T + q_b ---------------------------------------
__global__ void k_q(const float* __restrict__ y, const float* __restrict__ qw,
                    const float* __restrict__ qb0, float* __restrict__ q)
{
  int tid = blockIdx.x*256 + threadIdx.x;   // 83968
  if (tid >= B_*TDEC*NH) return;
  int co = tid & 127; int bt = tid >> 7;
  const float4* r4 = (const float4*)(y + bt*HID);
  const float4* w4 = (const float4*)(qw + co*HID);
  float acc = qb0[co];
  #pragma unroll
  for (int j = 0; j < 16; ++j){
    float4 rv = r4[j], wv = w4[j];
    acc += rv.x*wv.x + rv.y*wv.y + rv.z*wv.z + rv.w*wv.w;
  }
  q[tid] = acc;
}

// ---------------- k-conv weight prep: fragment-ordered fp16 A ---------------
__global__ void k_wprep(const float* __restrict__ kw, _Float16* __restrict__ kwA)
{
  int tid = blockIdx.x*256 + threadIdx.x;   // 147456
  if (tid >= 36*8*64*8) return;
  int j = tid & 7;
  int l = (tid >> 3) & 63;
  int f = (tid >> 9) & 7;
  int s = tid >> 12;
  int co = f*16 + (l & 15);
  int k  = s*32 + ((l >> 4) << 3) + j;
  int r  = k >> 7;
  int ci = k & 127;
  kwA[tid] = (_Float16)kw[(co*128 + ci)*9 + r];
}

// ---------------- k conv 3x3 pad 1 via fp16 MFMA implicit GEMM --------------
__global__ __launch_bounds__(256) void k_kconv2(const float* __restrict__ feat,
    const _Float16* __restrict__ kwA, const float* __restrict__ kb,
    float* __restrict__ ko)
{
  int bid = blockIdx.x;                     // (b, oh, wq): 256 blocks
  int wq = bid & 1; int oh = (bid >> 1) & 7; int b = bid >> 4;
  int w0 = wq*64;
  int tid = threadIdx.x;
  int l  = tid & 63;
  int wv = tid >> 6;

  __shared__ _Float16 Alds[4096];   // 8 co-frags x 64 lanes x 8
  __shared__ _Float16 Blds[2048];   // 4 m-frags  x 64 lanes x 8

  f32x4 acc[2][4];
  #pragma unroll
  for (int i = 0; i < 2; ++i)
    #pragma unroll
    for (int n = 0; n < 4; ++n)
      acc[i][n] = (f32x4){0.f,0.f,0.f,0.f};

  int u  = tid & 63;
  int c0 = (tid >> 6)*8;
  int bl  = ((c0 >> 3) << 4) + (u & 15);
  int bnf = u >> 4;
  int bdst = (bnf*64 + bl)*8;

  float bv[8];
  uint4 av0, av1;

  const uint4* kwA4 = (const uint4*)kwA;

  #define ISSUE_A(s) { av0 = kwA4[(s)*512 + tid]; av1 = kwA4[(s)*512 + tid + 256]; }
  #define ISSUE_B(s) {                                                        \
    int r = (s) >> 2; int ci0 = ((s) & 3) << 5;                               \
    int dh = r/3 - 1, dw2 = r%3 - 1;                                          \
    int ih = oh + dh;                                                         \
    int iw = w0 + u + dw2;                                                    \
    bool ok = (ih >= 0) & (ih < HF) & (iw >= 0) & (iw < WF);                  \
    const float* fp = feat + ((b*NH + ci0 + c0)*HF + ih)*WF + iw;             \
    _Pragma("unroll")                                                         \
    for (int jj = 0; jj < 8; ++jj) bv[jj] = ok ? fp[jj*(HF*WF)] : 0.f;        \
  }
  #define COMMIT() {                                                          \
    ((uint4*)Alds)[tid] = av0; ((uint4*)Alds)[tid + 256] = av1;               \
    half8 hb;                                                                 \
    _Pragma("unroll")                                                         \
    for (int jj = 0; jj < 8; ++jj) hb[jj] = (_Float16)bv[jj];                 \
    *(half8*)(Blds + bdst) = hb;                                              \
  }

  ISSUE_A(0); ISSUE_B(0);
  COMMIT();
  __syncthreads();

  for (int s = 0; s < 36; ++s){
    if (s < 35){ ISSUE_A(s+1); ISSUE_B(s+1); }
    half8 af[2], bf[4];
    #pragma unroll
    for (int i = 0; i < 2; ++i)
      af[i] = *(const half8*)(Alds + ((wv*2 + i)*64 + l)*8);
    #pragma unroll
    for (int n = 0; n < 4; ++n)
      bf[n] = *(const half8*)(Blds + (n*64 + l)*8);
    #pragma unroll
    for (int i = 0; i < 2; ++i)
      #pragma unroll
      for (int n = 0; n < 4; ++n)
        acc[i][n] = __builtin_amdgcn_mfma_f32_16x16x32_f16(af[i], bf[n], acc[i][n], 0, 0, 0);
    __syncthreads();
    if (s < 35){ COMMIT(); __syncthreads(); }
  }

  #pragma unroll
  for (int i = 0; i < 2; ++i){
    int cobase = (wv*2 + i)*16 + ((l >> 4) << 2);
    #pragma unroll
    for (int q = 0; q < 4; ++q){
      int co = cobase + q;
      float bias = kb[co];
      float* op = ko + ((b*NH + co)*HF + oh)*WF + w0 + (l & 15);
      #pragma unroll
      for (int n = 0; n < 4; ++n)
        op[n*16] = acc[i][n][q] + bias;
    }
  }
  #undef ISSUE_A
  #undef ISSUE_B
  #undef COMMIT
}

// ---------------- e[b,t,s] = sum_c e_w[c]*tanh(k[b,c,s] + q[b,t,c]) + e_b ----
// (b, s-tile) blocks; k-tile + all-t q staged in LDS; 4 t-slots x 64 s-lanes.
__global__ __launch_bounds__(256) void k_e2(const float* __restrict__ k,
    const float* __restrict__ q, const float* __restrict__ ew,
    const float* __restrict__ eb, float* __restrict__ e)
{
  int bid = blockIdx.x;                 // 256 blocks: (b, st)
  int st = bid & 15; int b = bid >> 4;
  int s0 = st*64;
  int tid = threadIdx.x;
  __shared__ float ksh[NH*64];          // 32 KB: k[b, c, s0..s0+63]
  __shared__ float qsh[TDEC*NH];        // 21 KB: q[b, :, :]
  __shared__ float ewsh[NH];
  #pragma unroll
  for (int i = 0; i < 32; ++i){
    int e2 = i*256 + tid; int c = e2 >> 6; int j = e2 & 63;
    ksh[e2] = k[(b*NH + c)*SPAT + s0 + j];
  }
  #pragma unroll
  for (int i = 0; i < 21; ++i){
    int e2 = i*256 + tid;
    if (e2 < TDEC*NH) qsh[e2] = q[b*TDEC*NH + e2];
  }
  if (tid < NH) ewsh[tid] = ew[tid];
  __syncthreads();
  int sl = tid & 63; int tp = tid >> 6;
  float ebv = eb[0];
  for (int t = tp; t < TDEC; t += 4){
    const float* qr = qsh + t*NH;
    float acc = ebv;
    #pragma unroll 8
    for (int c = 0; c < NH; ++c){
      float v = ksh[c*64 + sl] + qr[c];
      float ex = __expf(2.0f*v);
      float rc = __builtin_amdgcn_rcpf(ex + 1.0f);
      acc += ewsh[c]*(1.0f - 2.0f*rc);
    }
    e[(b*TDEC + t)*SPAT + s0 + sl] = acc;
  }
}

// ---------------- softmax over 1024 per (b,t), in-place ----------------------
__global__ __launch_bounds__(256) void k_softmax(float* __restrict__ e)
{
  int bt = blockIdx.x; int tid = threadIdx.x;
  float* row = e + bt*SPAT;
  __shared__ float red[256];
  float v[4];
  #pragma unroll
  for (int i = 0; i < 4; ++i) v[i] = row[tid + i*256];
  float m = fmaxf(fmaxf(v[0], v[1]), fmaxf(v[2], v[3]));
  red[tid] = m; __syncthreads();
  for (int s = 128; s > 0; s >>= 1){
    if (tid < s) red[tid] = fmaxf(red[tid], red[tid + s]);
    __syncthreads();
  }
  float mx = red[0];
  __syncthreads();
  float ev[4]; float sum = 0.f;
  #pragma unroll
  for (int i = 0; i < 4; ++i){ ev[i] = __expf(v[i] - mx); sum += ev[i]; }
  red[tid] = sum; __syncthreads();
  for (int s = 128; s > 0; s >>= 1){
    if (tid < s) red[tid] += red[tid + s];
    __syncthreads();
  }
  float inv = 1.f/red[0];
  #pragma unroll
  for (int i = 0; i < 4; ++i) row[tid + i*256] = ev[i]*inv;
}

// ---------------- attn_feat[b,t,c] = sum_s feat[b,c,s]*a[b,t,s] --------------
__global__ __launch_bounds__(256) void k_attnf(const float* __restrict__ feat,
    const float* __restrict__ a, float* __restrict__ attnf)
{
  int bid = blockIdx.x;                  // (b, tq(11), ch(2)): 352 blocks
  int ch = bid & 1; int rest = bid >> 1;
  int tq = rest % 11; int b = rest / 11;
  int tid = threadIdx.x;
  __shared__ __align__(16) float ash[4*SPAT];
  __shared__ float psh[4*4*64];
  for (int i = 0; i < 16; ++i){
    int e = i*256 + tid; int tt = e >> 10; int s = e & 1023;
    int t = tq*4 + tt;
    ash[e] = (t < TDEC) ? a[(b*TDEC + t)*SPAT + s] : 0.f;
  }
  __syncthreads();
  int cl = tid & 63; int sq = tid >> 6;
  const float* fp = feat + (b*NH + ch*64 + cl)*SPAT + sq*256;
  float acc[4] = {0.f,0.f,0.f,0.f};
  for (int i = 0; i < 64; ++i){
    float4 fv = *(const float4*)(fp + i*4);
    #pragma unroll
    for (int tt = 0; tt < 4; ++tt){
      const float* ar = ash + tt*SPAT + sq*256 + i*4;
      acc[tt] += fv.x*ar[0] + fv.y*ar[1] + fv.z*ar[2] + fv.w*ar[3];
    }
  }
  #pragma unroll
  for (int tt = 0; tt < 4; ++tt) psh[(sq*4 + tt)*64 + cl] = acc[tt];
  __syncthreads();
  {
    int tt = tid >> 6; int c2 = tid & 63;
    int t = tq*4 + tt;
    if (t < TDEC){
      float v = psh[(0*4 + tt)*64 + c2] + psh[(1*4 + tt)*64 + c2]
              + psh[(2*4 + tt)*64 + c2] + psh[(3*4 + tt)*64 + c2];
      attnf[(b*TDEC + t)*NH + ch*64 + c2] = v;
    }
  }
}

// ---------------- out = attnf @ fc_w^T + fc_b --------------------------------
__global__ __launch_bounds__(256) void k_fc(const float* __restrict__ attnf,
    const float* __restrict__ fcw, const float* __restrict__ fcb,
    float* __restrict__ out)
{
  int n0 = blockIdx.x*64;   // 104 cls-tiles
  int m0 = blockIdx.y*32;   // 21 m-tiles
  int tid = threadIdx.x;
  __shared__ __align__(16) float at[128*36];   // [j][m]
  __shared__ __align__(16) float wt[128*68];   // [j][cls]
  __shared__ float bsh[64];
  for (int i = 0; i < 16; ++i){
    int e = i*256 + tid; int m = e >> 7; int j = e & 127;
    at[j*36 + m] = (m0 + m < B_*TDEC) ? attnf[(m0 + m)*NH + j] : 0.f;
  }
  for (int i = 0; i < 32; ++i){
    int e = i*256 + tid; int cl = e >> 7; int j = e & 127;
    int n = n0 + cl;
    wt[j*68 + cl] = (n < NCLS) ? fcw[n*NH + j] : 0.f;
  }
  if (tid < 64) bsh[tid] = (n0 + tid < NCLS) ? fcb[n0 + tid] : 0.f;
  __syncthreads();
  int tn = tid & 15, tm = tid >> 4;
  float acc[2][4] = {{0.f,0.f,0.f,0.f},{0.f,0.f,0.f,0.f}};
  for (int j = 0; j < 128; ++j){
    float2 av = *(const float2*)(at + j*36 + tm*2);
    float4 wv = *(const float4*)(wt + j*68 + tn*4);
    acc[0][0] += av.x*wv.x; acc[0][1] += av.x*wv.y;
    acc[0][2] += av.x*wv.z; acc[0][3] += av.x*wv.w;
    acc[1][0] += av.y*wv.x; acc[1][1] += av.y*wv.y;
    acc[1][2] += av.y*wv.z; acc[1][3] += av.y*wv.w;
  }
  #pragma unroll
  for (int i = 0; i < 2; ++i){
    int m = m0 + tm*2 + i;
    if (m < B_*TDEC){
      #pragma unroll
      for (int ii = 0; ii < 4; ++ii){
        int n = n0 + tn*4 + ii;
        if (n < NCLS) out[m*NCLS + n] = acc[i][ii] + bsh[tn*4 + ii];
      }
    }
  }
}

// ============================================================================
extern "C" void kernel_launch(void* const* d_in, const int* in_sizes, int n_in,
                              void* d_out, int out_size, void* d_ws, size_t ws_size,
                              hipStream_t stream)
{
  (void)in_sizes; (void)n_in; (void)out_size; (void)ws_size;
  const float* x      = (const float*)d_in[0];
  const int*   tgt    = (const int*)  d_in[1];
  const float* conv0w = (const float*)d_in[2];
  const float* conv0b = (const float*)d_in[3];
  const float* bn0g   = (const float*)d_in[4];
  const float* bn0b   = (const float*)d_in[5];
  const float* bn0m   = (const float*)d_in[6];
  const float* bn0v   = (const float*)d_in[7];
  const float* dww    = (const float*)d_in[8];
  const float* dwb    = (const float*)d_in[9];
  const float* bn1g   = (const float*)d_in[10];
  const float* bn1b   = (const float*)d_in[11];
  const float* bn1m   = (const float*)d_in[12];
  const float* bn1v   = (const float*)d_in[13];
  const float* pww    = (const float*)d_in[14];
  const float* pwb    = (const float*)d_in[15];
  const float* bn2g   = (const float*)d_in[16];
  const float* bn2b   = (const float*)d_in[17];
  const float* bn2m   = (const float*)d_in[18];
  const float* bn2v   = (const float*)d_in[19];
  const float* encwih = (const float*)d_in[20];
  const float* encwhh = (const float*)d_in[21];
  const float* encbih = (const float*)d_in[22];
  const float* encbhh = (const float*)d_in[23];
  const float* decwih = (const float*)d_in[24];
  const float* decwhh = (const float*)d_in[25];
  const float* decbih = (const float*)d_in[26];
  const float* decbhh = (const float*)d_in[27];
  const float* emb    = (const float*)d_in[28];
  const float* qw     = (const float*)d_in[29];
  const float* qb0    = (const float*)d_in[30];
  const float* kw     = (const float*)d_in[31];
  const float* kb     = (const float*)d_in[32];
  const float* ew     = (const float*)d_in[33];
  const float* eb     = (const float*)d_in[34];
  const float* fcw    = (const float*)d_in[35];
  const float* fcb    = (const float*)d_in[36];

  float* ws    = (float*)d_ws;
  float* hbuf  = ws + 0;         // 2097152
  float* tbuf  = ws + 2097152;   // 2097152 (t; later: ebuf + kwA)
  float* feat  = ws + 4194304;   // 2097152
  float* xp    = ws + 6291456;   // 393216
  float* indec = ws + 6684672;   // 41984
  float* xpd   = ws + 6726656;   // 125952
  float* ybuf  = ws + 6852608;   // 41984
  float* qbuf  = ws + 6894592;   // 83968
  float* attf  = ws + 6978560;   // 83968
  float* pwT   = ws + 7062528;   // 16384
  float* kbuf  = hbuf;           // alias: h dead after k_dw
  float* ebuf  = tbuf;           // alias: t dead after k_pw (671744 floats)
  _Float16* kwA = (_Float16*)(tbuf + 1048576); // 147456 halves, inside dead tbuf
  float* out   = (float*)d_out;

  hipLaunchKernelGGL(k_pwT,     dim3(64),          dim3(256), 0, stream, pww, pwT);
  hipLaunchKernelGGL(k_conv0,   dim3(2048),        dim3(256), 0, stream,
                     x, conv0w, conv0b, bn0g, bn0b, bn0m, bn0v, hbuf);
  hipLaunchKernelGGL(k_dw,      dim3(8192),        dim3(256), 0, stream,
                     hbuf, dww, dwb, bn1g, bn1b, bn1m, bn1v, tbuf);
  hipLaunchKernelGGL(k_pw,      dim3(256),         dim3(512), 0, stream,
                     tbuf, pwT, pwb, bn2g, bn2b, bn2m, bn2v, feat);
  hipLaunchKernelGGL(k_wprep,   dim3(576),         dim3(256), 0, stream, kw, kwA);
  hipLaunchKernelGGL(k_embed,   dim3(160),         dim3(256), 0, stream, tgt, emb, indec);
  hipLaunchKernelGGL(k_encxp,   dim3(64, 4),       dim3(256), 0, stream,
                     feat, encwih, encbih, xp);
  hipLaunchKernelGGL((k_scan<128,false>), dim3(16), dim3(64), 0, stream,
                     xp, encwhh, encbhh, indec);
  hipLaunchKernelGGL(k_xpd,     dim3(492),         dim3(256), 0, stream,
                     indec, decwih, decbih, xpd);
  hipLaunchKernelGGL((k_scan<TDEC,true>), dim3(16), dim3(64), 0, stream,
                     xpd, decwhh, decbhh, ybuf);
  hipLaunchKernelGGL(k_q,       dim3(328),         dim3(256), 0, stream,
                     ybuf, qw, qb0, qbuf);
  hipLaunchKernelGGL(k_kconv2,  dim3(256),         dim3(256), 0, stream,
                     feat, kwA, kb, kbuf);
  hipLaunchKernelGGL(k_e2,      dim3(256),         dim3(256), 0, stream,
                     kbuf, qbuf, ew, eb, ebuf);
  hipLaunchKernelGGL(k_softmax, dim3(B_*TDEC),     dim3(256), 0, stream, ebuf);
  hipLaunchKernelGGL(k_attnf,   dim3(352),         dim3(256), 0, stream,
                     feat, ebuf, attf);
  hipLaunchKernelGGL(k_fc,      dim3(104, 21),     dim3(256), 0, stream,
                     attf, fcw, fcb, out);
}

// Round 5
// 376.349 us; speedup vs baseline: 1.3506x; 1.0323x over previous
//
#include <hip/hip_runtime.h>
#include <hip/hip_bf16.h>

#define DEV __device__ __forceinline__

#define B_    16
#define T_    40
#define TDEC  41
#define NH    128
#define HF    8
#define WF    128
#define HID   64
#define G3    192
#define NCLS  6625
#define SPAT  1024

typedef _Float16 half8 __attribute__((ext_vector_type(8)));
typedef float    f32x4 __attribute__((ext_vector_type(4)));
typedef float    f32x2 __attribute__((ext_vector_type(2)));

DEV float sigmoidf_(float x){ return 1.0f/(1.0f + __expf(-x)); }
DEV float tanhf_(float x){ float e = __expf(2.0f*x); return 1.0f - 2.0f/(e + 1.0f); }
DEV float gelu_(float x){ return 0.5f*x*(1.0f + erff(x*0.70710678118654752f)); }
DEV float bnf_(float x, float g, float b, float m, float v){
  return (x - m)*rsqrtf(v + 1e-5f)*g + b;
}

// ---------------- conv0 4x4 s4 + BN + GELU -> h (16,128,8,128) ----------------
__global__ __launch_bounds__(256) void k_conv0(const float* __restrict__ x,
    const float* __restrict__ w, const float* __restrict__ bias,
    const float* __restrict__ bng, const float* __restrict__ bnb,
    const float* __restrict__ bnm, const float* __restrict__ bnv,
    float* __restrict__ h)
{
  int tid = blockIdx.x*256 + threadIdx.x;   // 524288 threads, 4 co each
  int ow = tid & 127;
  int oh = (tid >> 7) & 7;
  int c4 = (tid >> 10) & 31;
  int b  = tid >> 15;
  float acc[4] = {0.f,0.f,0.f,0.f};
  int xbase = ((b*3)*32 + oh*4)*512 + ow*4;
  for (int ci = 0; ci < 3; ++ci){
    #pragma unroll
    for (int kh = 0; kh < 4; ++kh){
      float4 xv = *(const float4*)(x + xbase + ci*(32*512) + kh*512);
      #pragma unroll
      for (int cc = 0; cc < 4; ++cc){
        int co = c4*4 + cc;
        const float* wp = w + ((co*3 + ci)*4 + kh)*4;
        acc[cc] += xv.x*wp[0] + xv.y*wp[1] + xv.z*wp[2] + xv.w*wp[3];
      }
    }
  }
  #pragma unroll
  for (int cc = 0; cc < 4; ++cc){
    int co = c4*4 + cc;
    float v = acc[cc] + bias[co];
    v = bnf_(v, bng[co], bnb[co], bnm[co], bnv[co]);
    h[((b*NH + co)*HF + oh)*WF + ow] = gelu_(v);
  }
}

// ---------------- depthwise 3x3 (blk idx 1) + BN + GELU + residual -> t -------
__global__ __launch_bounds__(256) void k_dw(const float* __restrict__ h,
    const float* __restrict__ dww, const float* __restrict__ dwb,
    const float* __restrict__ g1, const float* __restrict__ b1,
    const float* __restrict__ m1, const float* __restrict__ v1,
    float* __restrict__ t)
{
  int tid = blockIdx.x*256 + threadIdx.x;   // 2097152
  int ow = tid & 127;
  int oh = (tid >> 7) & 7;
  int c  = (tid >> 10) & 127;
  int b  = tid >> 17;
  const float* wp = dww + NH*9 + c*9;       // block index 1
  const float* hp = h + ((b*NH + c)*HF)*WF;
  float acc = 0.f;
  #pragma unroll
  for (int kh = 0; kh < 3; ++kh){
    int ih = oh + kh - 1;
    if (ih < 0 || ih >= HF) continue;
    #pragma unroll
    for (int kw = 0; kw < 3; ++kw){
      int iw = ow + kw - 1;
      if (iw < 0 || iw >= WF) continue;
      acc += hp[ih*WF + iw]*wp[kh*3 + kw];
    }
  }
  float val = acc + dwb[NH + c];
  val = bnf_(val, g1[NH + c], b1[NH + c], m1[NH + c], v1[NH + c]);
  t[tid] = hp[oh*WF + ow] + gelu_(val);
}

// ---------------- transpose pw weights: pwT[ci][co] = pw[1][co][ci] ----------
__global__ void k_pwT(const float* __restrict__ pw, float* __restrict__ pwT){
  int tid = blockIdx.x*256 + threadIdx.x;   // 16384
  int ci = tid & 127; int co = tid >> 7;
  pwT[ci*128 + co] = pw[16384 + co*128 + ci];
}

// ---------------- pointwise 128x128 (blk idx 1) + BN + GELU -> feat ----------
__global__ __launch_bounds__(512) void k_pw(const float* __restrict__ t,
    const float* __restrict__ pwT, const float* __restrict__ pwb,
    const float* __restrict__ g2, const float* __restrict__ b2,
    const float* __restrict__ m2, const float* __restrict__ v2,
    float* __restrict__ feat)
{
  int bid = blockIdx.x;                     // (b, oh, whalf): 256 blocks
  int wh = bid & 1; int oh = (bid >> 1) & 7; int b = bid >> 4;
  int w0 = wh*64;
  int tid = threadIdx.x;
  __shared__ __align__(16) float tile[128*64];
  for (int i = 0; i < 16; ++i){
    int e = i*512 + tid; int ci = e >> 6; int wloc = e & 63;
    tile[ci*64 + wloc] = t[((b*NH + ci)*HF + oh)*WF + w0 + wloc];
  }
  __syncthreads();
  int co = tid & 127; int wq = tid >> 7;
  float acc[16];
  #pragma unroll
  for (int i = 0; i < 16; ++i) acc[i] = 0.f;
  for (int ci = 0; ci < 128; ++ci){
    float wt = pwT[ci*128 + co];
    const float4* tp = (const float4*)(tile + ci*64 + wq*16);
    #pragma unroll
    for (int j = 0; j < 4; ++j){
      float4 tv = tp[j];
      acc[j*4+0] += tv.x*wt; acc[j*4+1] += tv.y*wt;
      acc[j*4+2] += tv.z*wt; acc[j*4+3] += tv.w*wt;
    }
  }
  float bb = pwb[128 + co];
  float gg = g2[128 + co], bc = b2[128 + co], mm = m2[128 + co], vv = v2[128 + co];
  float* op = feat + ((b*NH + co)*HF + oh)*WF + w0 + wq*16;
  #pragma unroll
  for (int i = 0; i < 16; ++i){
    float v = bnf_(acc[i] + bb, gg, bc, mm, vv);
    op[i] = gelu_(v);
  }
}

// ---------------- enc xp GEMM: (2048x1024)@(192x1024)^T + bih -> xp ----------
__global__ __launch_bounds__(256) void k_encxp(const float* __restrict__ feat,
    const float* __restrict__ wih, const float* __restrict__ bih,
    float* __restrict__ xp)
{
  int m0 = blockIdx.x*32;     // 64 m-tiles
  int n0 = blockIdx.y*48;     // 4 n-tiles
  int b  = m0 >> 7;
  int w0 = m0 & 127;
  int tid = threadIdx.x;
  __shared__ float As[64*33];  // [k][m]
  __shared__ float Bs[64*49];  // [k][n]
  int tx = tid & 15, ty = tid >> 4;
  float acc[2][3] = {{0.f,0.f,0.f},{0.f,0.f,0.f}};
  for (int kt = 0; kt < 16; ++kt){
    int k0 = kt*64;
    #pragma unroll
    for (int i = 0; i < 8; ++i){
      int e = i*256 + tid; int kd = e >> 5; int mi = e & 31;
      int kg = k0 + kd;
      As[kd*33 + mi] = feat[((b*NH + (kg >> 3))*HF + (kg & 7))*WF + w0 + mi];
    }
    #pragma unroll
    for (int i = 0; i < 12; ++i){
      int e = i*256 + tid; int gi = e >> 6; int kd = e & 63;
      Bs[kd*49 + gi] = wih[(n0 + gi)*1024 + k0 + kd];
    }
    __syncthreads();
    for (int kd = 0; kd < 64; ++kd){
      float a0 = As[kd*33 + ty*2], a1 = As[kd*33 + ty*2 + 1];
      float b0 = Bs[kd*49 + tx*3], b1 = Bs[kd*49 + tx*3 + 1], b2 = Bs[kd*49 + tx*3 + 2];
      acc[0][0] += a0*b0; acc[0][1] += a0*b1; acc[0][2] += a0*b2;
      acc[1][0] += a1*b0; acc[1][1] += a1*b1; acc[1][2] += a1*b2;
    }
    __syncthreads();
  }
  #pragma unroll
  for (int i = 0; i < 2; ++i){
    int m = m0 + ty*2 + i;
    #pragma unroll
    for (int j = 0; j < 3; ++j){
      int g = n0 + tx*3 + j;
      xp[m*G3 + g] = acc[i][j] + bih[g];
    }
  }
}

// ---------------- GRU scan, single-wave per batch, weights in VGPRs ----------
template<int STEPS, bool WRITE_ALL>
__global__ __launch_bounds__(64, 1) void k_scan(const float* __restrict__ xp,
    const float* __restrict__ whh, const float* __restrict__ bhh,
    float* __restrict__ outp)
{
  __shared__ float hsh[HID];
  int g = threadIdx.x;     // 0..63
  int b = blockIdx.x;
  f32x2 w0[32], w1[32], w2[32];
  const f32x2* p0 = (const f32x2*)(whh + g*HID);
  const f32x2* p1 = (const f32x2*)(whh + (HID + g)*HID);
  const f32x2* p2 = (const f32x2*)(whh + (2*HID + g)*HID);
  #pragma unroll
  for (int k = 0; k < 32; ++k){ w0[k] = p0[k]; w1[k] = p1[k]; w2[k] = p2[k]; }
  float b0 = bhh[g], b1 = bhh[HID + g], b2 = bhh[2*HID + g];
  float hg = 0.f;
  hsh[g] = 0.f;
  __syncthreads();
  const float* xpb = xp + b*STEPS*G3;
  float x0 = xpb[g], x1 = xpb[HID + g], x2 = xpb[2*HID + g];
  for (int t = 0; t < STEPS; ++t){
    float x0n = 0.f, x1n = 0.f, x2n = 0.f;
    if (t + 1 < STEPS){
      const float* p = xpb + (t + 1)*G3 + g;
      x0n = p[0]; x1n = p[HID]; x2n = p[2*HID];
    }
    f32x2 ar0{0.f,0.f}, ar1{0.f,0.f}, az0{0.f,0.f}, az1{0.f,0.f}, an0{0.f,0.f}, an1{0.f,0.f};
    const f32x2* h2 = (const f32x2*)hsh;
    #pragma unroll
    for (int k = 0; k < 32; k += 2){
      f32x2 hA = h2[k], hB = h2[k+1];
      ar0 += w0[k]*hA; ar1 += w0[k+1]*hB;
      az0 += w1[k]*hA; az1 += w1[k+1]*hB;
      an0 += w2[k]*hA; an1 += w2[k+1]*hB;
    }
    float hp0 = (ar0.x + ar0.y) + (ar1.x + ar1.y) + b0;
    float hp1 = (az0.x + az0.y) + (az1.x + az1.y) + b1;
    float hp2 = (an0.x + an0.y) + (an1.x + an1.y) + b2;
    float r = sigmoidf_(x0 + hp0);
    float z = sigmoidf_(x1 + hp1);
    float n = tanhf_(x2 + r*hp2);
    hg = (1.f - z)*n + z*hg;
    if (WRITE_ALL) outp[(b*TDEC + t)*HID + g] = hg;
    x0 = x0n; x1 = x1n; x2 = x2n;
    __syncthreads();
    hsh[g] = hg;
    __syncthreads();
  }
  if (!WRITE_ALL) outp[(b*TDEC)*HID + g] = hg;
}

// ---------------- embedding fill: indec rows 1..40 ---------------------------
__global__ void k_embed(const int* __restrict__ tgt, const float* __restrict__ emb,
                        float* __restrict__ indec)
{
  int tid = blockIdx.x*256 + threadIdx.x;   // 40960
  if (tid >= B_*T_*HID) return;
  int j = tid & 63; int rest = tid >> 6;
  int t = rest % T_; int b = rest / T_;
  int cls = tgt[b*T_ + t];
  indec[(b*TDEC + 1 + t)*HID + j] = emb[cls*HID + j];
}

// ---------------- dec xp: (656x64)@(192x64)^T + bih --------------------------
__global__ void k_xpd(const float* __restrict__ indec, const float* __restrict__ wih,
                      const float* __restrict__ bih, float* __restrict__ xpd)
{
  int tid = blockIdx.x*256 + threadIdx.x;   // 125952
  if (tid >= B_*TDEC*G3) return;
  int g = tid % G3; int bt = tid / G3;
  const float4* r4 = (const float4*)(indec + bt*HID);
  const float4* w4 = (const float4*)(wih + g*HID);
  float acc = bih[g];
  #pragma unroll
  for (int j = 0; j < 16; ++j){
    float4 rv = r4[j], wv = w4[j];
    acc += rv.x*wv.x + rv.y*wv.y + rv.z*wv.z + rv.w*wv.w;
  }
  xpd[tid] = acc;
}

// ---------------- q = y @ q_w^T + q_b ---------------------------------------
__global__ void k_q(const float* __restrict__ y, const float* __restrict__ qw,
                    const float* __restrict__ qb0, float* __restrict__ q)
{
  int tid = blockIdx.x*256 + threadIdx.x;   // 83968
  if (tid >= B_*TDEC*NH) return;
  int co = tid & 127; int bt = tid >> 7;
  const float4* r4 = (const float4*)(y + bt*HID);
  const float4* w4 = (const float4*)(qw + co*HID);
  float acc = qb0[co];
  #pragma unroll
  for (int j = 0; j < 16; ++j){
    float4 rv = r4[j], wv = w4[j];
    acc += rv.x*wv.x + rv.y*wv.y + rv.z*wv.z + rv.w*wv.w;
  }
  q[tid] = acc;
}

// ---------------- k-conv weight prep: fragment-ordered fp16 A ---------------
__global__ void k_wprep(const float* __restrict__ kw, _Float16* __restrict__ kwA)
{
  int tid = blockIdx.x*256 + threadIdx.x;   // 147456
  if (tid >= 36*8*64*8) return;
  int j = tid & 7;
  int l = (tid >> 3) & 63;
  int f = (tid >> 9) & 7;
  int s = tid >> 12;
  int co = f*16 + (l & 15);
  int k  = s*32 + ((l >> 4) << 3) + j;
  int r  = k >> 7;
  int ci = k & 127;
  kwA[tid] = (_Float16)kw[(co*128 + ci)*9 + r];
}

// ---------------- k conv 3x3 pad 1 via fp16 MFMA, barrier-free 1-wave blocks -
// grid 4096: (b, oh, wq, cs, mq). Each wave: 2 co-frags x 16 spatial, K=1152.
__global__ __launch_bounds__(64) void k_kconv3(const float* __restrict__ feat,
    const uint4* __restrict__ kwA4, const float* __restrict__ kb,
    float* __restrict__ ko)
{
  int bid = blockIdx.x;
  int mq = bid & 3;
  int cs = (bid >> 2) & 3;
  int wq = (bid >> 4) & 1;
  int oh = (bid >> 5) & 7;
  int b  = bid >> 8;
  int l  = threadIdx.x;
  int w0 = wq*64 + mq*16;
  int iwb = w0 + (l & 15);
  int cib = (l >> 4) << 3;

  f32x4 acc0{0.f,0.f,0.f,0.f}, acc1{0.f,0.f,0.f,0.f};
  uint4 a0A, a0B, a1A, a1B;
  float b0v[8], b1v[8];

  #define ISS(s, aX, aY, bvv) {                                               \
    aX = kwA4[(s)*512 + cs*128 + l];                                          \
    aY = kwA4[(s)*512 + cs*128 + 64 + l];                                     \
    int r = (s) >> 2; int dh = r/3 - 1; int dw2 = r%3 - 1;                    \
    int ci0 = ((s) & 3) << 5;                                                 \
    int ih = oh + dh; int iw = iwb + dw2;                                     \
    bool ok = (ih >= 0) & (ih < HF) & (iw >= 0) & (iw < WF);                  \
    const float* fp = feat + ((b*NH + ci0 + cib)*HF + ih)*WF + iw;            \
    _Pragma("unroll")                                                         \
    for (int jj = 0; jj < 8; ++jj) bvv[jj] = ok ? fp[jj*(HF*WF)] : 0.f;       \
  }
  #define CMP(aX, aY, bvv) {                                                  \
    half8 bf;                                                                 \
    _Pragma("unroll")                                                         \
    for (int jj = 0; jj < 8; ++jj) bf[jj] = (_Float16)bvv[jj];                \
    half8 af0 = __builtin_bit_cast(half8, aX);                                \
    half8 af1 = __builtin_bit_cast(half8, aY);                                \
    acc0 = __builtin_amdgcn_mfma_f32_16x16x32_f16(af0, bf, acc0, 0, 0, 0);    \
    acc1 = __builtin_amdgcn_mfma_f32_16x16x32_f16(af1, bf, acc1, 0, 0, 0);    \
  }

  ISS(0, a0A, a0B, b0v);
  for (int s = 0; s < 36; s += 2){
    if (s + 1 < 36) ISS(s + 1, a1A, a1B, b1v);
    CMP(a0A, a0B, b0v);
    if (s + 2 < 36) ISS(s + 2, a0A, a0B, b0v);
    if (s + 1 < 36) CMP(a1A, a1B, b1v);
  }
  #undef ISS
  #undef CMP

  // epilogue: D row = co-frag row = (l>>4)*4 + q, col = spatial = l&15
  int m = w0 + (l & 15);
  #pragma unroll
  for (int q = 0; q < 4; ++q){
    int co0 = cs*32 + ((l >> 4) << 2) + q;
    int co1 = co0 + 16;
    ko[((b*NH + co0)*HF + oh)*WF + m] = acc0[q] + kb[co0];
    ko[((b*NH + co1)*HF + oh)*WF + m] = acc1[q] + kb[co1];
  }
}

// ---------------- e[b,t,s] = sum_c e_w[c]*tanh(k[b,c,s] + q[b,t,c]) + e_b ----
__global__ __launch_bounds__(256) void k_e2(const float* __restrict__ k,
    const float* __restrict__ q, const float* __restrict__ ew,
    const float* __restrict__ eb, float* __restrict__ e)
{
  int bid = blockIdx.x;                 // 256 blocks: (b, st)
  int st = bid & 15; int b = bid >> 4;
  int s0 = st*64;
  int tid = threadIdx.x;
  __shared__ float ksh[NH*64];          // 32 KB: k[b, c, s0..s0+63]
  __shared__ float qsh[TDEC*NH];        // 21 KB: q[b, :, :]
  __shared__ float ewsh[NH];
  #pragma unroll
  for (int i = 0; i < 32; ++i){
    int e2 = i*256 + tid; int c = e2 >> 6; int j = e2 & 63;
    ksh[e2] = k[(b*NH + c)*SPAT + s0 + j];
  }
  #pragma unroll
  for (int i = 0; i < 21; ++i){
    int e2 = i*256 + tid;
    if (e2 < TDEC*NH) qsh[e2] = q[b*TDEC*NH + e2];
  }
  if (tid < NH) ewsh[tid] = ew[tid];
  __syncthreads();
  int sl = tid & 63; int tp = tid >> 6;
  float ebv = eb[0];
  for (int t = tp; t < TDEC; t += 4){
    const float* qr = qsh + t*NH;
    float acc = ebv;
    #pragma unroll 8
    for (int c = 0; c < NH; ++c){
      float v = ksh[c*64 + sl] + qr[c];
      float ex = __expf(2.0f*v);
      float rc = __builtin_amdgcn_rcpf(ex + 1.0f);
      acc += ewsh[c]*(1.0f - 2.0f*rc);
    }
    e[(b*TDEC + t)*SPAT + s0 + sl] = acc;
  }
}

// ---------------- softmax over 1024 per (b,t), in-place ----------------------
__global__ __launch_bounds__(256) void k_softmax(float* __restrict__ e)
{
  int bt = blockIdx.x; int tid = threadIdx.x;
  float* row = e + bt*SPAT;
  __shared__ float red[256];
  float v[4];
  #pragma unroll
  for (int i = 0; i < 4; ++i) v[i] = row[tid + i*256];
  float m = fmaxf(fmaxf(v[0], v[1]), fmaxf(v[2], v[3]));
  red[tid] = m; __syncthreads();
  for (int s = 128; s > 0; s >>= 1){
    if (tid < s) red[tid] = fmaxf(red[tid], red[tid + s]);
    __syncthreads();
  }
  float mx = red[0];
  __syncthreads();
  float ev[4]; float sum = 0.f;
  #pragma unroll
  for (int i = 0; i < 4; ++i){ ev[i] = __expf(v[i] - mx); sum += ev[i]; }
  red[tid] = sum; __syncthreads();
  for (int s = 128; s > 0; s >>= 1){
    if (tid < s) red[tid] += red[tid + s];
    __syncthreads();
  }
  float inv = 1.f/red[0];
  #pragma unroll
  for (int i = 0; i < 4; ++i) row[tid + i*256] = ev[i]*inv;
}

// ---------------- attn_feat[b,t,c] = sum_s feat[b,c,s]*a[b,t,s] --------------
__global__ __launch_bounds__(256) void k_attnf(const float* __restrict__ feat,
    const float* __restrict__ a, float* __restrict__ attnf)
{
  int bid = blockIdx.x;                  // (b, tq(11), ch(2)): 352 blocks
  int ch = bid & 1; int rest = bid >> 1;
  int tq = rest % 11; int b = rest / 11;
  int tid = threadIdx.x;
  __shared__ __align__(16) float ash[4*SPAT];
  __shared__ float psh[4*4*64];
  for (int i = 0; i < 16; ++i){
    int e = i*256 + tid; int tt = e >> 10; int s = e & 1023;
    int t = tq*4 + tt;
    ash[e] = (t < TDEC) ? a[(b*TDEC + t)*SPAT + s] : 0.f;
  }
  __syncthreads();
  int cl = tid & 63; int sq = tid >> 6;
  const float* fp = feat + (b*NH + ch*64 + cl)*SPAT + sq*256;
  float acc[4] = {0.f,0.f,0.f,0.f};
  for (int i = 0; i < 64; ++i){
    float4 fv = *(const float4*)(fp + i*4);
    #pragma unroll
    for (int tt = 0; tt < 4; ++tt){
      const float* ar = ash + tt*SPAT + sq*256 + i*4;
      acc[tt] += fv.x*ar[0] + fv.y*ar[1] + fv.z*ar[2] + fv.w*ar[3];
    }
  }
  #pragma unroll
  for (int tt = 0; tt < 4; ++tt) psh[(sq*4 + tt)*64 + cl] = acc[tt];
  __syncthreads();
  {
    int tt = tid >> 6; int c2 = tid & 63;
    int t = tq*4 + tt;
    if (t < TDEC){
      float v = psh[(0*4 + tt)*64 + c2] + psh[(1*4 + tt)*64 + c2]
              + psh[(2*4 + tt)*64 + c2] + psh[(3*4 + tt)*64 + c2];
      attnf[(b*TDEC + t)*NH + ch*64 + c2] = v;
    }
  }
}

// ---------------- out = attnf @ fc_w^T + fc_b --------------------------------
__global__ __launch_bounds__(256) void k_fc(const float* __restrict__ attnf,
    const float* __restrict__ fcw, const float* __restrict__ fcb,
    float* __restrict__ out)
{
  int n0 = blockIdx.x*64;   // 104 cls-tiles
  int m0 = blockIdx.y*32;   // 21 m-tiles
  int tid = threadIdx.x;
  __shared__ __align__(16) float at[128*36];   // [j][m]
  __shared__ __align__(16) float wt[128*68];   // [j][cls]
  __shared__ float bsh[64];
  for (int i = 0; i < 16; ++i){
    int e = i*256 + tid; int m = e >> 7; int j = e & 127;
    at[j*36 + m] = (m0 + m < B_*TDEC) ? attnf[(m0 + m)*NH + j] : 0.f;
  }
  for (int i = 0; i < 32; ++i){
    int e = i*256 + tid; int cl = e >> 7; int j = e & 127;
    int n = n0 + cl;
    wt[j*68 + cl] = (n < NCLS) ? fcw[n*NH + j] : 0.f;
  }
  if (tid < 64) bsh[tid] = (n0 + tid < NCLS) ? fcb[n0 + tid] : 0.f;
  __syncthreads();
  int tn = tid & 15, tm = tid >> 4;
  float acc[2][4] = {{0.f,0.f,0.f,0.f},{0.f,0.f,0.f,0.f}};
  for (int j = 0; j < 128; ++j){
    float2 av = *(const float2*)(at + j*36 + tm*2);
    float4 wv = *(const float4*)(wt + j*68 + tn*4);
    acc[0][0] += av.x*wv.x; acc[0][1] += av.x*wv.y;
    acc[0][2] += av.x*wv.z; acc[0][3] += av.x*wv.w;
    acc[1][0] += av.y*wv.x; acc[1][1] += av.y*wv.y;
    acc[1][2] += av.y*wv.z; acc[1][3] += av.y*wv.w;
  }
  #pragma unroll
  for (int i = 0; i < 2; ++i){
    int m = m0 + tm*2 + i;
    if (m < B_*TDEC){
      #pragma unroll
      for (int ii = 0; ii < 4; ++ii){
        int n = n0 + tn*4 + ii;
        if (n < NCLS) out[m*NCLS + n] = acc[i][ii] + bsh[tn*4 + ii];
      }
    }
  }
}

// ============================================================================
extern "C" void kernel_launch(void* const* d_in, const int* in_sizes, int n_in,
                              void* d_out, int out_size, void* d_ws, size_t ws_size,
                              hipStream_t stream)
{
  (void)in_sizes; (void)n_in; (void)out_size; (void)ws_size;
  const float* x      = (const float*)d_in[0];
  const int*   tgt    = (const int*)  d_in[1];
  const float* conv0w = (const float*)d_in[2];
  const float* conv0b = (const float*)d_in[3];
  const float* bn0g   = (const float*)d_in[4];
  const float* bn0b   = (const float*)d_in[5];
  const float* bn0m   = (const float*)d_in[6];
  const float* bn0v   = (const float*)d_in[7];
  const float* dww    = (const float*)d_in[8];
  const float* dwb    = (const float*)d_in[9];
  const float* bn1g   = (const float*)d_in[10];
  const float* bn1b   = (const float*)d_in[11];
  const float* bn1m   = (const float*)d_in[12];
  const float* bn1v   = (const float*)d_in[13];
  const float* pww    = (const float*)d_in[14];
  const float* pwb    = (const float*)d_in[15];
  const float* bn2g   = (const float*)d_in[16];
  const float* bn2b   = (const float*)d_in[17];
  const float* bn2m   = (const float*)d_in[18];
  const float* bn2v   = (const float*)d_in[19];
  const float* encwih = (const float*)d_in[20];
  const float* encwhh = (const float*)d_in[21];
  const float* encbih = (const float*)d_in[22];
  const float* encbhh = (const float*)d_in[23];
  const float* decwih = (const float*)d_in[24];
  const float* decwhh = (const float*)d_in[25];
  const float* decbih = (const float*)d_in[26];
  const float* decbhh = (const float*)d_in[27];
  const float* emb    = (const float*)d_in[28];
  const float* qw     = (const float*)d_in[29];
  const float* qb0    = (const float*)d_in[30];
  const float* kw     = (const float*)d_in[31];
  const float* kb     = (const float*)d_in[32];
  const float* ew     = (const float*)d_in[33];
  const float* eb     = (const float*)d_in[34];
  const float* fcw    = (const float*)d_in[35];
  const float* fcb    = (const float*)d_in[36];

  float* ws    = (float*)d_ws;
  float* hbuf  = ws + 0;         // 2097152
  float* tbuf  = ws + 2097152;   // 2097152 (t; later: ebuf + kwA)
  float* feat  = ws + 4194304;   // 2097152
  float* xp    = ws + 6291456;   // 393216
  float* indec = ws + 6684672;   // 41984
  float* xpd   = ws + 6726656;   // 125952
  float* ybuf  = ws + 6852608;   // 41984
  float* qbuf  = ws + 6894592;   // 83968
  float* attf  = ws + 6978560;   // 83968
  float* pwT   = ws + 7062528;   // 16384
  float* kbuf  = hbuf;           // alias: h dead after k_dw
  float* ebuf  = tbuf;           // alias: t dead after k_pw (671744 floats)
  _Float16* kwA = (_Float16*)(tbuf + 1048576); // 147456 halves, inside dead tbuf
  float* out   = (float*)d_out;

  hipLaunchKernelGGL(k_pwT,     dim3(64),          dim3(256), 0, stream, pww, pwT);
  hipLaunchKernelGGL(k_conv0,   dim3(2048),        dim3(256), 0, stream,
                     x, conv0w, conv0b, bn0g, bn0b, bn0m, bn0v, hbuf);
  hipLaunchKernelGGL(k_dw,      dim3(8192),        dim3(256), 0, stream,
                     hbuf, dww, dwb, bn1g, bn1b, bn1m, bn1v, tbuf);
  hipLaunchKernelGGL(k_pw,      dim3(256),         dim3(512), 0, stream,
                     tbuf, pwT, pwb, bn2g, bn2b, bn2m, bn2v, feat);
  hipLaunchKernelGGL(k_wprep,   dim3(576),         dim3(256), 0, stream, kw, kwA);
  hipLaunchKernelGGL(k_embed,   dim3(160),         dim3(256), 0, stream, tgt, emb, indec);
  hipLaunchKernelGGL(k_encxp,   dim3(64, 4),       dim3(256), 0, stream,
                     feat, encwih, encbih, xp);
  hipLaunchKernelGGL((k_scan<128,false>), dim3(16), dim3(64), 0, stream,
                     xp, encwhh, encbhh, indec);
  hipLaunchKernelGGL(k_xpd,     dim3(492),         dim3(256), 0, stream,
                     indec, decwih, decbih, xpd);
  hipLaunchKernelGGL((k_scan<TDEC,true>), dim3(16), dim3(64), 0, stream,
                     xpd, decwhh, decbhh, ybuf);
  hipLaunchKernelGGL(k_q,       dim3(328),         dim3(256), 0, stream,
                     ybuf, qw, qb0, qbuf);
  hipLaunchKernelGGL(k_kconv3,  dim3(4096),        dim3(64), 0, stream,
                     feat, (const uint4*)kwA, kb, kbuf);
  hipLaunchKernelGGL(k_e2,      dim3(256),         dim3(256), 0, stream,
                     kbuf, qbuf, ew, eb, ebuf);
  hipLaunchKernelGGL(k_softmax, dim3(B_*TDEC),     dim3(256), 0, stream, ebuf);
  hipLaunchKernelGGL(k_attnf,   dim3(352),         dim3(256), 0, stream,
                     feat, ebuf, attf);
  hipLaunchKernelGGL(k_fc,      dim3(104, 21),     dim3(256), 0, stream,
                     attf, fcw, fcb, out);
}

// Round 6
// 372.611 us; speedup vs baseline: 1.3641x; 1.0100x over previous
//
#include <hip/hip_runtime.h>
#include <hip/hip_bf16.h>

#define DEV __device__ __forceinline__

#define B_    16
#define T_    40
#define TDEC  41
#define NH    128
#define HF    8
#define WF    128
#define HID   64
#define G3    192
#define NCLS  6625
#define SPAT  1024

typedef _Float16 half8 __attribute__((ext_vector_type(8)));
typedef float    f32x4 __attribute__((ext_vector_type(4)));
typedef float    f32x2 __attribute__((ext_vector_type(2)));

DEV float sigmoidf_(float x){ return 1.0f/(1.0f + __expf(-x)); }
DEV float tanhf_(float x){ float e = __expf(2.0f*x); return 1.0f - 2.0f/(e + 1.0f); }
DEV float gelu_(float x){ return 0.5f*x*(1.0f + erff(x*0.70710678118654752f)); }
DEV float bnf_(float x, float g, float b, float m, float v){
  return (x - m)*rsqrtf(v + 1e-5f)*g + b;
}

// ---------------- conv0 4x4 s4 + BN + GELU -> h (16,128,8,128) ----------------
__global__ __launch_bounds__(256) void k_conv0(const float* __restrict__ x,
    const float* __restrict__ w, const float* __restrict__ bias,
    const float* __restrict__ bng, const float* __restrict__ bnb,
    const float* __restrict__ bnm, const float* __restrict__ bnv,
    float* __restrict__ h)
{
  int tid = blockIdx.x*256 + threadIdx.x;   // 524288 threads, 4 co each
  int ow = tid & 127;
  int oh = (tid >> 7) & 7;
  int c4 = (tid >> 10) & 31;
  int b  = tid >> 15;
  float acc[4] = {0.f,0.f,0.f,0.f};
  int xbase = ((b*3)*32 + oh*4)*512 + ow*4;
  for (int ci = 0; ci < 3; ++ci){
    #pragma unroll
    for (int kh = 0; kh < 4; ++kh){
      float4 xv = *(const float4*)(x + xbase + ci*(32*512) + kh*512);
      #pragma unroll
      for (int cc = 0; cc < 4; ++cc){
        int co = c4*4 + cc;
        const float* wp = w + ((co*3 + ci)*4 + kh)*4;
        acc[cc] += xv.x*wp[0] + xv.y*wp[1] + xv.z*wp[2] + xv.w*wp[3];
      }
    }
  }
  #pragma unroll
  for (int cc = 0; cc < 4; ++cc){
    int co = c4*4 + cc;
    float v = acc[cc] + bias[co];
    v = bnf_(v, bng[co], bnb[co], bnm[co], bnv[co]);
    h[((b*NH + co)*HF + oh)*WF + ow] = gelu_(v);
  }
}

// ---------------- depthwise 3x3 (blk idx 1) + BN + GELU + residual -> t -------
__global__ __launch_bounds__(256) void k_dw(const float* __restrict__ h,
    const float* __restrict__ dww, const float* __restrict__ dwb,
    const float* __restrict__ g1, const float* __restrict__ b1,
    const float* __restrict__ m1, const float* __restrict__ v1,
    float* __restrict__ t)
{
  int tid = blockIdx.x*256 + threadIdx.x;   // 2097152
  int ow = tid & 127;
  int oh = (tid >> 7) & 7;
  int c  = (tid >> 10) & 127;
  int b  = tid >> 17;
  const float* wp = dww + NH*9 + c*9;       // block index 1
  const float* hp = h + ((b*NH + c)*HF)*WF;
  float acc = 0.f;
  #pragma unroll
  for (int kh = 0; kh < 3; ++kh){
    int ih = oh + kh - 1;
    if (ih < 0 || ih >= HF) continue;
    #pragma unroll
    for (int kw = 0; kw < 3; ++kw){
      int iw = ow + kw - 1;
      if (iw < 0 || iw >= WF) continue;
      acc += hp[ih*WF + iw]*wp[kh*3 + kw];
    }
  }
  float val = acc + dwb[NH + c];
  val = bnf_(val, g1[NH + c], b1[NH + c], m1[NH + c], v1[NH + c]);
  t[tid] = hp[oh*WF + ow] + gelu_(val);
}

// ---------------- transpose pw weights: pwT[ci][co] = pw[1][co][ci] ----------
__global__ void k_pwT(const float* __restrict__ pw, float* __restrict__ pwT){
  int tid = blockIdx.x*256 + threadIdx.x;   // 16384
  int ci = tid & 127; int co = tid >> 7;
  pwT[ci*128 + co] = pw[16384 + co*128 + ci];
}

// ---------------- pointwise 128x128 (blk idx 1) + BN + GELU -> feat ----------
__global__ __launch_bounds__(512) void k_pw(const float* __restrict__ t,
    const float* __restrict__ pwT, const float* __restrict__ pwb,
    const float* __restrict__ g2, const float* __restrict__ b2,
    const float* __restrict__ m2, const float* __restrict__ v2,
    float* __restrict__ feat)
{
  int bid = blockIdx.x;                     // (b, oh, whalf): 256 blocks
  int wh = bid & 1; int oh = (bid >> 1) & 7; int b = bid >> 4;
  int w0 = wh*64;
  int tid = threadIdx.x;
  __shared__ __align__(16) float tile[128*64];
  for (int i = 0; i < 16; ++i){
    int e = i*512 + tid; int ci = e >> 6; int wloc = e & 63;
    tile[ci*64 + wloc] = t[((b*NH + ci)*HF + oh)*WF + w0 + wloc];
  }
  __syncthreads();
  int co = tid & 127; int wq = tid >> 7;
  float acc[16];
  #pragma unroll
  for (int i = 0; i < 16; ++i) acc[i] = 0.f;
  for (int ci = 0; ci < 128; ++ci){
    float wt = pwT[ci*128 + co];
    const float4* tp = (const float4*)(tile + ci*64 + wq*16);
    #pragma unroll
    for (int j = 0; j < 4; ++j){
      float4 tv = tp[j];
      acc[j*4+0] += tv.x*wt; acc[j*4+1] += tv.y*wt;
      acc[j*4+2] += tv.z*wt; acc[j*4+3] += tv.w*wt;
    }
  }
  float bb = pwb[128 + co];
  float gg = g2[128 + co], bc = b2[128 + co], mm = m2[128 + co], vv = v2[128 + co];
  float* op = feat + ((b*NH + co)*HF + oh)*WF + w0 + wq*16;
  #pragma unroll
  for (int i = 0; i < 16; ++i){
    float v = bnf_(acc[i] + bb, gg, bc, mm, vv);
    op[i] = gelu_(v);
  }
}

// ---------------- enc xp GEMM: (2048x1024)@(192x1024)^T + bih -> xp ----------
__global__ __launch_bounds__(256) void k_encxp(const float* __restrict__ feat,
    const float* __restrict__ wih, const float* __restrict__ bih,
    float* __restrict__ xp)
{
  int m0 = blockIdx.x*32;     // 64 m-tiles
  int n0 = blockIdx.y*48;     // 4 n-tiles
  int b  = m0 >> 7;
  int w0 = m0 & 127;
  int tid = threadIdx.x;
  __shared__ float As[64*33];  // [k][m]
  __shared__ float Bs[64*49];  // [k][n]
  int tx = tid & 15, ty = tid >> 4;
  float acc[2][3] = {{0.f,0.f,0.f},{0.f,0.f,0.f}};
  for (int kt = 0; kt < 16; ++kt){
    int k0 = kt*64;
    #pragma unroll
    for (int i = 0; i < 8; ++i){
      int e = i*256 + tid; int kd = e >> 5; int mi = e & 31;
      int kg = k0 + kd;
      As[kd*33 + mi] = feat[((b*NH + (kg >> 3))*HF + (kg & 7))*WF + w0 + mi];
    }
    #pragma unroll
    for (int i = 0; i < 12; ++i){
      int e = i*256 + tid; int gi = e >> 6; int kd = e & 63;
      Bs[kd*49 + gi] = wih[(n0 + gi)*1024 + k0 + kd];
    }
    __syncthreads();
    for (int kd = 0; kd < 64; ++kd){
      float a0 = As[kd*33 + ty*2], a1 = As[kd*33 + ty*2 + 1];
      float b0 = Bs[kd*49 + tx*3], b1 = Bs[kd*49 + tx*3 + 1], b2 = Bs[kd*49 + tx*3 + 2];
      acc[0][0] += a0*b0; acc[0][1] += a0*b1; acc[0][2] += a0*b2;
      acc[1][0] += a1*b0; acc[1][1] += a1*b1; acc[1][2] += a1*b2;
    }
    __syncthreads();
  }
  #pragma unroll
  for (int i = 0; i < 2; ++i){
    int m = m0 + ty*2 + i;
    #pragma unroll
    for (int j = 0; j < 3; ++j){
      int g = n0 + tx*3 + j;
      xp[m*G3 + g] = acc[i][j] + bih[g];
    }
  }
}

// ---------------- GRU scan, single-wave, barrier-free, weights in VGPRs ------
// Wave-synchronous: single wave64 per block; same-wave DS ordering makes
// __syncthreads unnecessary (removes per-step vmcnt(0) drain of xp prefetch).
template<int STEPS, bool WRITE_ALL>
__global__ __launch_bounds__(64, 1) void k_scan(const float* __restrict__ xp,
    const float* __restrict__ whh, const float* __restrict__ bhh,
    float* __restrict__ outp)
{
  __shared__ float hsh[HID];
  int g = threadIdx.x;     // 0..63
  int b = blockIdx.x;
  f32x4 w0[16], w1[16], w2[16];
  const f32x4* p0 = (const f32x4*)(whh + g*HID);
  const f32x4* p1 = (const f32x4*)(whh + (HID + g)*HID);
  const f32x4* p2 = (const f32x4*)(whh + (2*HID + g)*HID);
  #pragma unroll
  for (int k = 0; k < 16; ++k){ w0[k] = p0[k]; w1[k] = p1[k]; w2[k] = p2[k]; }
  float b0 = bhh[g], b1 = bhh[HID + g], b2 = bhh[2*HID + g];
  float hg = 0.f;
  hsh[g] = 0.f;
  const float* xpb = xp + b*STEPS*G3;
  float x0 = xpb[g], x1 = xpb[HID + g], x2 = xpb[2*HID + g];
  for (int t = 0; t < STEPS; ++t){
    float x0n = 0.f, x1n = 0.f, x2n = 0.f;
    if (t + 1 < STEPS){
      const float* p = xpb + (t + 1)*G3 + g;
      x0n = p[0]; x1n = p[HID]; x2n = p[2*HID];
    }
    f32x4 a0{0.f,0.f,0.f,0.f}, a1{0.f,0.f,0.f,0.f}, a2{0.f,0.f,0.f,0.f};
    f32x4 c0{0.f,0.f,0.f,0.f}, c1{0.f,0.f,0.f,0.f}, c2{0.f,0.f,0.f,0.f};
    const f32x4* h4 = (const f32x4*)hsh;
    #pragma unroll
    for (int k = 0; k < 16; k += 2){
      f32x4 hA = h4[k], hB = h4[k+1];
      a0 += w0[k]*hA; c0 += w0[k+1]*hB;
      a1 += w1[k]*hA; c1 += w1[k+1]*hB;
      a2 += w2[k]*hA; c2 += w2[k+1]*hB;
    }
    a0 += c0; a1 += c1; a2 += c2;
    float hp0 = (a0[0] + a0[1]) + (a0[2] + a0[3]) + b0;
    float hp1 = (a1[0] + a1[1]) + (a1[2] + a1[3]) + b1;
    float hp2 = (a2[0] + a2[1]) + (a2[2] + a2[3]) + b2;
    float e0 = __expf(-(x0 + hp0));
    float r  = __builtin_amdgcn_rcpf(1.0f + e0);
    float e1 = __expf(-(x1 + hp1));
    float z  = __builtin_amdgcn_rcpf(1.0f + e1);
    float ag = x2 + r*hp2;
    float ex = __expf(2.0f*ag);
    float n  = 1.0f - 2.0f*__builtin_amdgcn_rcpf(ex + 1.0f);
    hg = z*(hg - n) + n;
    if (WRITE_ALL) outp[(b*TDEC + t)*HID + g] = hg;
    x0 = x0n; x1 = x1n; x2 = x2n;
    hsh[g] = hg;
  }
  if (!WRITE_ALL) outp[(b*TDEC)*HID + g] = hg;
}

// ---------------- embedding fill: indec rows 1..40 ---------------------------
__global__ void k_embed(const int* __restrict__ tgt, const float* __restrict__ emb,
                        float* __restrict__ indec)
{
  int tid = blockIdx.x*256 + threadIdx.x;   // 40960
  if (tid >= B_*T_*HID) return;
  int j = tid & 63; int rest = tid >> 6;
  int t = rest % T_; int b = rest / T_;
  int cls = tgt[b*T_ + t];
  indec[(b*TDEC + 1 + t)*HID + j] = emb[cls*HID + j];
}

// ---------------- dec xp: (656x64)@(192x64)^T + bih --------------------------
__global__ void k_xpd(const float* __restrict__ indec, const float* __restrict__ wih,
                      const float* __restrict__ bih, float* __restrict__ xpd)
{
  int tid = blockIdx.x*256 + threadIdx.x;   // 125952
  if (tid >= B_*TDEC*G3) return;
  int g = tid % G3; int bt = tid / G3;
  const float4* r4 = (const float4*)(indec + bt*HID);
  const float4* w4 = (const float4*)(wih + g*HID);
  float acc = bih[g];
  #pragma unroll
  for (int j = 0; j < 16; ++j){
    float4 rv = r4[j], wv = w4[j];
    acc += rv.x*wv.x + rv.y*wv.y + rv.z*wv.z + rv.w*wv.w;
  }
  xpd[tid] = acc;
}

// ---------------- q = y @ q_w^T + q_b ---------------------------------------
__global__ void k_q(const float* __restrict__ y, const float* __restrict__ qw,
                    const float* __restrict__ qb0, float* __restrict__ q)
{
  int tid = blockIdx.x*256 + threadIdx.x;   // 83968
  if (tid >= B_*TDEC*NH) return;
  int co = tid & 127; int bt = tid >> 7;
  const float4* r4 = (const float4*)(y + bt*HID);
  const float4* w4 = (const float4*)(qw + co*HID);
  float acc = qb0[co];
  #pragma unroll
  for (int j = 0; j < 16; ++j){
    float4 rv = r4[j], wv = w4[j];
    acc += rv.x*wv.x + rv.y*wv.y + rv.z*wv.z + rv.w*wv.w;
  }
  q[tid] = acc;
}

// ---------------- k-conv weight prep: fragment-ordered fp16 A ---------------
__global__ void k_wprep(const float* __restrict__ kw, _Float16* __restrict__ kwA)
{
  int tid = blockIdx.x*256 + threadIdx.x;   // 147456
  if (tid >= 36*8*64*8) return;
  int j = tid & 7;
  int l = (tid >> 3) & 63;
  int f = (tid >> 9) & 7;
  int s = tid >> 12;
  int co = f*16 + (l & 15);
  int k  = s*32 + ((l >> 4) << 3) + j;
  int r  = k >> 7;
  int ci = k & 127;
  kwA[tid] = (_Float16)kw[(co*128 + ci)*9 + r];
}

// ---------------- k conv 3x3 pad 1 via fp16 MFMA, barrier-free 1-wave blocks -
__global__ __launch_bounds__(64) void k_kconv3(const float* __restrict__ feat,
    const uint4* __restrict__ kwA4, const float* __restrict__ kb,
    float* __restrict__ ko)
{
  int bid = blockIdx.x;
  int mq = bid & 3;
  int cs = (bid >> 2) & 3;
  int wq = (bid >> 4) & 1;
  int oh = (bid >> 5) & 7;
  int b  = bid >> 8;
  int l  = threadIdx.x;
  int w0 = wq*64 + mq*16;
  int iwb = w0 + (l & 15);
  int cib = (l >> 4) << 3;

  f32x4 acc0{0.f,0.f,0.f,0.f}, acc1{0.f,0.f,0.f,0.f};
  uint4 a0A, a0B, a1A, a1B;
  float b0v[8], b1v[8];

  #define ISS(s, aX, aY, bvv) {                                               \
    aX = kwA4[(s)*512 + cs*128 + l];                                          \
    aY = kwA4[(s)*512 + cs*128 + 64 + l];                                     \
    int r = (s) >> 2; int dh = r/3 - 1; int dw2 = r%3 - 1;                    \
    int ci0 = ((s) & 3) << 5;                                                 \
    int ih = oh + dh; int iw = iwb + dw2;                                     \
    bool ok = (ih >= 0) & (ih < HF) & (iw >= 0) & (iw < WF);                  \
    const float* fp = feat + ((b*NH + ci0 + cib)*HF + ih)*WF + iw;            \
    _Pragma("unroll")                                                         \
    for (int jj = 0; jj < 8; ++jj) bvv[jj] = ok ? fp[jj*(HF*WF)] : 0.f;       \
  }
  #define CMP(aX, aY, bvv) {                                                  \
    half8 bf;                                                                 \
    _Pragma("unroll")                                                         \
    for (int jj = 0; jj < 8; ++jj) bf[jj] = (_Float16)bvv[jj];                \
    half8 af0 = __builtin_bit_cast(half8, aX);                                \
    half8 af1 = __builtin_bit_cast(half8, aY);                                \
    acc0 = __builtin_amdgcn_mfma_f32_16x16x32_f16(af0, bf, acc0, 0, 0, 0);    \
    acc1 = __builtin_amdgcn_mfma_f32_16x16x32_f16(af1, bf, acc1, 0, 0, 0);    \
  }

  ISS(0, a0A, a0B, b0v);
  for (int s = 0; s < 36; s += 2){
    if (s + 1 < 36) ISS(s + 1, a1A, a1B, b1v);
    CMP(a0A, a0B, b0v);
    if (s + 2 < 36) ISS(s + 2, a0A, a0B, b0v);
    if (s + 1 < 36) CMP(a1A, a1B, b1v);
  }
  #undef ISS
  #undef CMP

  int m = w0 + (l & 15);
  #pragma unroll
  for (int q = 0; q < 4; ++q){
    int co0 = cs*32 + ((l >> 4) << 2) + q;
    int co1 = co0 + 16;
    ko[((b*NH + co0)*HF + oh)*WF + m] = acc0[q] + kb[co0];
    ko[((b*NH + co1)*HF + oh)*WF + m] = acc1[q] + kb[co1];
  }
}

// ---------------- e[b,t,s] = sum_c e_w[c]*tanh(k[b,c,s] + q[b,t,c]) + e_b ----
__global__ __launch_bounds__(256) void k_e2(const float* __restrict__ k,
    const float* __restrict__ q, const float* __restrict__ ew,
    const float* __restrict__ eb, float* __restrict__ e)
{
  int bid = blockIdx.x;                 // 256 blocks: (b, st)
  int st = bid & 15; int b = bid >> 4;
  int s0 = st*64;
  int tid = threadIdx.x;
  __shared__ float ksh[NH*64];          // 32 KB: k[b, c, s0..s0+63]
  __shared__ float qsh[TDEC*NH];        // 21 KB: q[b, :, :]
  __shared__ float ewsh[NH];
  #pragma unroll
  for (int i = 0; i < 32; ++i){
    int e2 = i*256 + tid; int c = e2 >> 6; int j = e2 & 63;
    ksh[e2] = k[(b*NH + c)*SPAT + s0 + j];
  }
  #pragma unroll
  for (int i = 0; i < 21; ++i){
    int e2 = i*256 + tid;
    if (e2 < TDEC*NH) qsh[e2] = q[b*TDEC*NH + e2];
  }
  if (tid < NH) ewsh[tid] = ew[tid];
  __syncthreads();
  int sl = tid & 63; int tp = tid >> 6;
  float ebv = eb[0];
  for (int t = tp; t < TDEC; t += 4){
    const float* qr = qsh + t*NH;
    float acc = ebv;
    #pragma unroll 8
    for (int c = 0; c < NH; ++c){
      float v = ksh[c*64 + sl] + qr[c];
      float ex = __expf(2.0f*v);
      float rc = __builtin_amdgcn_rcpf(ex + 1.0f);
      acc += ewsh[c]*(1.0f - 2.0f*rc);
    }
    e[(b*TDEC + t)*SPAT + s0 + sl] = acc;
  }
}

// ---------------- softmax over 1024 per (b,t), in-place ----------------------
__global__ __launch_bounds__(256) void k_softmax(float* __restrict__ e)
{
  int bt = blockIdx.x; int tid = threadIdx.x;
  float* row = e + bt*SPAT;
  __shared__ float red[256];
  float v[4];
  #pragma unroll
  for (int i = 0; i < 4; ++i) v[i] = row[tid + i*256];
  float m = fmaxf(fmaxf(v[0], v[1]), fmaxf(v[2], v[3]));
  red[tid] = m; __syncthreads();
  for (int s = 128; s > 0; s >>= 1){
    if (tid < s) red[tid] = fmaxf(red[tid], red[tid + s]);
    __syncthreads();
  }
  float mx = red[0];
  __syncthreads();
  float ev[4]; float sum = 0.f;
  #pragma unroll
  for (int i = 0; i < 4; ++i){ ev[i] = __expf(v[i] - mx); sum += ev[i]; }
  red[tid] = sum; __syncthreads();
  for (int s = 128; s > 0; s >>= 1){
    if (tid < s) red[tid] += red[tid + s];
    __syncthreads();
  }
  float inv = 1.f/red[0];
  #pragma unroll
  for (int i = 0; i < 4; ++i) row[tid + i*256] = ev[i]*inv;
}

// ---------------- attn_feat[b,t,c] = sum_s feat[b,c,s]*a[b,t,s] --------------
__global__ __launch_bounds__(256) void k_attnf(const float* __restrict__ feat,
    const float* __restrict__ a, float* __restrict__ attnf)
{
  int bid = blockIdx.x;                  // (b, tq(11), ch(2)): 352 blocks
  int ch = bid & 1; int rest = bid >> 1;
  int tq = rest % 11; int b = rest / 11;
  int tid = threadIdx.x;
  __shared__ __align__(16) float ash[4*SPAT];
  __shared__ float psh[4*4*64];
  for (int i = 0; i < 16; ++i){
    int e = i*256 + tid; int tt = e >> 10; int s = e & 1023;
    int t = tq*4 + tt;
    ash[e] = (t < TDEC) ? a[(b*TDEC + t)*SPAT + s] : 0.f;
  }
  __syncthreads();
  int cl = tid & 63; int sq = tid >> 6;
  const float* fp = feat + (b*NH + ch*64 + cl)*SPAT + sq*256;
  float acc[4] = {0.f,0.f,0.f,0.f};
  for (int i = 0; i < 64; ++i){
    float4 fv = *(const float4*)(fp + i*4);
    #pragma unroll
    for (int tt = 0; tt < 4; ++tt){
      const float* ar = ash + tt*SPAT + sq*256 + i*4;
      acc[tt] += fv.x*ar[0] + fv.y*ar[1] + fv.z*ar[2] + fv.w*ar[3];
    }
  }
  #pragma unroll
  for (int tt = 0; tt < 4; ++tt) psh[(sq*4 + tt)*64 + cl] = acc[tt];
  __syncthreads();
  {
    int tt = tid >> 6; int c2 = tid & 63;
    int t = tq*4 + tt;
    if (t < TDEC){
      float v = psh[(0*4 + tt)*64 + c2] + psh[(1*4 + tt)*64 + c2]
              + psh[(2*4 + tt)*64 + c2] + psh[(3*4 + tt)*64 + c2];
      attnf[(b*TDEC + t)*NH + ch*64 + c2] = v;
    }
  }
}

// ---------------- out = attnf @ fc_w^T + fc_b --------------------------------
__global__ __launch_bounds__(256) void k_fc(const float* __restrict__ attnf,
    const float* __restrict__ fcw, const float* __restrict__ fcb,
    float* __restrict__ out)
{
  int n0 = blockIdx.x*64;   // 104 cls-tiles
  int m0 = blockIdx.y*32;   // 21 m-tiles
  int tid = threadIdx.x;
  __shared__ __align__(16) float at[128*36];   // [j][m]
  __shared__ __align__(16) float wt[128*68];   // [j][cls]
  __shared__ float bsh[64];
  for (int i = 0; i < 16; ++i){
    int e = i*256 + tid; int m = e >> 7; int j = e & 127;
    at[j*36 + m] = (m0 + m < B_*TDEC) ? attnf[(m0 + m)*NH + j] : 0.f;
  }
  for (int i = 0; i < 32; ++i){
    int e = i*256 + tid; int cl = e >> 7; int j = e & 127;
    int n = n0 + cl;
    wt[j*68 + cl] = (n < NCLS) ? fcw[n*NH + j] : 0.f;
  }
  if (tid < 64) bsh[tid] = (n0 + tid < NCLS) ? fcb[n0 + tid] : 0.f;
  __syncthreads();
  int tn = tid & 15, tm = tid >> 4;
  float acc[2][4] = {{0.f,0.f,0.f,0.f},{0.f,0.f,0.f,0.f}};
  for (int j = 0; j < 128; ++j){
    float2 av = *(const float2*)(at + j*36 + tm*2);
    float4 wv = *(const float4*)(wt + j*68 + tn*4);
    acc[0][0] += av.x*wv.x; acc[0][1] += av.x*wv.y;
    acc[0][2] += av.x*wv.z; acc[0][3] += av.x*wv.w;
    acc[1][0] += av.y*wv.x; acc[1][1] += av.y*wv.y;
    acc[1][2] += av.y*wv.z; acc[1][3] += av.y*wv.w;
  }
  #pragma unroll
  for (int i = 0; i < 2; ++i){
    int m = m0 + tm*2 + i;
    if (m < B_*TDEC){
      #pragma unroll
      for (int ii = 0; ii < 4; ++ii){
        int n = n0 + tn*4 + ii;
        if (n < NCLS) out[m*NCLS + n] = acc[i][ii] + bsh[tn*4 + ii];
      }
    }
  }
}

// ============================================================================
extern "C" void kernel_launch(void* const* d_in, const int* in_sizes, int n_in,
                              void* d_out, int out_size, void* d_ws, size_t ws_size,
                              hipStream_t stream)
{
  (void)in_sizes; (void)n_in; (void)out_size; (void)ws_size;
  const float* x      = (const float*)d_in[0];
  const int*   tgt    = (const int*)  d_in[1];
  const float* conv0w = (const float*)d_in[2];
  const float* conv0b = (const float*)d_in[3];
  const float* bn0g   = (const float*)d_in[4];
  const float* bn0b   = (const float*)d_in[5];
  const float* bn0m   = (const float*)d_in[6];
  const float* bn0v   = (const float*)d_in[7];
  const float* dww    = (const float*)d_in[8];
  const float* dwb    = (const float*)d_in[9];
  const float* bn1g   = (const float*)d_in[10];
  const float* bn1b   = (const float*)d_in[11];
  const float* bn1m   = (const float*)d_in[12];
  const float* bn1v   = (const float*)d_in[13];
  const float* pww    = (const float*)d_in[14];
  const float* pwb    = (const float*)d_in[15];
  const float* bn2g   = (const float*)d_in[16];
  const float* bn2b   = (const float*)d_in[17];
  const float* bn2m   = (const float*)d_in[18];
  const float* bn2v   = (const float*)d_in[19];
  const float* encwih = (const float*)d_in[20];
  const float* encwhh = (const float*)d_in[21];
  const float* encbih = (const float*)d_in[22];
  const float* encbhh = (const float*)d_in[23];
  const float* decwih = (const float*)d_in[24];
  const float* decwhh = (const float*)d_in[25];
  const float* decbih = (const float*)d_in[26];
  const float* decbhh = (const float*)d_in[27];
  const float* emb    = (const float*)d_in[28];
  const float* qw     = (const float*)d_in[29];
  const float* qb0    = (const float*)d_in[30];
  const float* kw     = (const float*)d_in[31];
  const float* kb     = (const float*)d_in[32];
  const float* ew     = (const float*)d_in[33];
  const float* eb     = (const float*)d_in[34];
  const float* fcw    = (const float*)d_in[35];
  const float* fcb    = (const float*)d_in[36];

  float* ws    = (float*)d_ws;
  float* hbuf  = ws + 0;         // 2097152
  float* tbuf  = ws + 2097152;   // 2097152 (t; later: ebuf + kwA)
  float* feat  = ws + 4194304;   // 2097152
  float* xp    = ws + 6291456;   // 393216
  float* indec = ws + 6684672;   // 41984
  float* xpd   = ws + 6726656;   // 125952
  float* ybuf  = ws + 6852608;   // 41984
  float* qbuf  = ws + 6894592;   // 83968
  float* attf  = ws + 6978560;   // 83968
  float* pwT   = ws + 7062528;   // 16384
  float* kbuf  = hbuf;           // alias: h dead after k_dw
  float* ebuf  = tbuf;           // alias: t dead after k_pw (671744 floats)
  _Float16* kwA = (_Float16*)(tbuf + 1048576); // 147456 halves, inside dead tbuf
  float* out   = (float*)d_out;

  hipLaunchKernelGGL(k_pwT,     dim3(64),          dim3(256), 0, stream, pww, pwT);
  hipLaunchKernelGGL(k_conv0,   dim3(2048),        dim3(256), 0, stream,
                     x, conv0w, conv0b, bn0g, bn0b, bn0m, bn0v, hbuf);
  hipLaunchKernelGGL(k_dw,      dim3(8192),        dim3(256), 0, stream,
                     hbuf, dww, dwb, bn1g, bn1b, bn1m, bn1v, tbuf);
  hipLaunchKernelGGL(k_pw,      dim3(256),         dim3(512), 0, stream,
                     tbuf, pwT, pwb, bn2g, bn2b, bn2m, bn2v, feat);
  hipLaunchKernelGGL(k_wprep,   dim3(576),         dim3(256), 0, stream, kw, kwA);
  hipLaunchKernelGGL(k_embed,   dim3(160),         dim3(256), 0, stream, tgt, emb, indec);
  hipLaunchKernelGGL(k_encxp,   dim3(64, 4),       dim3(256), 0, stream,
                     feat, encwih, encbih, xp);
  hipLaunchKernelGGL((k_scan<128,false>), dim3(16), dim3(64), 0, stream,
                     xp, encwhh, encbhh, indec);
  hipLaunchKernelGGL(k_xpd,     dim3(492),         dim3(256), 0, stream,
                     indec, decwih, decbih, xpd);
  hipLaunchKernelGGL((k_scan<TDEC,true>), dim3(16), dim3(64), 0, stream,
                     xpd, decwhh, decbhh, ybuf);
  hipLaunchKernelGGL(k_q,       dim3(328),         dim3(256), 0, stream,
                     ybuf, qw, qb0, qbuf);
  hipLaunchKernelGGL(k_kconv3,  dim3(4096),        dim3(64), 0, stream,
                     feat, (const uint4*)kwA, kb, kbuf);
  hipLaunchKernelGGL(k_e2,      dim3(256),         dim3(256), 0, stream,
                     kbuf, qbuf, ew, eb, ebuf);
  hipLaunchKernelGGL(k_softmax, dim3(B_*TDEC),     dim3(256), 0, stream, ebuf);
  hipLaunchKernelGGL(k_attnf,   dim3(352),         dim3(256), 0, stream,
                     feat, ebuf, attf);
  hipLaunchKernelGGL(k_fc,      dim3(104, 21),     dim3(256), 0, stream,
                     attf, fcw, fcb, out);
}

// Round 7
// 352.611 us; speedup vs baseline: 1.4415x; 1.0567x over previous
//
#include <hip/hip_runtime.h>
#include <hip/hip_bf16.h>

#define DEV __device__ __forceinline__

#define B_    16
#define T_    40
#define TDEC  41
#define NH    128
#define HF    8
#define WF    128
#define HID   64
#define G3    192
#define NCLS  6625
#define SPAT  1024

typedef _Float16 half8 __attribute__((ext_vector_type(8)));
typedef float    f32x4 __attribute__((ext_vector_type(4)));
typedef float    f32x2 __attribute__((ext_vector_type(2)));

DEV float sigmoidf_(float x){ return 1.0f/(1.0f + __expf(-x)); }
DEV float tanhf_(float x){ float e = __expf(2.0f*x); return 1.0f - 2.0f/(e + 1.0f); }
DEV float gelu_(float x){ return 0.5f*x*(1.0f + erff(x*0.70710678118654752f)); }
DEV float bnf_(float x, float g, float b, float m, float v){
  return (x - m)*rsqrtf(v + 1e-5f)*g + b;
}

// ---------------- conv0 4x4 s4 + BN + GELU -> h (16,128,8,128) ----------------
__global__ __launch_bounds__(256) void k_conv0(const float* __restrict__ x,
    const float* __restrict__ w, const float* __restrict__ bias,
    const float* __restrict__ bng, const float* __restrict__ bnb,
    const float* __restrict__ bnm, const float* __restrict__ bnv,
    float* __restrict__ h)
{
  int tid = blockIdx.x*256 + threadIdx.x;   // 524288 threads, 4 co each
  int ow = tid & 127;
  int oh = (tid >> 7) & 7;
  int c4 = (tid >> 10) & 31;
  int b  = tid >> 15;
  float acc[4] = {0.f,0.f,0.f,0.f};
  int xbase = ((b*3)*32 + oh*4)*512 + ow*4;
  for (int ci = 0; ci < 3; ++ci){
    #pragma unroll
    for (int kh = 0; kh < 4; ++kh){
      float4 xv = *(const float4*)(x + xbase + ci*(32*512) + kh*512);
      #pragma unroll
      for (int cc = 0; cc < 4; ++cc){
        int co = c4*4 + cc;
        const float* wp = w + ((co*3 + ci)*4 + kh)*4;
        acc[cc] += xv.x*wp[0] + xv.y*wp[1] + xv.z*wp[2] + xv.w*wp[3];
      }
    }
  }
  #pragma unroll
  for (int cc = 0; cc < 4; ++cc){
    int co = c4*4 + cc;
    float v = acc[cc] + bias[co];
    v = bnf_(v, bng[co], bnb[co], bnm[co], bnv[co]);
    h[((b*NH + co)*HF + oh)*WF + ow] = gelu_(v);
  }
}

// ---------------- depthwise 3x3 (blk idx 1) + BN + GELU + residual -> t -------
__global__ __launch_bounds__(256) void k_dw(const float* __restrict__ h,
    const float* __restrict__ dww, const float* __restrict__ dwb,
    const float* __restrict__ g1, const float* __restrict__ b1,
    const float* __restrict__ m1, const float* __restrict__ v1,
    float* __restrict__ t)
{
  int tid = blockIdx.x*256 + threadIdx.x;   // 2097152
  int ow = tid & 127;
  int oh = (tid >> 7) & 7;
  int c  = (tid >> 10) & 127;
  int b  = tid >> 17;
  const float* wp = dww + NH*9 + c*9;       // block index 1
  const float* hp = h + ((b*NH + c)*HF)*WF;
  float acc = 0.f;
  #pragma unroll
  for (int kh = 0; kh < 3; ++kh){
    int ih = oh + kh - 1;
    if (ih < 0 || ih >= HF) continue;
    #pragma unroll
    for (int kw = 0; kw < 3; ++kw){
      int iw = ow + kw - 1;
      if (iw < 0 || iw >= WF) continue;
      acc += hp[ih*WF + iw]*wp[kh*3 + kw];
    }
  }
  float val = acc + dwb[NH + c];
  val = bnf_(val, g1[NH + c], b1[NH + c], m1[NH + c], v1[NH + c]);
  t[tid] = hp[oh*WF + ow] + gelu_(val);
}

// ---------------- transpose pw weights: pwT[ci][co] = pw[1][co][ci] ----------
__global__ void k_pwT(const float* __restrict__ pw, float* __restrict__ pwT){
  int tid = blockIdx.x*256 + threadIdx.x;   // 16384
  int ci = tid & 127; int co = tid >> 7;
  pwT[ci*128 + co] = pw[16384 + co*128 + ci];
}

// ---------------- pointwise 128x128 (blk idx 1) + BN + GELU -> feat ----------
__global__ __launch_bounds__(512) void k_pw(const float* __restrict__ t,
    const float* __restrict__ pwT, const float* __restrict__ pwb,
    const float* __restrict__ g2, const float* __restrict__ b2,
    const float* __restrict__ m2, const float* __restrict__ v2,
    float* __restrict__ feat)
{
  int bid = blockIdx.x;                     // (b, oh, whalf): 256 blocks
  int wh = bid & 1; int oh = (bid >> 1) & 7; int b = bid >> 4;
  int w0 = wh*64;
  int tid = threadIdx.x;
  __shared__ __align__(16) float tile[128*64];
  for (int i = 0; i < 16; ++i){
    int e = i*512 + tid; int ci = e >> 6; int wloc = e & 63;
    tile[ci*64 + wloc] = t[((b*NH + ci)*HF + oh)*WF + w0 + wloc];
  }
  __syncthreads();
  int co = tid & 127; int wq = tid >> 7;
  float acc[16];
  #pragma unroll
  for (int i = 0; i < 16; ++i) acc[i] = 0.f;
  for (int ci = 0; ci < 128; ++ci){
    float wt = pwT[ci*128 + co];
    const float4* tp = (const float4*)(tile + ci*64 + wq*16);
    #pragma unroll
    for (int j = 0; j < 4; ++j){
      float4 tv = tp[j];
      acc[j*4+0] += tv.x*wt; acc[j*4+1] += tv.y*wt;
      acc[j*4+2] += tv.z*wt; acc[j*4+3] += tv.w*wt;
    }
  }
  float bb = pwb[128 + co];
  float gg = g2[128 + co], bc = b2[128 + co], mm = m2[128 + co], vv = v2[128 + co];
  float* op = feat + ((b*NH + co)*HF + oh)*WF + w0 + wq*16;
  #pragma unroll
  for (int i = 0; i < 16; ++i){
    float v = bnf_(acc[i] + bb, gg, bc, mm, vv);
    op[i] = gelu_(v);
  }
}

// ---------------- enc xp GEMM: (2048x1024)@(192x1024)^T + bih -> xp ----------
__global__ __launch_bounds__(256) void k_encxp(const float* __restrict__ feat,
    const float* __restrict__ wih, const float* __restrict__ bih,
    float* __restrict__ xp)
{
  int m0 = blockIdx.x*32;     // 64 m-tiles
  int n0 = blockIdx.y*48;     // 4 n-tiles
  int b  = m0 >> 7;
  int w0 = m0 & 127;
  int tid = threadIdx.x;
  __shared__ float As[64*33];  // [k][m]
  __shared__ float Bs[64*49];  // [k][n]
  int tx = tid & 15, ty = tid >> 4;
  float acc[2][3] = {{0.f,0.f,0.f},{0.f,0.f,0.f}};
  for (int kt = 0; kt < 16; ++kt){
    int k0 = kt*64;
    #pragma unroll
    for (int i = 0; i < 8; ++i){
      int e = i*256 + tid; int kd = e >> 5; int mi = e & 31;
      int kg = k0 + kd;
      As[kd*33 + mi] = feat[((b*NH + (kg >> 3))*HF + (kg & 7))*WF + w0 + mi];
    }
    #pragma unroll
    for (int i = 0; i < 12; ++i){
      int e = i*256 + tid; int gi = e >> 6; int kd = e & 63;
      Bs[kd*49 + gi] = wih[(n0 + gi)*1024 + k0 + kd];
    }
    __syncthreads();
    for (int kd = 0; kd < 64; ++kd){
      float a0 = As[kd*33 + ty*2], a1 = As[kd*33 + ty*2 + 1];
      float b0 = Bs[kd*49 + tx*3], b1 = Bs[kd*49 + tx*3 + 1], b2 = Bs[kd*49 + tx*3 + 2];
      acc[0][0] += a0*b0; acc[0][1] += a0*b1; acc[0][2] += a0*b2;
      acc[1][0] += a1*b0; acc[1][1] += a1*b1; acc[1][2] += a1*b2;
    }
    __syncthreads();
  }
  #pragma unroll
  for (int i = 0; i < 2; ++i){
    int m = m0 + ty*2 + i;
    #pragma unroll
    for (int j = 0; j < 3; ++j){
      int g = n0 + tx*3 + j;
      xp[m*G3 + g] = acc[i][j] + bih[g];
    }
  }
}

// ---------------- GRU scan, single-wave, barrier-free, weights in VGPRs ------
template<int STEPS, bool WRITE_ALL>
__global__ __launch_bounds__(64, 1) void k_scan(const float* __restrict__ xp,
    const float* __restrict__ whh, const float* __restrict__ bhh,
    float* __restrict__ outp)
{
  __shared__ float hsh[HID];
  int g = threadIdx.x;     // 0..63
  int b = blockIdx.x;
  f32x4 w0[16], w1[16], w2[16];
  const f32x4* p0 = (const f32x4*)(whh + g*HID);
  const f32x4* p1 = (const f32x4*)(whh + (HID + g)*HID);
  const f32x4* p2 = (const f32x4*)(whh + (2*HID + g)*HID);
  #pragma unroll
  for (int k = 0; k < 16; ++k){ w0[k] = p0[k]; w1[k] = p1[k]; w2[k] = p2[k]; }
  float b0 = bhh[g], b1 = bhh[HID + g], b2 = bhh[2*HID + g];
  float hg = 0.f;
  hsh[g] = 0.f;
  const float* xpb = xp + b*STEPS*G3;
  float x0 = xpb[g], x1 = xpb[HID + g], x2 = xpb[2*HID + g];
  for (int t = 0; t < STEPS; ++t){
    float x0n = 0.f, x1n = 0.f, x2n = 0.f;
    if (t + 1 < STEPS){
      const float* p = xpb + (t + 1)*G3 + g;
      x0n = p[0]; x1n = p[HID]; x2n = p[2*HID];
    }
    f32x4 a0{0.f,0.f,0.f,0.f}, a1{0.f,0.f,0.f,0.f}, a2{0.f,0.f,0.f,0.f};
    f32x4 c0{0.f,0.f,0.f,0.f}, c1{0.f,0.f,0.f,0.f}, c2{0.f,0.f,0.f,0.f};
    const f32x4* h4 = (const f32x4*)hsh;
    #pragma unroll
    for (int k = 0; k < 16; k += 2){
      f32x4 hA = h4[k], hB = h4[k+1];
      a0 += w0[k]*hA; c0 += w0[k+1]*hB;
      a1 += w1[k]*hA; c1 += w1[k+1]*hB;
      a2 += w2[k]*hA; c2 += w2[k+1]*hB;
    }
    a0 += c0; a1 += c1; a2 += c2;
    float hp0 = (a0[0] + a0[1]) + (a0[2] + a0[3]) + b0;
    float hp1 = (a1[0] + a1[1]) + (a1[2] + a1[3]) + b1;
    float hp2 = (a2[0] + a2[1]) + (a2[2] + a2[3]) + b2;
    float e0 = __expf(-(x0 + hp0));
    float r  = __builtin_amdgcn_rcpf(1.0f + e0);
    float e1 = __expf(-(x1 + hp1));
    float z  = __builtin_amdgcn_rcpf(1.0f + e1);
    float ag = x2 + r*hp2;
    float ex = __expf(2.0f*ag);
    float n  = 1.0f - 2.0f*__builtin_amdgcn_rcpf(ex + 1.0f);
    hg = z*(hg - n) + n;
    if (WRITE_ALL) outp[(b*TDEC + t)*HID + g] = hg;
    x0 = x0n; x1 = x1n; x2 = x2n;
    hsh[g] = hg;
  }
  if (!WRITE_ALL) outp[(b*TDEC)*HID + g] = hg;
}

// ---------------- embedding fill: indec rows 1..40 ---------------------------
__global__ void k_embed(const int* __restrict__ tgt, const float* __restrict__ emb,
                        float* __restrict__ indec)
{
  int tid = blockIdx.x*256 + threadIdx.x;   // 40960
  if (tid >= B_*T_*HID) return;
  int j = tid & 63; int rest = tid >> 6;
  int t = rest % T_; int b = rest / T_;
  int cls = tgt[b*T_ + t];
  indec[(b*TDEC + 1 + t)*HID + j] = emb[cls*HID + j];
}

// ---------------- dec xp: (656x64)@(192x64)^T + bih --------------------------
__global__ void k_xpd(const float* __restrict__ indec, const float* __restrict__ wih,
                      const float* __restrict__ bih, float* __restrict__ xpd)
{
  int tid = blockIdx.x*256 + threadIdx.x;   // 125952
  if (tid >= B_*TDEC*G3) return;
  int g = tid % G3; int bt = tid / G3;
  const float4* r4 = (const float4*)(indec + bt*HID);
  const float4* w4 = (const float4*)(wih + g*HID);
  float acc = bih[g];
  #pragma unroll
  for (int j = 0; j < 16; ++j){
    float4 rv = r4[j], wv = w4[j];
    acc += rv.x*wv.x + rv.y*wv.y + rv.z*wv.z + rv.w*wv.w;
  }
  xpd[tid] = acc;
}

// ---------------- q = y @ q_w^T + q_b ---------------------------------------
__global__ void k_q(const float* __restrict__ y, const float* __restrict__ qw,
                    const float* __restrict__ qb0, float* __restrict__ q)
{
  int tid = blockIdx.x*256 + threadIdx.x;   // 83968
  if (tid >= B_*TDEC*NH) return;
  int co = tid & 127; int bt = tid >> 7;
  const float4* r4 = (const float4*)(y + bt*HID);
  const float4* w4 = (const float4*)(qw + co*HID);
  float acc = qb0[co];
  #pragma unroll
  for (int j = 0; j < 16; ++j){
    float4 rv = r4[j], wv = w4[j];
    acc += rv.x*wv.x + rv.y*wv.y + rv.z*wv.z + rv.w*wv.w;
  }
  q[tid] = acc;
}

// ---------------- k-conv weight prep: fragment-ordered fp16 A ---------------
__global__ void k_wprep(const float* __restrict__ kw, _Float16* __restrict__ kwA)
{
  int tid = blockIdx.x*256 + threadIdx.x;   // 147456
  if (tid >= 36*8*64*8) return;
  int j = tid & 7;
  int l = (tid >> 3) & 63;
  int f = (tid >> 9) & 7;
  int s = tid >> 12;
  int co = f*16 + (l & 15);
  int k  = s*32 + ((l >> 4) << 3) + j;
  int r  = k >> 7;
  int ci = k & 127;
  kwA[tid] = (_Float16)kw[(co*128 + ci)*9 + r];
}

// ---------------- k conv 3x3 pad 1 via fp16 MFMA, barrier-free 1-wave blocks -
// XCD-aware decode: bid&7 selects a batch PAIR so each XCD's L2 caches only
// 2 batches of feat (1MB) + kwA (288KB) instead of thrashing on all 16.
__global__ __launch_bounds__(64) void k_kconv3(const float* __restrict__ feat,
    const uint4* __restrict__ kwA4, const float* __restrict__ kb,
    float* __restrict__ ko)
{
  int bid = blockIdx.x;
  int b  = ((bid & 7) << 1) | ((bid >> 3) & 1);   // bits 0-3 -> batch
  int mq = (bid >> 4) & 3;
  int cs = (bid >> 6) & 3;
  int wq = (bid >> 8) & 1;
  int oh = (bid >> 9) & 7;
  int l  = threadIdx.x;
  int w0 = wq*64 + mq*16;
  int iwb = w0 + (l & 15);
  int cib = (l >> 4) << 3;

  f32x4 acc0{0.f,0.f,0.f,0.f}, acc1{0.f,0.f,0.f,0.f};
  uint4 a0A, a0B, a1A, a1B;
  float b0v[8], b1v[8];

  #define ISS(s, aX, aY, bvv) {                                               \
    aX = kwA4[(s)*512 + cs*128 + l];                                          \
    aY = kwA4[(s)*512 + cs*128 + 64 + l];                                     \
    int r = (s) >> 2; int dh = r/3 - 1; int dw2 = r%3 - 1;                    \
    int ci0 = ((s) & 3) << 5;                                                 \
    int ih = oh + dh; int iw = iwb + dw2;                                     \
    bool ok = (ih >= 0) & (ih < HF) & (iw >= 0) & (iw < WF);                  \
    const float* fp = feat + ((b*NH + ci0 + cib)*HF + ih)*WF + iw;            \
    _Pragma("unroll")                                                         \
    for (int jj = 0; jj < 8; ++jj) bvv[jj] = ok ? fp[jj*(HF*WF)] : 0.f;       \
  }
  #define CMP(aX, aY, bvv) {                                                  \
    half8 bf;                                                                 \
    _Pragma("unroll")                                                         \
    for (int jj = 0; jj < 8; ++jj) bf[jj] = (_Float16)bvv[jj];                \
    half8 af0 = __builtin_bit_cast(half8, aX);                                \
    half8 af1 = __builtin_bit_cast(half8, aY);                                \
    acc0 = __builtin_amdgcn_mfma_f32_16x16x32_f16(af0, bf, acc0, 0, 0, 0);    \
    acc1 = __builtin_amdgcn_mfma_f32_16x16x32_f16(af1, bf, acc1, 0, 0, 0);    \
  }

  ISS(0, a0A, a0B, b0v);
  for (int s = 0; s < 36; s += 2){
    if (s + 1 < 36) ISS(s + 1, a1A, a1B, b1v);
    CMP(a0A, a0B, b0v);
    if (s + 2 < 36) ISS(s + 2, a0A, a0B, b0v);
    if (s + 1 < 36) CMP(a1A, a1B, b1v);
  }
  #undef ISS
  #undef CMP

  int m = w0 + (l & 15);
  #pragma unroll
  for (int q = 0; q < 4; ++q){
    int co0 = cs*32 + ((l >> 4) << 2) + q;
    int co1 = co0 + 16;
    ko[((b*NH + co0)*HF + oh)*WF + m] = acc0[q] + kb[co0];
    ko[((b*NH + co1)*HF + oh)*WF + m] = acc1[q] + kb[co1];
  }
}

// ---------------- e[b,t,s] = sum_c e_w[c]*tanh(k[b,c,s] + q[b,t,c]) + e_b ----
__global__ __launch_bounds__(256) void k_e2(const float* __restrict__ k,
    const float* __restrict__ q, const float* __restrict__ ew,
    const float* __restrict__ eb, float* __restrict__ e)
{
  int bid = blockIdx.x;                 // 256 blocks: (b, st)
  int st = bid & 15; int b = bid >> 4;
  int s0 = st*64;
  int tid = threadIdx.x;
  __shared__ float ksh[NH*64];          // 32 KB: k[b, c, s0..s0+63]
  __shared__ float qsh[TDEC*NH];        // 21 KB: q[b, :, :]
  __shared__ float ewsh[NH];
  #pragma unroll
  for (int i = 0; i < 32; ++i){
    int e2 = i*256 + tid; int c = e2 >> 6; int j = e2 & 63;
    ksh[e2] = k[(b*NH + c)*SPAT + s0 + j];
  }
  #pragma unroll
  for (int i = 0; i < 21; ++i){
    int e2 = i*256 + tid;
    if (e2 < TDEC*NH) qsh[e2] = q[b*TDEC*NH + e2];
  }
  if (tid < NH) ewsh[tid] = ew[tid];
  __syncthreads();
  int sl = tid & 63; int tp = tid >> 6;
  float ebv = eb[0];
  for (int t = tp; t < TDEC; t += 4){
    const float* qr = qsh + t*NH;
    float acc = ebv;
    #pragma unroll 8
    for (int c = 0; c < NH; ++c){
      float v = ksh[c*64 + sl] + qr[c];
      float ex = __expf(2.0f*v);
      float rc = __builtin_amdgcn_rcpf(ex + 1.0f);
      acc += ewsh[c]*(1.0f - 2.0f*rc);
    }
    e[(b*TDEC + t)*SPAT + s0 + sl] = acc;
  }
}

// ---------------- softmax over 1024 per (b,t), in-place ----------------------
__global__ __launch_bounds__(256) void k_softmax(float* __restrict__ e)
{
  int bt = blockIdx.x; int tid = threadIdx.x;
  float* row = e + bt*SPAT;
  __shared__ float red[256];
  float v[4];
  #pragma unroll
  for (int i = 0; i < 4; ++i) v[i] = row[tid + i*256];
  float m = fmaxf(fmaxf(v[0], v[1]), fmaxf(v[2], v[3]));
  red[tid] = m; __syncthreads();
  for (int s = 128; s > 0; s >>= 1){
    if (tid < s) red[tid] = fmaxf(red[tid], red[tid + s]);
    __syncthreads();
  }
  float mx = red[0];
  __syncthreads();
  float ev[4]; float sum = 0.f;
  #pragma unroll
  for (int i = 0; i < 4; ++i){ ev[i] = __expf(v[i] - mx); sum += ev[i]; }
  red[tid] = sum; __syncthreads();
  for (int s = 128; s > 0; s >>= 1){
    if (tid < s) red[tid] += red[tid + s];
    __syncthreads();
  }
  float inv = 1.f/red[0];
  #pragma unroll
  for (int i = 0; i < 4; ++i) row[tid + i*256] = ev[i]*inv;
}

// ---------------- attn_feat[b,t,c] = sum_s feat[b,c,s]*a[b,t,s] --------------
__global__ __launch_bounds__(256) void k_attnf(const float* __restrict__ feat,
    const float* __restrict__ a, float* __restrict__ attnf)
{
  int bid = blockIdx.x;                  // (b, tq(11), ch(2)): 352 blocks
  int ch = bid & 1; int rest = bid >> 1;
  int tq = rest % 11; int b = rest / 11;
  int tid = threadIdx.x;
  __shared__ __align__(16) float ash[4*SPAT];
  __shared__ float psh[4*4*64];
  for (int i = 0; i < 16; ++i){
    int e = i*256 + tid; int tt = e >> 10; int s = e & 1023;
    int t = tq*4 + tt;
    ash[e] = (t < TDEC) ? a[(b*TDEC + t)*SPAT + s] : 0.f;
  }
  __syncthreads();
  int cl = tid & 63; int sq = tid >> 6;
  const float* fp = feat + (b*NH + ch*64 + cl)*SPAT + sq*256;
  float acc[4] = {0.f,0.f,0.f,0.f};
  for (int i = 0; i < 64; ++i){
    float4 fv = *(const float4*)(fp + i*4);
    #pragma unroll
    for (int tt = 0; tt < 4; ++tt){
      const float* ar = ash + tt*SPAT + sq*256 + i*4;
      acc[tt] += fv.x*ar[0] + fv.y*ar[1] + fv.z*ar[2] + fv.w*ar[3];
    }
  }
  #pragma unroll
  for (int tt = 0; tt < 4; ++tt) psh[(sq*4 + tt)*64 + cl] = acc[tt];
  __syncthreads();
  {
    int tt = tid >> 6; int c2 = tid & 63;
    int t = tq*4 + tt;
    if (t < TDEC){
      float v = psh[(0*4 + tt)*64 + c2] + psh[(1*4 + tt)*64 + c2]
              + psh[(2*4 + tt)*64 + c2] + psh[(3*4 + tt)*64 + c2];
      attnf[(b*TDEC + t)*NH + ch*64 + c2] = v;
    }
  }
}

// ---------------- out = attnf @ fc_w^T + fc_b --------------------------------
__global__ __launch_bounds__(256) void k_fc(const float* __restrict__ attnf,
    const float* __restrict__ fcw, const float* __restrict__ fcb,
    float* __restrict__ out)
{
  int n0 = blockIdx.x*64;   // 104 cls-tiles
  int m0 = blockIdx.y*32;   // 21 m-tiles
  int tid = threadIdx.x;
  __shared__ __align__(16) float at[128*36];   // [j][m]
  __shared__ __align__(16) float wt[128*68];   // [j][cls]
  __shared__ float bsh[64];
  for (int i = 0; i < 16; ++i){
    int e = i*256 + tid; int m = e >> 7; int j = e & 127;
    at[j*36 + m] = (m0 + m < B_*TDEC) ? attnf[(m0 + m)*NH + j] : 0.f;
  }
  for (int i = 0; i < 32; ++i){
    int e = i*256 + tid; int cl = e >> 7; int j = e & 127;
    int n = n0 + cl;
    wt[j*68 + cl] = (n < NCLS) ? fcw[n*NH + j] : 0.f;
  }
  if (tid < 64) bsh[tid] = (n0 + tid < NCLS) ? fcb[n0 + tid] : 0.f;
  __syncthreads();
  int tn = tid & 15, tm = tid >> 4;
  float acc[2][4] = {{0.f,0.f,0.f,0.f},{0.f,0.f,0.f,0.f}};
  for (int j = 0; j < 128; ++j){
    float2 av = *(const float2*)(at + j*36 + tm*2);
    float4 wv = *(const float4*)(wt + j*68 + tn*4);
    acc[0][0] += av.x*wv.x; acc[0][1] += av.x*wv.y;
    acc[0][2] += av.x*wv.z; acc[0][3] += av.x*wv.w;
    acc[1][0] += av.y*wv.x; acc[1][1] += av.y*wv.y;
    acc[1][2] += av.y*wv.z; acc[1][3] += av.y*wv.w;
  }
  #pragma unroll
  for (int i = 0; i < 2; ++i){
    int m = m0 + tm*2 + i;
    if (m < B_*TDEC){
      #pragma unroll
      for (int ii = 0; ii < 4; ++ii){
        int n = n0 + tn*4 + ii;
        if (n < NCLS) out[m*NCLS + n] = acc[i][ii] + bsh[tn*4 + ii];
      }
    }
  }
}

// ============================================================================
extern "C" void kernel_launch(void* const* d_in, const int* in_sizes, int n_in,
                              void* d_out, int out_size, void* d_ws, size_t ws_size,
                              hipStream_t stream)
{
  (void)in_sizes; (void)n_in; (void)out_size; (void)ws_size;
  const float* x      = (const float*)d_in[0];
  const int*   tgt    = (const int*)  d_in[1];
  const float* conv0w = (const float*)d_in[2];
  const float* conv0b = (const float*)d_in[3];
  const float* bn0g   = (const float*)d_in[4];
  const float* bn0b   = (const float*)d_in[5];
  const float* bn0m   = (const float*)d_in[6];
  const float* bn0v   = (const float*)d_in[7];
  const float* dww    = (const float*)d_in[8];
  const float* dwb    = (const float*)d_in[9];
  const float* bn1g   = (const float*)d_in[10];
  const float* bn1b   = (const float*)d_in[11];
  const float* bn1m   = (const float*)d_in[12];
  const float* bn1v   = (const float*)d_in[13];
  const float* pww    = (const float*)d_in[14];
  const float* pwb    = (const float*)d_in[15];
  const float* bn2g   = (const float*)d_in[16];
  const float* bn2b   = (const float*)d_in[17];
  const float* bn2m   = (const float*)d_in[18];
  const float* bn2v   = (const float*)d_in[19];
  const float* encwih = (const float*)d_in[20];
  const float* encwhh = (const float*)d_in[21];
  const float* encbih = (const float*)d_in[22];
  const float* encbhh = (const float*)d_in[23];
  const float* decwih = (const float*)d_in[24];
  const float* decwhh = (const float*)d_in[25];
  const float* decbih = (const float*)d_in[26];
  const float* decbhh = (const float*)d_in[27];
  const float* emb    = (const float*)d_in[28];
  const float* qw     = (const float*)d_in[29];
  const float* qb0    = (const float*)d_in[30];
  const float* kw     = (const float*)d_in[31];
  const float* kb     = (const float*)d_in[32];
  const float* ew     = (const float*)d_in[33];
  const float* eb     = (const float*)d_in[34];
  const float* fcw    = (const float*)d_in[35];
  const float* fcb    = (const float*)d_in[36];

  float* ws    = (float*)d_ws;
  float* hbuf  = ws + 0;         // 2097152
  float* tbuf  = ws + 2097152;   // 2097152 (t; later: ebuf + kwA)
  float* feat  = ws + 4194304;   // 2097152
  float* xp    = ws + 6291456;   // 393216
  float* indec = ws + 6684672;   // 41984
  float* xpd   = ws + 6726656;   // 125952
  float* ybuf  = ws + 6852608;   // 41984
  float* qbuf  = ws + 6894592;   // 83968
  float* attf  = ws + 6978560;   // 83968
  float* pwT   = ws + 7062528;   // 16384
  float* kbuf  = hbuf;           // alias: h dead after k_dw
  float* ebuf  = tbuf;           // alias: t dead after k_pw (671744 floats)
  _Float16* kwA = (_Float16*)(tbuf + 1048576); // 147456 halves, inside dead tbuf
  float* out   = (float*)d_out;

  hipLaunchKernelGGL(k_pwT,     dim3(64),          dim3(256), 0, stream, pww, pwT);
  hipLaunchKernelGGL(k_conv0,   dim3(2048),        dim3(256), 0, stream,
                     x, conv0w, conv0b, bn0g, bn0b, bn0m, bn0v, hbuf);
  hipLaunchKernelGGL(k_dw,      dim3(8192),        dim3(256), 0, stream,
                     hbuf, dww, dwb, bn1g, bn1b, bn1m, bn1v, tbuf);
  hipLaunchKernelGGL(k_pw,      dim3(256),         dim3(512), 0, stream,
                     tbuf, pwT, pwb, bn2g, bn2b, bn2m, bn2v, feat);
  hipLaunchKernelGGL(k_wprep,   dim3(576),         dim3(256), 0, stream, kw, kwA);
  hipLaunchKernelGGL(k_embed,   dim3(160),         dim3(256), 0, stream, tgt, emb, indec);
  hipLaunchKernelGGL(k_encxp,   dim3(64, 4),       dim3(256), 0, stream,
                     feat, encwih, encbih, xp);
  hipLaunchKernelGGL((k_scan<128,false>), dim3(16), dim3(64), 0, stream,
                     xp, encwhh, encbhh, indec);
  hipLaunchKernelGGL(k_xpd,     dim3(492),         dim3(256), 0, stream,
                     indec, decwih, decbih, xpd);
  hipLaunchKernelGGL((k_scan<TDEC,true>), dim3(16), dim3(64), 0, stream,
                     xpd, decwhh, decbhh, ybuf);
  hipLaunchKernelGGL(k_q,       dim3(328),         dim3(256), 0, stream,
                     ybuf, qw, qb0, qbuf);
  hipLaunchKernelGGL(k_kconv3,  dim3(4096),        dim3(64), 0, stream,
                     feat, (const uint4*)kwA, kb, kbuf);
  hipLaunchKernelGGL(k_e2,      dim3(256),         dim3(256), 0, stream,
                     kbuf, qbuf, ew, eb, ebuf);
  hipLaunchKernelGGL(k_softmax, dim3(B_*TDEC),     dim3(256), 0, stream, ebuf);
  hipLaunchKernelGGL(k_attnf,   dim3(352),         dim3(256), 0, stream,
                     feat, ebuf, attf);
  hipLaunchKernelGGL(k_fc,      dim3(104, 21),     dim3(256), 0, stream,
                     attf, fcw, fcb, out);
}